// Round 2
// baseline (1031.806 us; speedup 1.0000x reference)
//
#include <hip/hip_runtime.h>

// Problem constants (fixed by the reference)
#define ND 10000
#define NT_ 10000
#define EE 500000
#define BB 8192
#define DF 256
#define TFD 256
#define HH 128
#define CF 954
#define P1C 2048
#define P2C 512

typedef unsigned short u16;
typedef __attribute__((ext_vector_type(8))) short short8;
typedef __attribute__((ext_vector_type(4))) float f4;

__device__ inline u16 f2bf(float f) {
  unsigned int u = __builtin_bit_cast(unsigned int, f);
  unsigned int r = (u + 0x7FFFu + ((u >> 16) & 1u)) >> 16;
  return (u16)r;
}
__device__ inline float bf2f(u16 b) {
  return __builtin_bit_cast(float, ((unsigned int)b) << 16);
}
__device__ inline u16 to_bf(float v) { return f2bf(v); }
__device__ inline u16 to_bf(u16 v) { return v; }
__device__ inline float ldval(float v) { return v; }
__device__ inline float ldval(u16 v) { return bf2f(v); }

__device__ inline void load8cvt(const float* p, u16* dst) {
#pragma unroll
  for (int i = 0; i < 4; ++i) {
    float2 v = reinterpret_cast<const float2*>(p)[i];
    dst[2 * i] = f2bf(v.x);
    dst[2 * i + 1] = f2bf(v.y);
  }
}
__device__ inline void load8cvt(const u16* p, u16* dst) {
#pragma unroll
  for (int i = 0; i < 4; ++i) {
    unsigned int v = reinterpret_cast<const unsigned int*>(p)[i];
    dst[2 * i] = (u16)(v & 0xFFFFu);
    dst[2 * i + 1] = (u16)(v >> 16);
  }
}

// ---------------- weight transpose: fp32 [K,N] -> bf16 [N,K] ----------------
__global__ void __launch_bounds__(256) transpose_w(const float* __restrict__ W,
                                                   u16* __restrict__ Wt, int K, int N) {
  __shared__ u16 tile[32][33];
  const int bn = blockIdx.x << 5;
  const int bk = blockIdx.y << 5;
  const int tx = threadIdx.x;  // 0..31
  const int ty = threadIdx.y;  // 0..7
#pragma unroll
  for (int i = ty; i < 32; i += 8) {
    int k = bk + i, n = bn + tx;
    tile[i][tx] = (k < K && n < N) ? f2bf(W[(long)k * N + n]) : (u16)0;
  }
  __syncthreads();
#pragma unroll
  for (int i = ty; i < 32; i += 8) {
    int n = bn + i, k = bk + tx;
    if (n < N && k < K) Wt[(long)n * K + k] = tile[tx][i];
  }
}

// ---------------- bf16 MFMA GEMM: C[M,N] = act(A[M,K] @ Bt[N,K]^T + bias) ----
// 128x128 tile, BK=32, 4 waves (2x2), each wave 64x64 via 4x4 16x16x32 mfma.
template <typename TA, int ACT, int BIAS>
__global__ void __launch_bounds__(256) gemm_bt(const TA* __restrict__ A,
                                               const u16* __restrict__ Bt,
                                               const float* __restrict__ bias,
                                               u16* __restrict__ C, int M, int N, int K) {
  const int tiles_n = N >> 7;
  const int bm = blockIdx.x / tiles_n;
  const int bn = blockIdx.x % tiles_n;
  const int row0 = bm << 7, col0 = bn << 7;
  __shared__ u16 As[128][40];  // 80B row stride: 16B-aligned, 2-way-bank-free
  __shared__ u16 Bs[128][40];
  const int t = threadIdx.x;
  const int lane = t & 63;
  const int wid = t >> 6;
  const int wr = wid >> 1, wc = wid & 1;
  const int lr = lane & 15, lk = lane >> 4;
  f4 acc[4][4] = {};
  const int nk = (K + 31) >> 5;
  for (int kt = 0; kt < nk; ++kt) {
    const int k0 = kt << 5;
    __syncthreads();
#pragma unroll
    for (int q = 0; q < 2; ++q) {
      const int c = t + (q << 8);
      const int r = c >> 2;
      const int cp = (c & 3) << 3;
      const int gk = k0 + cp;
      union { u16 u[8]; short8 v; } ta, tb;
      const int gr = row0 + r;
      if (gr < M && gk + 8 <= K) {
        load8cvt(A + (long)gr * K + gk, ta.u);
      } else {
#pragma unroll
        for (int i = 0; i < 8; ++i) {
          int kk = gk + i;
          ta.u[i] = (gr < M && kk < K) ? to_bf(A[(long)gr * K + kk]) : (u16)0;
        }
      }
      const int gn = col0 + r;  // N is always a multiple of 128 here
      if (gk + 8 <= K) {
        load8cvt(Bt + (long)gn * K + gk, tb.u);
      } else {
#pragma unroll
        for (int i = 0; i < 8; ++i) {
          int kk = gk + i;
          tb.u[i] = (kk < K) ? Bt[(long)gn * K + kk] : (u16)0;
        }
      }
      *reinterpret_cast<short8*>(&As[r][cp]) = ta.v;
      *reinterpret_cast<short8*>(&Bs[r][cp]) = tb.v;
    }
    __syncthreads();
    short8 af[4], bfr[4];
#pragma unroll
    for (int m = 0; m < 4; ++m)
      af[m] = *reinterpret_cast<const short8*>(&As[(wr << 6) + (m << 4) + lr][lk << 3]);
#pragma unroll
    for (int n = 0; n < 4; ++n)
      bfr[n] = *reinterpret_cast<const short8*>(&Bs[(wc << 6) + (n << 4) + lr][lk << 3]);
#pragma unroll
    for (int m = 0; m < 4; ++m)
#pragma unroll
      for (int n = 0; n < 4; ++n)
        acc[m][n] = __builtin_amdgcn_mfma_f32_16x16x32_bf16(af[m], bfr[n], acc[m][n], 0, 0, 0);
  }
#pragma unroll
  for (int n = 0; n < 4; ++n) {
    const int col = col0 + (wc << 6) + (n << 4) + lr;
    const float bv = BIAS ? bias[col] : 0.0f;
#pragma unroll
    for (int m = 0; m < 4; ++m) {
#pragma unroll
      for (int r = 0; r < 4; ++r) {
        int row = row0 + (wr << 6) + (m << 4) + (lk << 2) + r;
        if (row < M) {
          float x = acc[m][n][r] + bv;
          if (ACT) x = fmaxf(x, 0.0f);
          C[(long)row * N + col] = f2bf(x);
        }
      }
    }
  }
}

// ---------------- per-node attention logits: es = hs.a_s, ed = hd.a_d --------
__global__ void __launch_bounds__(128) esed_kernel(const u16* __restrict__ hs,
                                                   const u16* __restrict__ hd,
                                                   const float* __restrict__ a_s,
                                                   const float* __restrict__ a_d,
                                                   float* __restrict__ es,
                                                   float* __restrict__ ed) {
  const int row = blockIdx.x;
  const int t = threadIdx.x;
  float ps = bf2f(hs[(long)row * HH + t]) * a_s[t];
  float pd = bf2f(hd[(long)row * HH + t]) * a_d[t];
#pragma unroll
  for (int o = 32; o > 0; o >>= 1) {
    ps += __shfl_down(ps, o);
    pd += __shfl_down(pd, o);
  }
  __shared__ float s0[2], s1[2];
  if ((t & 63) == 0) { s0[t >> 6] = ps; s1[t >> 6] = pd; }
  __syncthreads();
  if (t == 0) {
    es[row] = s0[0] + s0[1];
    ed[row] = s1[0] + s1[1];
  }
}

// ---------------- CSR build ----------------
__global__ void __launch_bounds__(256) count4_kernel(const int* __restrict__ d0,
                                                     const int* __restrict__ d1,
                                                     const int* __restrict__ d2,
                                                     const int* __restrict__ d3,
                                                     int* __restrict__ cnt_all, int n) {
  const int cv = blockIdx.y;
  const int* dp = cv == 0 ? d0 : cv == 1 ? d1 : cv == 2 ? d2 : d3;
  int i = blockIdx.x * 256 + threadIdx.x;
  if (i < n) atomicAdd(&cnt_all[cv * ND + dp[i]], 1);
}

__global__ void __launch_bounds__(1024) scan4_kernel(const int* __restrict__ cnt_all,
                                                     int* __restrict__ offs_all,
                                                     int* __restrict__ cur_all, int n) {
  const int cv = blockIdx.x;
  const int* cnt = cnt_all + cv * ND;
  int* offs = offs_all + cv * 10004;
  int* curp = cur_all + cv * ND;
  const int t = threadIdx.x;
  const int lane = t & 63, w = t >> 6;  // 16 waves
  __shared__ int wpre[16];
  __shared__ int wsum[16];
  int carry = 0;
  for (int base = 0; base < n; base += 1024) {
    int x = (base + t < n) ? cnt[base + t] : 0;
    int v = x;
#pragma unroll
    for (int o = 1; o < 64; o <<= 1) {
      int y = __shfl_up(v, o);
      if (lane >= o) v += y;
    }
    if (lane == 63) wsum[w] = v;
    __syncthreads();
    if (w == 0 && lane < 16) {
      int s = wsum[lane];
#pragma unroll
      for (int o = 1; o < 16; o <<= 1) {
        int y = __shfl_up(s, o);
        if (lane >= o) s += y;
      }
      wpre[lane] = s;
    }
    __syncthreads();
    int wofs = (w == 0) ? 0 : wpre[w - 1];
    int excl = v + wofs - x;
    if (base + t < n) {
      offs[base + t] = carry + excl;
      curp[base + t] = carry + excl;
    }
    int tot = wpre[15];
    __syncthreads();
    carry += tot;
  }
  if (t == 0) offs[n] = carry;
}

__global__ void __launch_bounds__(256) scatter4_kernel(const int* __restrict__ d0,
                                                       const int* __restrict__ d1,
                                                       const int* __restrict__ d2,
                                                       const int* __restrict__ d3,
                                                       int* __restrict__ cur_all,
                                                       int* __restrict__ lst_all, int n) {
  const int cv = blockIdx.y;
  const int* dp = cv == 0 ? d0 : cv == 1 ? d1 : cv == 2 ? d2 : d3;
  int i = blockIdx.x * 256 + threadIdx.x;
  if (i < n) {
    int p = atomicAdd(&cur_all[cv * ND + dp[i]], 1);
    lst_all[(long)cv * EE + p] = i;
  }
}

// ---------------- per-dst edge softmax + gather-accumulate (no float atomics)
__global__ void __launch_bounds__(128) gat_accum_kernel(const int* __restrict__ offs,
                                                        const int* __restrict__ lst,
                                                        const int* __restrict__ src,
                                                        const float* __restrict__ es,
                                                        const float* __restrict__ ed,
                                                        const u16* __restrict__ hs,
                                                        float* __restrict__ exbuf,
                                                        float* __restrict__ acc) {
  const int d = blockIdx.x;
  const int t = threadIdx.x;
  const int o0 = offs[d], o1 = offs[d + 1];
  const int deg = o1 - o0;
  const float edd = ed[d];
  float part = 0.f;
  for (int j = t; j < deg; j += 128) {
    int s = src[lst[o0 + j]];
    float e = es[s] + edd;
    e = e > 0.f ? e : 0.2f * e;
    float ex = __expf(e);
    exbuf[o0 + j] = ex;
    part += ex;
  }
#pragma unroll
  for (int o = 32; o > 0; o >>= 1) part += __shfl_down(part, o);
  __shared__ float sh[2];
  if ((t & 63) == 0) sh[t >> 6] = part;
  __syncthreads();
  const float scale = 1.0f / (sh[0] + sh[1] + 1e-16f);
  float a = 0.f;
  for (int j = 0; j < deg; ++j) {
    int eid = lst[o0 + j];
    int s = src[eid];
    float al = exbuf[o0 + j] * scale;
    a += al * bf2f(hs[(long)s * HH + t]);
  }
  acc[(long)d * HH + t] = a;
}

// ---------------- finalize: relu(accA+accB+bA+bB) -> fp32 out (+bf16 feat) ---
__global__ void __launch_bounds__(256) finalize_kernel(const float* __restrict__ a1,
                                                       const float* __restrict__ a2,
                                                       const float* __restrict__ b1,
                                                       const float* __restrict__ b2,
                                                       float* __restrict__ out,
                                                       u16* __restrict__ feat, int n) {
  int i = blockIdx.x * 256 + threadIdx.x;
  if (i >= n) return;
  int h = i & (HH - 1);
  float v = a1[i] + a2[i] + b1[h] + b2[h];
  v = fmaxf(v, 0.0f);
  out[i] = v;
  if (feat) feat[i] = f2bf(v);
}

// ---------------- row L2-normalize -> bf16 ----------------
template <typename T>
__global__ void __launch_bounds__(256) rownorm_kernel(const T* __restrict__ X,
                                                      u16* __restrict__ Y, int K) {
  const int row = blockIdx.x;
  const int t = threadIdx.x;
  const T* xr = X + (long)row * K;
  float ss = 0.f;
  for (int k = t; k < K; k += 256) {
    float v = ldval(xr[k]);
    ss += v * v;
  }
#pragma unroll
  for (int o = 32; o > 0; o >>= 1) ss += __shfl_down(ss, o);
  __shared__ float sh[4];
  if ((t & 63) == 0) sh[t >> 6] = ss;
  __syncthreads();
  float tot = sh[0] + sh[1] + sh[2] + sh[3];
  float inv = 1.0f / fmaxf(sqrtf(tot), 1e-12f);
  u16* yr = Y + (long)row * K;
  for (int k = t; k < K; k += 256) yr[k] = f2bf(ldval(xr[k]) * inv);
}

// ---------------- hidden = [feat[id1], feat[id2], cell] ----------------
__global__ void __launch_bounds__(256) build_hidden_kernel(const u16* __restrict__ feat,
                                                           const int* __restrict__ id1,
                                                           const int* __restrict__ id2,
                                                           const u16* __restrict__ cell,
                                                           u16* __restrict__ hidden) {
  int i = blockIdx.x * 256 + threadIdx.x;  // < BB*512
  int row = i >> 9, col = i & 511;
  u16 v;
  if (col < 128) v = feat[(long)id1[row] * HH + col];
  else if (col < 256) v = feat[(long)id2[row] * HH + (col - 128)];
  else v = cell[(long)row * 256 + (col - 256)];
  hidden[i] = v;
}

// ---------------- logits: [B,128] @ [128,2] + b -> fp32 ----------------
__global__ void __launch_bounds__(128) logits_kernel(const u16* __restrict__ h2,
                                                     const float* __restrict__ W,
                                                     const float* __restrict__ b,
                                                     float* __restrict__ out) {
  const int row = blockIdx.x;
  const int t = threadIdx.x;
  float hv = bf2f(h2[(long)row * HH + t]);
  float p0 = hv * W[2 * t], p1 = hv * W[2 * t + 1];
#pragma unroll
  for (int o = 32; o > 0; o >>= 1) {
    p0 += __shfl_down(p0, o);
    p1 += __shfl_down(p1, o);
  }
  __shared__ float sA[2], sB[2];
  if ((t & 63) == 0) { sA[t >> 6] = p0; sB[t >> 6] = p1; }
  __syncthreads();
  if (t == 0) {
    out[2 * row] = sA[0] + sA[1] + b[0];
    out[2 * row + 1] = sB[0] + sB[1] + b[1];
  }
}

extern "C" void kernel_launch(void* const* d_in, const int* in_sizes, int n_in,
                              void* d_out, int out_size, void* d_ws, size_t ws_size,
                              hipStream_t stream) {
  const float* x_drug = (const float*)d_in[0];
  const float* x_target = (const float*)d_in[1];
  const float* cellf = (const float*)d_in[2];
  const float* dd_W = (const float*)d_in[3];
  const float* dd_as = (const float*)d_in[4];
  const float* dd_ad = (const float*)d_in[5];
  const float* dd_b = (const float*)d_in[6];
  const float* dt_Ws = (const float*)d_in[7];
  const float* dt_Wd = (const float*)d_in[8];
  const float* dt_as = (const float*)d_in[9];
  const float* dt_ad = (const float*)d_in[10];
  const float* dt_b = (const float*)d_in[11];
  const float* td_Ws = (const float*)d_in[12];
  const float* td_Wd = (const float*)d_in[13];
  const float* td_as = (const float*)d_in[14];
  const float* td_ad = (const float*)d_in[15];
  const float* td_b = (const float*)d_in[16];
  const float* tt_W = (const float*)d_in[17];
  const float* tt_as = (const float*)d_in[18];
  const float* tt_ad = (const float*)d_in[19];
  const float* tt_b = (const float*)d_in[20];
  const float* r1_W1 = (const float*)d_in[21];
  const float* r1_b1 = (const float*)d_in[22];
  const float* r1_W2 = (const float*)d_in[23];
  const float* r1_b2 = (const float*)d_in[24];
  const float* r1_W3 = (const float*)d_in[25];
  const float* r1_b3 = (const float*)d_in[26];
  const float* r2_W1 = (const float*)d_in[27];
  const float* r2_b1 = (const float*)d_in[28];
  const float* r2_W2 = (const float*)d_in[29];
  const float* r2_b2 = (const float*)d_in[30];
  const float* r2_W3 = (const float*)d_in[31];
  const float* r2_b3 = (const float*)d_in[32];
  const float* cls_W = (const float*)d_in[33];
  const float* cls_b = (const float*)d_in[34];
  // conv order: 0=dd(dst=drug), 1=td(dst=drug), 2=dt(dst=target), 3=tt(dst=target)
  const int* src_dd = (const int*)d_in[35];
  const int* dst_dd = (const int*)d_in[36];
  const int* src_dt = (const int*)d_in[37];
  const int* dst_dt = (const int*)d_in[38];
  const int* src_td = (const int*)d_in[39];
  const int* dst_td = (const int*)d_in[40];
  const int* src_tt = (const int*)d_in[41];
  const int* dst_tt = (const int*)d_in[42];
  const int* drug1 = (const int*)d_in[43];
  const int* drug2 = (const int*)d_in[44];
  float* out = (float*)d_out;

  char* ws = (char*)d_ws;
  size_t cur = 0;
  auto alloc = [&](size_t b) {
    size_t r = cur;
    cur += (b + 255) & ~(size_t)255;
    return r;
  };

  u16* wt_dd = (u16*)(ws + alloc((size_t)DF * HH * 2));
  u16* wt_tds = (u16*)(ws + alloc((size_t)TFD * HH * 2));
  u16* wt_tdd = (u16*)(ws + alloc((size_t)DF * HH * 2));
  u16* wt_dts = (u16*)(ws + alloc((size_t)DF * HH * 2));
  u16* wt_dtd = (u16*)(ws + alloc((size_t)TFD * HH * 2));
  u16* wt_tt = (u16*)(ws + alloc((size_t)TFD * HH * 2));
  u16* wt1 = (u16*)(ws + alloc((size_t)P1C * CF * 2));
  u16* wt2 = (u16*)(ws + alloc((size_t)P2C * P1C * 2));
  u16* wt3 = (u16*)(ws + alloc((size_t)256 * P2C * 2));
  u16* wt4 = (u16*)(ws + alloc((size_t)P1C * 512 * 2));
  u16* wt5 = (u16*)(ws + alloc((size_t)P2C * P1C * 2));
  u16* wt6 = (u16*)(ws + alloc((size_t)HH * P2C * 2));
  u16* h_dd = (u16*)(ws + alloc((size_t)ND * HH * 2));
  u16* h_tds = (u16*)(ws + alloc((size_t)NT_ * HH * 2));
  u16* h_tdd = (u16*)(ws + alloc((size_t)ND * HH * 2));
  u16* h_dts = (u16*)(ws + alloc((size_t)ND * HH * 2));
  u16* h_dtd = (u16*)(ws + alloc((size_t)NT_ * HH * 2));
  u16* h_tt = (u16*)(ws + alloc((size_t)NT_ * HH * 2));
  float* es0 = (float*)(ws + alloc(ND * 4));
  float* ed0 = (float*)(ws + alloc(ND * 4));
  float* es1 = (float*)(ws + alloc(NT_ * 4));
  float* ed1 = (float*)(ws + alloc(ND * 4));
  float* es2 = (float*)(ws + alloc(ND * 4));
  float* ed2 = (float*)(ws + alloc(NT_ * 4));
  float* es3 = (float*)(ws + alloc(NT_ * 4));
  float* ed3 = (float*)(ws + alloc(NT_ * 4));
  size_t cnt_off = alloc((size_t)4 * ND * 4);
  int* cnt_all = (int*)(ws + cnt_off);
  int* cur_all = (int*)(ws + alloc((size_t)4 * ND * 4));
  int* offs_all = (int*)(ws + alloc((size_t)4 * 10004 * 4));
  int* lst_all = (int*)(ws + alloc((size_t)4 * EE * 4));
  float* exb0 = (float*)(ws + alloc((size_t)EE * 4));
  float* exb1 = (float*)(ws + alloc((size_t)EE * 4));
  float* exb2 = (float*)(ws + alloc((size_t)EE * 4));
  float* exb3 = (float*)(ws + alloc((size_t)EE * 4));
  float* acc0 = (float*)(ws + alloc((size_t)ND * HH * 4));
  float* acc1 = (float*)(ws + alloc((size_t)ND * HH * 4));
  float* acc2 = (float*)(ws + alloc((size_t)NT_ * HH * 4));
  float* acc3 = (float*)(ws + alloc((size_t)NT_ * HH * 4));
  u16* feat = (u16*)(ws + alloc((size_t)ND * HH * 2));
  u16* cellnorm = (u16*)(ws + alloc((size_t)BB * CF * 2));
  u16* big = (u16*)(ws + alloc((size_t)BB * P1C * 2));
  u16* mid = (u16*)(ws + alloc((size_t)BB * P2C * 2));
  u16* cellout = (u16*)(ws + alloc((size_t)BB * 256 * 2));
  u16* hidden = (u16*)(ws + alloc((size_t)BB * 512 * 2));
  u16* hiddennorm = (u16*)(ws + alloc((size_t)BB * 512 * 2));
  u16* h2 = (u16*)(ws + alloc((size_t)BB * HH * 2));

  dim3 tb(32, 8);
  transpose_w<<<dim3(HH / 32, DF / 32), tb, 0, stream>>>(dd_W, wt_dd, DF, HH);
  transpose_w<<<dim3(HH / 32, TFD / 32), tb, 0, stream>>>(td_Ws, wt_tds, TFD, HH);
  transpose_w<<<dim3(HH / 32, DF / 32), tb, 0, stream>>>(td_Wd, wt_tdd, DF, HH);
  transpose_w<<<dim3(HH / 32, DF / 32), tb, 0, stream>>>(dt_Ws, wt_dts, DF, HH);
  transpose_w<<<dim3(HH / 32, TFD / 32), tb, 0, stream>>>(dt_Wd, wt_dtd, TFD, HH);
  transpose_w<<<dim3(HH / 32, TFD / 32), tb, 0, stream>>>(tt_W, wt_tt, TFD, HH);
  transpose_w<<<dim3(P1C / 32, (CF + 31) / 32), tb, 0, stream>>>(r1_W1, wt1, CF, P1C);
  transpose_w<<<dim3(P2C / 32, P1C / 32), tb, 0, stream>>>(r1_W2, wt2, P1C, P2C);
  transpose_w<<<dim3(256 / 32, P2C / 32), tb, 0, stream>>>(r1_W3, wt3, P2C, 256);
  transpose_w<<<dim3(P1C / 32, 512 / 32), tb, 0, stream>>>(r2_W1, wt4, 512, P1C);
  transpose_w<<<dim3(P2C / 32, P1C / 32), tb, 0, stream>>>(r2_W2, wt5, P1C, P2C);
  transpose_w<<<dim3(HH / 32, P2C / 32), tb, 0, stream>>>(r2_W3, wt6, P2C, HH);

  const int gM = (ND + 127) / 128;  // 79 (N=128 -> tiles_n=1)
  gemm_bt<float, 0, 0><<<gM, 256, 0, stream>>>(x_drug, wt_dd, nullptr, h_dd, ND, HH, DF);
  gemm_bt<float, 0, 0><<<gM, 256, 0, stream>>>(x_target, wt_tds, nullptr, h_tds, NT_, HH, TFD);
  gemm_bt<float, 0, 0><<<gM, 256, 0, stream>>>(x_drug, wt_tdd, nullptr, h_tdd, ND, HH, DF);
  gemm_bt<float, 0, 0><<<gM, 256, 0, stream>>>(x_drug, wt_dts, nullptr, h_dts, ND, HH, DF);
  gemm_bt<float, 0, 0><<<gM, 256, 0, stream>>>(x_target, wt_dtd, nullptr, h_dtd, NT_, HH, TFD);
  gemm_bt<float, 0, 0><<<gM, 256, 0, stream>>>(x_target, wt_tt, nullptr, h_tt, NT_, HH, TFD);

  esed_kernel<<<ND, 128, 0, stream>>>(h_dd, h_dd, dd_as, dd_ad, es0, ed0);
  esed_kernel<<<ND, 128, 0, stream>>>(h_tds, h_tdd, td_as, td_ad, es1, ed1);
  esed_kernel<<<ND, 128, 0, stream>>>(h_dts, h_dtd, dt_as, dt_ad, es2, ed2);
  esed_kernel<<<NT_, 128, 0, stream>>>(h_tt, h_tt, tt_as, tt_ad, es3, ed3);

  hipMemsetAsync(ws + cnt_off, 0, (size_t)4 * ND * 4, stream);
  const int egrid = (EE + 255) / 256;
  count4_kernel<<<dim3(egrid, 4), 256, 0, stream>>>(dst_dd, dst_td, dst_dt, dst_tt, cnt_all, EE);
  scan4_kernel<<<4, 1024, 0, stream>>>(cnt_all, offs_all, cur_all, ND);
  scatter4_kernel<<<dim3(egrid, 4), 256, 0, stream>>>(dst_dd, dst_td, dst_dt, dst_tt, cur_all,
                                                      lst_all, EE);

  gat_accum_kernel<<<ND, 128, 0, stream>>>(offs_all + 0 * 10004, lst_all + 0L * EE, src_dd, es0,
                                           ed0, h_dd, exb0, acc0);
  gat_accum_kernel<<<ND, 128, 0, stream>>>(offs_all + 1 * 10004, lst_all + 1L * EE, src_td, es1,
                                           ed1, h_tds, exb1, acc1);
  gat_accum_kernel<<<NT_, 128, 0, stream>>>(offs_all + 2 * 10004, lst_all + 2L * EE, src_dt, es2,
                                            ed2, h_dts, exb2, acc2);
  gat_accum_kernel<<<NT_, 128, 0, stream>>>(offs_all + 3 * 10004, lst_all + 3L * EE, src_tt, es3,
                                            ed3, h_tt, exb3, acc3);

  finalize_kernel<<<(ND * HH + 255) / 256, 256, 0, stream>>>(acc0, acc1, dd_b, td_b, out + 16384,
                                                             feat, ND * HH);
  finalize_kernel<<<(NT_ * HH + 255) / 256, 256, 0, stream>>>(acc2, acc3, dt_b, tt_b,
                                                              out + 16384 + ND * HH, nullptr,
                                                              NT_ * HH);

  rownorm_kernel<float><<<BB, 256, 0, stream>>>(cellf, cellnorm, CF);
  gemm_bt<u16, 1, 1><<<(BB / 128) * (P1C / 128), 256, 0, stream>>>(cellnorm, wt1, r1_b1, big, BB,
                                                                   P1C, CF);
  gemm_bt<u16, 1, 1><<<(BB / 128) * (P2C / 128), 256, 0, stream>>>(big, wt2, r1_b2, mid, BB, P2C,
                                                                   P1C);
  gemm_bt<u16, 1, 1><<<(BB / 128) * (256 / 128), 256, 0, stream>>>(mid, wt3, r1_b3, cellout, BB,
                                                                   256, P2C);
  build_hidden_kernel<<<BB * 512 / 256, 256, 0, stream>>>(feat, drug1, drug2, cellout, hidden);
  rownorm_kernel<u16><<<BB, 256, 0, stream>>>(hidden, hiddennorm, 512);
  gemm_bt<u16, 1, 1><<<(BB / 128) * (P1C / 128), 256, 0, stream>>>(hiddennorm, wt4, r2_b1, big, BB,
                                                                   P1C, 512);
  gemm_bt<u16, 1, 1><<<(BB / 128) * (P2C / 128), 256, 0, stream>>>(big, wt5, r2_b2, mid, BB, P2C,
                                                                   P1C);
  gemm_bt<u16, 1, 1><<<(BB / 128) * (HH / 128), 256, 0, stream>>>(mid, wt6, r2_b3, h2, BB, HH,
                                                                  P2C);
  logits_kernel<<<BB, 128, 0, stream>>>(h2, cls_W, cls_b, out);
}

// Round 3
// 558.436 us; speedup vs baseline: 1.8477x; 1.8477x over previous
//
#include <hip/hip_runtime.h>

// Problem constants (fixed by the reference)
#define ND 10000
#define NT_ 10000
#define EE 500000
#define BB 8192
#define DF 256
#define TFD 256
#define HH 128
#define CF 954
#define P1C 2048
#define P2C 512

// sort constants
#define CHUNK 4096
#define NCH 123          // ceil(500000/4096)
#define NBK 157          // ceil(10000/64)
#define MAXB 6144        // per-bucket LDS capacity (mean 3200, sigma ~57)

typedef unsigned short u16;
typedef __attribute__((ext_vector_type(8))) short short8;
typedef __attribute__((ext_vector_type(4))) float f4;

__device__ inline u16 f2bf(float f) {
  unsigned int u = __builtin_bit_cast(unsigned int, f);
  unsigned int r = (u + 0x7FFFu + ((u >> 16) & 1u)) >> 16;
  return (u16)r;
}
__device__ inline float bf2f(u16 b) {
  return __builtin_bit_cast(float, ((unsigned int)b) << 16);
}
__device__ inline u16 to_bf(float v) { return f2bf(v); }
__device__ inline u16 to_bf(u16 v) { return v; }
__device__ inline float ldval(float v) { return v; }
__device__ inline float ldval(u16 v) { return bf2f(v); }

__device__ inline void load8cvt(const float* p, u16* dst) {
#pragma unroll
  for (int i = 0; i < 4; ++i) {
    float2 v = reinterpret_cast<const float2*>(p)[i];
    dst[2 * i] = f2bf(v.x);
    dst[2 * i + 1] = f2bf(v.y);
  }
}
__device__ inline void load8cvt(const u16* p, u16* dst) {
#pragma unroll
  for (int i = 0; i < 4; ++i) {
    unsigned int v = reinterpret_cast<const unsigned int*>(p)[i];
    dst[2 * i] = (u16)(v & 0xFFFFu);
    dst[2 * i + 1] = (u16)(v >> 16);
  }
}

// ================= fused weight transpose: fp32 [K,N] -> bf16 [N,K] =========
struct TransArgs {
  const float* W[12];
  u16* Wt[12];
  int K[12];
  int N[12];
};

__global__ void __launch_bounds__(256) transpose_all(TransArgs ta) {
  const int id = blockIdx.y;
  const int K = ta.K[id], N = ta.N[id];
  const int tn = (N + 31) >> 5, tk = (K + 31) >> 5;
  if ((int)blockIdx.x >= tn * tk) return;
  const float* W = ta.W[id];
  u16* Wt = ta.Wt[id];
  const int bn = (blockIdx.x % tn) << 5;
  const int bk = (blockIdx.x / tn) << 5;
  __shared__ u16 tile[32][33];
  const int tx = threadIdx.x;  // 0..31
  const int ty = threadIdx.y;  // 0..7
#pragma unroll
  for (int i = ty; i < 32; i += 8) {
    int k = bk + i, n = bn + tx;
    tile[i][tx] = (k < K && n < N) ? f2bf(W[(long)k * N + n]) : (u16)0;
  }
  __syncthreads();
#pragma unroll
  for (int i = ty; i < 32; i += 8) {
    int n = bn + i, k = bk + tx;
    if (n < N && k < K) Wt[(long)n * K + k] = tile[tx][i];
  }
}

// ================= fused 6x node GEMM: [10000,256]x[256,128] bf16 MFMA ======
struct Gemm6Args {
  const float* A[6];
  const u16* B[6];
  u16* C[6];
};

__global__ void __launch_bounds__(256) gemm6(Gemm6Args g) {
  const int id = blockIdx.y;
  const float* __restrict__ A = g.A[id];
  const u16* __restrict__ Bt = g.B[id];
  u16* __restrict__ C = g.C[id];
  const int M = ND, K = DF;  // N=128
  const int row0 = blockIdx.x << 7;
  __shared__ u16 As[128][40];
  __shared__ u16 Bs[128][40];
  const int t = threadIdx.x;
  const int lane = t & 63;
  const int wid = t >> 6;
  const int wr = wid >> 1, wc = wid & 1;
  const int lr = lane & 15, lk = lane >> 4;
  f4 acc[4][4] = {};
  for (int kt = 0; kt < (K >> 5); ++kt) {
    const int k0 = kt << 5;
    __syncthreads();
#pragma unroll
    for (int q = 0; q < 2; ++q) {
      const int c = t + (q << 8);
      const int r = c >> 2;
      const int cp = (c & 3) << 3;
      const int gk = k0 + cp;
      union { u16 u[8]; short8 v; } ta, tb;
      const int gr = row0 + r;
      if (gr < M) {
        load8cvt(A + (long)gr * K + gk, ta.u);
      } else {
#pragma unroll
        for (int i = 0; i < 8; ++i) ta.u[i] = 0;
      }
      load8cvt(Bt + (long)r * K + gk, tb.u);
      *reinterpret_cast<short8*>(&As[r][cp]) = ta.v;
      *reinterpret_cast<short8*>(&Bs[r][cp]) = tb.v;
    }
    __syncthreads();
    short8 af[4], bfr[4];
#pragma unroll
    for (int m = 0; m < 4; ++m)
      af[m] = *reinterpret_cast<const short8*>(&As[(wr << 6) + (m << 4) + lr][lk << 3]);
#pragma unroll
    for (int n = 0; n < 4; ++n)
      bfr[n] = *reinterpret_cast<const short8*>(&Bs[(wc << 6) + (n << 4) + lr][lk << 3]);
#pragma unroll
    for (int m = 0; m < 4; ++m)
#pragma unroll
      for (int n = 0; n < 4; ++n)
        acc[m][n] = __builtin_amdgcn_mfma_f32_16x16x32_bf16(af[m], bfr[n], acc[m][n], 0, 0, 0);
  }
#pragma unroll
  for (int n = 0; n < 4; ++n) {
    const int col = (wc << 6) + (n << 4) + lr;
#pragma unroll
    for (int m = 0; m < 4; ++m) {
#pragma unroll
      for (int r = 0; r < 4; ++r) {
        int row = row0 + (wr << 6) + (m << 4) + (lk << 2) + r;
        if (row < M) C[(long)row * HH + col] = f2bf(acc[m][n][r]);
      }
    }
  }
}

// ================= general bf16 MFMA GEMM (MLP chain) =======================
template <typename TA, int ACT, int BIAS>
__global__ void __launch_bounds__(256) gemm_bt(const TA* __restrict__ A,
                                               const u16* __restrict__ Bt,
                                               const float* __restrict__ bias,
                                               u16* __restrict__ C, int M, int N, int K) {
  const int tiles_n = N >> 7;
  const int bm = blockIdx.x / tiles_n;
  const int bn = blockIdx.x % tiles_n;
  const int row0 = bm << 7, col0 = bn << 7;
  __shared__ u16 As[128][40];
  __shared__ u16 Bs[128][40];
  const int t = threadIdx.x;
  const int lane = t & 63;
  const int wid = t >> 6;
  const int wr = wid >> 1, wc = wid & 1;
  const int lr = lane & 15, lk = lane >> 4;
  f4 acc[4][4] = {};
  const int nk = (K + 31) >> 5;
  for (int kt = 0; kt < nk; ++kt) {
    const int k0 = kt << 5;
    __syncthreads();
#pragma unroll
    for (int q = 0; q < 2; ++q) {
      const int c = t + (q << 8);
      const int r = c >> 2;
      const int cp = (c & 3) << 3;
      const int gk = k0 + cp;
      union { u16 u[8]; short8 v; } ta, tb;
      const int gr = row0 + r;
      if (gr < M && gk + 8 <= K) {
        load8cvt(A + (long)gr * K + gk, ta.u);
      } else {
#pragma unroll
        for (int i = 0; i < 8; ++i) {
          int kk = gk + i;
          ta.u[i] = (gr < M && kk < K) ? to_bf(A[(long)gr * K + kk]) : (u16)0;
        }
      }
      const int gn = col0 + r;
      if (gk + 8 <= K) {
        load8cvt(Bt + (long)gn * K + gk, tb.u);
      } else {
#pragma unroll
        for (int i = 0; i < 8; ++i) {
          int kk = gk + i;
          tb.u[i] = (kk < K) ? Bt[(long)gn * K + kk] : (u16)0;
        }
      }
      *reinterpret_cast<short8*>(&As[r][cp]) = ta.v;
      *reinterpret_cast<short8*>(&Bs[r][cp]) = tb.v;
    }
    __syncthreads();
    short8 af[4], bfr[4];
#pragma unroll
    for (int m = 0; m < 4; ++m)
      af[m] = *reinterpret_cast<const short8*>(&As[(wr << 6) + (m << 4) + lr][lk << 3]);
#pragma unroll
    for (int n = 0; n < 4; ++n)
      bfr[n] = *reinterpret_cast<const short8*>(&Bs[(wc << 6) + (n << 4) + lr][lk << 3]);
#pragma unroll
    for (int m = 0; m < 4; ++m)
#pragma unroll
      for (int n = 0; n < 4; ++n)
        acc[m][n] = __builtin_amdgcn_mfma_f32_16x16x32_bf16(af[m], bfr[n], acc[m][n], 0, 0, 0);
  }
#pragma unroll
  for (int n = 0; n < 4; ++n) {
    const int col = col0 + (wc << 6) + (n << 4) + lr;
    const float bv = BIAS ? bias[col] : 0.0f;
#pragma unroll
    for (int m = 0; m < 4; ++m) {
#pragma unroll
      for (int r = 0; r < 4; ++r) {
        int row = row0 + (wr << 6) + (m << 4) + (lk << 2) + r;
        if (row < M) {
          float x = acc[m][n][r] + bv;
          if (ACT) x = fmaxf(x, 0.0f);
          C[(long)row * N + col] = f2bf(x);
        }
      }
    }
  }
}

// ================= fused per-node attention logits (4 convs) ================
struct EsedArgs {
  const u16* hs[4];
  const u16* hd[4];
  const float* as_[4];
  const float* ad_[4];
  float* es[4];
  float* ed[4];
};

__global__ void __launch_bounds__(128) esed4(EsedArgs ea) {
  const int cv = blockIdx.y;
  const int row = blockIdx.x;
  const int t = threadIdx.x;
  float ps = bf2f(ea.hs[cv][(long)row * HH + t]) * ea.as_[cv][t];
  float pd = bf2f(ea.hd[cv][(long)row * HH + t]) * ea.ad_[cv][t];
#pragma unroll
  for (int o = 32; o > 0; o >>= 1) {
    ps += __shfl_down(ps, o);
    pd += __shfl_down(pd, o);
  }
  __shared__ float s0[2], s1[2];
  if ((t & 63) == 0) { s0[t >> 6] = ps; s1[t >> 6] = pd; }
  __syncthreads();
  if (t == 0) {
    ea.es[cv][row] = s0[0] + s0[1];
    ea.ed[cv][row] = s1[0] + s1[1];
  }
}

// ================= binned counting sort (coalesced CSR build) ===============
struct EdgePtrs {
  const int* dst[4];
  const int* src[4];
};

// S1: per-(conv,chunk) bucket histogram
__global__ void __launch_bounds__(256) sort_count(EdgePtrs ep, int* __restrict__ hist) {
  const int cv = blockIdx.y, ch = blockIdx.x;
  __shared__ int h[NBK];
  for (int i = threadIdx.x; i < NBK; i += 256) h[i] = 0;
  __syncthreads();
  const int* dst = ep.dst[cv];
  const int e0 = ch * CHUNK;
  const int e1 = e0 + CHUNK < EE ? e0 + CHUNK : EE;
  for (int i = e0 + threadIdx.x; i < e1; i += 256) atomicAdd(&h[dst[i] >> 6], 1);
  __syncthreads();
  int* out = hist + ((long)cv * NCH + ch) * NBK;
  for (int i = threadIdx.x; i < NBK; i += 256) out[i] = h[i];
}

// S2: per-conv scan: hist -> per-chunk exclusive prefixes; bucket bases
__global__ void __launch_bounds__(256) sort_scan(int* __restrict__ hist, int* __restrict__ base,
                                                 int* __restrict__ offs_all) {
  const int cv = blockIdx.x;
  int* H = hist + (long)cv * NCH * NBK;
  __shared__ int tot[NBK];
  for (int b = threadIdx.x; b < NBK; b += 256) {
    int run = 0;
    for (int ch = 0; ch < NCH; ++ch) {
      int v = H[ch * NBK + b];
      H[ch * NBK + b] = run;
      run += v;
    }
    tot[b] = run;
  }
  __syncthreads();
  if (threadIdx.x == 0) {
    int* B = base + cv * (NBK + 1);
    int run = 0;
    for (int b = 0; b < NBK; ++b) { B[b] = run; run += tot[b]; }
    B[NBK] = run;
    offs_all[(long)cv * 10001 + 10000] = run;  // sentinel == E
  }
}

// S3: chunk-local bucket sort in LDS, coalesced run-writes of packed (d<<16|s)
__global__ void __launch_bounds__(256) sort_scatter(EdgePtrs ep, const int* __restrict__ hist,
                                                    const int* __restrict__ base,
                                                    unsigned int* __restrict__ binned) {
  const int cv = blockIdx.y, ch = blockIdx.x;
  __shared__ int lcnt[NBK];
  __shared__ int lofs[NBK];
  __shared__ int lcur[NBK];
  __shared__ int sofs[NBK];  // global dest base for this (conv,chunk,bucket)
  __shared__ unsigned int buf[CHUNK];
  for (int i = threadIdx.x; i < NBK; i += 256) lcnt[i] = 0;
  __syncthreads();
  const int* dst = ep.dst[cv];
  const int* src = ep.src[cv];
  const int e0 = ch * CHUNK;
  const int e1 = e0 + CHUNK < EE ? e0 + CHUNK : EE;
  const int n = e1 - e0;
  unsigned int pk[16];
#pragma unroll
  for (int u = 0; u < 16; ++u) {
    int i = e0 + u * 256 + threadIdx.x;
    unsigned int p = 0xFFFFFFFFu;
    if (i < e1) {
      int d = dst[i];
      p = ((unsigned int)d << 16) | (unsigned int)src[i];
      atomicAdd(&lcnt[d >> 6], 1);
    }
    pk[u] = p;
  }
  // load global offsets for this chunk
  {
    const int* chOfs = hist + ((long)cv * NCH + ch) * NBK;
    const int* B = base + cv * (NBK + 1);
    for (int b = threadIdx.x; b < NBK; b += 256) sofs[b] = B[b] + chOfs[b];
  }
  __syncthreads();
  if (threadIdx.x == 0) {
    int run = 0;
    for (int b = 0; b < NBK; ++b) { lofs[b] = run; lcur[b] = run; run += lcnt[b]; }
  }
  __syncthreads();
#pragma unroll
  for (int u = 0; u < 16; ++u) {
    if (pk[u] != 0xFFFFFFFFu) {
      int b = pk[u] >> 22;
      int p = atomicAdd(&lcur[b], 1);
      buf[p] = pk[u];
    }
  }
  __syncthreads();
  unsigned int* outp = binned + (long)cv * EE;
  for (int i = threadIdx.x; i < n; i += 256) {
    unsigned int p = buf[i];
    int b = p >> 22;
    outp[sofs[b] + (i - lofs[b])] = p;
  }
}

// S4: per-bucket dst sort -> final u16 src lists in CSR order + offs
__global__ void __launch_bounds__(256) sort_bucket(const unsigned int* __restrict__ binned,
                                                   const int* __restrict__ base,
                                                   int* __restrict__ offs_all,
                                                   u16* __restrict__ srcs) {
  const int cv = blockIdx.y, b = blockIdx.x;
  const int* B = base + cv * (NBK + 1);
  const int s0 = B[b], s1 = B[b + 1];
  int n = s1 - s0;
  if (n > MAXB) n = MAXB;  // impossible for uniform-random dst; safety clamp
  __shared__ unsigned int buf[MAXB];
  __shared__ u16 obuf[MAXB];
  __shared__ int cnt[64], dofs[64], dcur[64];
  if (threadIdx.x < 64) cnt[threadIdx.x] = 0;
  __syncthreads();
  const unsigned int* inp = binned + (long)cv * EE + s0;
  for (int i = threadIdx.x; i < n; i += 256) {
    unsigned int p = inp[i];
    buf[i] = p;
    atomicAdd(&cnt[(p >> 16) & 63], 1);
  }
  __syncthreads();
  if (threadIdx.x == 0) {
    int run = 0;
    for (int i = 0; i < 64; ++i) { dofs[i] = run; dcur[i] = run; run += cnt[i]; }
  }
  __syncthreads();
  if (threadIdx.x < 64) {
    int d = (b << 6) + threadIdx.x;
    if (d < 10000) offs_all[(long)cv * 10001 + d] = s0 + dofs[threadIdx.x];
  }
  for (int i = threadIdx.x; i < n; i += 256) {
    unsigned int p = buf[i];
    int pos = atomicAdd(&dcur[(p >> 16) & 63], 1);
    obuf[pos] = (u16)(p & 0xFFFFu);
  }
  __syncthreads();
  u16* outp = srcs + (long)cv * EE + s0;
  for (int i = threadIdx.x; i < n; i += 256) outp[i] = obuf[i];
}

// ================= fused GAT: softmax + accumulate + bias + relu + out ======
struct GatArgs {
  const int* offs[4];
  const u16* srcs[4];
  const float* es[4];
  const float* ed[4];
  const u16* hs[4];
  const float* bias[4];
};

#define GCAP 2048
__global__ void __launch_bounds__(128) gat2(GatArgs ga, float* __restrict__ out,
                                            u16* __restrict__ feat, float* __restrict__ exfall) {
  const int d = blockIdx.x;
  const int half = blockIdx.y;  // 0: drug (convs 0,1)  1: target (convs 2,3)
  const int t = threadIdx.x;
  __shared__ float al[GCAP];
  __shared__ u16 sl[GCAP];
  __shared__ float red[2];
  float a = 0.f;
#pragma unroll
  for (int q = 0; q < 2; ++q) {
    const int cv = half * 2 + q;
    const int* offs = ga.offs[cv];
    const int o0 = offs[d], o1 = offs[d + 1];
    const int deg = o1 - o0;
    const u16* sp = ga.srcs[cv] + o0;
    const float* es = ga.es[cv];
    const float edd = ga.ed[cv][d];
    const u16* hs = ga.hs[cv];
    const int degc = deg > GCAP ? GCAP : deg;
    __syncthreads();  // al/sl/red free from previous q
    float part = 0.f;
    for (int j = t; j < degc; j += 128) {
      int s = sp[j];
      float e = es[s] + edd;
      e = e > 0.f ? e : 0.2f * e;
      float ex = __expf(e);
      al[j] = ex;
      sl[j] = (u16)s;
      part += ex;
    }
    for (int j = GCAP + t; j < deg; j += 128) {  // cold path, never taken for this data
      int s = sp[j];
      float e = es[s] + edd;
      e = e > 0.f ? e : 0.2f * e;
      float ex = __expf(e);
      exfall[(long)cv * EE + o0 + j] = ex;
      part += ex;
    }
#pragma unroll
    for (int o = 32; o > 0; o >>= 1) part += __shfl_down(part, o);
    if ((t & 63) == 0) red[t >> 6] = part;
    __syncthreads();
    const float inv = 1.0f / (red[0] + red[1] + 1e-16f);
#pragma unroll 4
    for (int j = 0; j < degc; ++j) {
      a += al[j] * inv * bf2f(hs[(long)sl[j] * HH + t]);
    }
    for (int j = GCAP; j < deg; ++j) {
      int s = sp[j];
      a += exfall[(long)cv * EE + o0 + j] * inv * bf2f(hs[(long)s * HH + t]);
    }
  }
  const float* b1 = ga.bias[half * 2];
  const float* b2 = ga.bias[half * 2 + 1];
  float v = fmaxf(a + b1[t] + b2[t], 0.0f);
  out[16384 + (long)half * ND * HH + (long)d * HH + t] = v;
  if (half == 0) feat[(long)d * HH + t] = f2bf(v);
}

// ================= row L2-normalize -> bf16 ================================
template <typename T>
__global__ void __launch_bounds__(256) rownorm_kernel(const T* __restrict__ X,
                                                      u16* __restrict__ Y, int K) {
  const int row = blockIdx.x;
  const int t = threadIdx.x;
  const T* xr = X + (long)row * K;
  float ss = 0.f;
  for (int k = t; k < K; k += 256) {
    float v = ldval(xr[k]);
    ss += v * v;
  }
#pragma unroll
  for (int o = 32; o > 0; o >>= 1) ss += __shfl_down(ss, o);
  __shared__ float sh[4];
  if ((t & 63) == 0) sh[t >> 6] = ss;
  __syncthreads();
  float tot = sh[0] + sh[1] + sh[2] + sh[3];
  float inv = 1.0f / fmaxf(sqrtf(tot), 1e-12f);
  u16* yr = Y + (long)row * K;
  for (int k = t; k < K; k += 256) yr[k] = f2bf(ldval(xr[k]) * inv);
}

// ================= hidden = [feat[id1], feat[id2], cell] ====================
__global__ void __launch_bounds__(256) build_hidden_kernel(const u16* __restrict__ feat,
                                                           const int* __restrict__ id1,
                                                           const int* __restrict__ id2,
                                                           const u16* __restrict__ cell,
                                                           u16* __restrict__ hidden) {
  int i = blockIdx.x * 256 + threadIdx.x;
  int row = i >> 9, col = i & 511;
  u16 v;
  if (col < 128) v = feat[(long)id1[row] * HH + col];
  else if (col < 256) v = feat[(long)id2[row] * HH + (col - 128)];
  else v = cell[(long)row * 256 + (col - 256)];
  hidden[i] = v;
}

// ================= logits: [B,128] @ [128,2] + b -> fp32 ====================
__global__ void __launch_bounds__(128) logits_kernel(const u16* __restrict__ h2,
                                                     const float* __restrict__ W,
                                                     const float* __restrict__ b,
                                                     float* __restrict__ out) {
  const int row = blockIdx.x;
  const int t = threadIdx.x;
  float hv = bf2f(h2[(long)row * HH + t]);
  float p0 = hv * W[2 * t], p1 = hv * W[2 * t + 1];
#pragma unroll
  for (int o = 32; o > 0; o >>= 1) {
    p0 += __shfl_down(p0, o);
    p1 += __shfl_down(p1, o);
  }
  __shared__ float sA[2], sB[2];
  if ((t & 63) == 0) { sA[t >> 6] = p0; sB[t >> 6] = p1; }
  __syncthreads();
  if (t == 0) {
    out[2 * row] = sA[0] + sA[1] + b[0];
    out[2 * row + 1] = sB[0] + sB[1] + b[1];
  }
}

extern "C" void kernel_launch(void* const* d_in, const int* in_sizes, int n_in,
                              void* d_out, int out_size, void* d_ws, size_t ws_size,
                              hipStream_t stream) {
  const float* x_drug = (const float*)d_in[0];
  const float* x_target = (const float*)d_in[1];
  const float* cellf = (const float*)d_in[2];
  const float* dd_W = (const float*)d_in[3];
  const float* dd_as = (const float*)d_in[4];
  const float* dd_ad = (const float*)d_in[5];
  const float* dd_b = (const float*)d_in[6];
  const float* dt_Ws = (const float*)d_in[7];
  const float* dt_Wd = (const float*)d_in[8];
  const float* dt_as = (const float*)d_in[9];
  const float* dt_ad = (const float*)d_in[10];
  const float* dt_b = (const float*)d_in[11];
  const float* td_Ws = (const float*)d_in[12];
  const float* td_Wd = (const float*)d_in[13];
  const float* td_as = (const float*)d_in[14];
  const float* td_ad = (const float*)d_in[15];
  const float* td_b = (const float*)d_in[16];
  const float* tt_W = (const float*)d_in[17];
  const float* tt_as = (const float*)d_in[18];
  const float* tt_ad = (const float*)d_in[19];
  const float* tt_b = (const float*)d_in[20];
  const float* r1_W1 = (const float*)d_in[21];
  const float* r1_b1 = (const float*)d_in[22];
  const float* r1_W2 = (const float*)d_in[23];
  const float* r1_b2 = (const float*)d_in[24];
  const float* r1_W3 = (const float*)d_in[25];
  const float* r1_b3 = (const float*)d_in[26];
  const float* r2_W1 = (const float*)d_in[27];
  const float* r2_b1 = (const float*)d_in[28];
  const float* r2_W2 = (const float*)d_in[29];
  const float* r2_b2 = (const float*)d_in[30];
  const float* r2_W3 = (const float*)d_in[31];
  const float* r2_b3 = (const float*)d_in[32];
  const float* cls_W = (const float*)d_in[33];
  const float* cls_b = (const float*)d_in[34];
  const int* src_dd = (const int*)d_in[35];
  const int* dst_dd = (const int*)d_in[36];
  const int* src_dt = (const int*)d_in[37];
  const int* dst_dt = (const int*)d_in[38];
  const int* src_td = (const int*)d_in[39];
  const int* dst_td = (const int*)d_in[40];
  const int* src_tt = (const int*)d_in[41];
  const int* dst_tt = (const int*)d_in[42];
  const int* drug1 = (const int*)d_in[43];
  const int* drug2 = (const int*)d_in[44];
  float* out = (float*)d_out;

  char* ws = (char*)d_ws;
  size_t cur = 0;
  auto alloc = [&](size_t b) {
    size_t r = cur;
    cur += (b + 255) & ~(size_t)255;
    return r;
  };

  u16* wt_dd = (u16*)(ws + alloc((size_t)DF * HH * 2));
  u16* wt_tds = (u16*)(ws + alloc((size_t)TFD * HH * 2));
  u16* wt_tdd = (u16*)(ws + alloc((size_t)DF * HH * 2));
  u16* wt_dts = (u16*)(ws + alloc((size_t)DF * HH * 2));
  u16* wt_dtd = (u16*)(ws + alloc((size_t)TFD * HH * 2));
  u16* wt_tt = (u16*)(ws + alloc((size_t)TFD * HH * 2));
  u16* wt1 = (u16*)(ws + alloc((size_t)P1C * CF * 2));
  u16* wt2 = (u16*)(ws + alloc((size_t)P2C * P1C * 2));
  u16* wt3 = (u16*)(ws + alloc((size_t)256 * P2C * 2));
  u16* wt4 = (u16*)(ws + alloc((size_t)P1C * 512 * 2));
  u16* wt5 = (u16*)(ws + alloc((size_t)P2C * P1C * 2));
  u16* wt6 = (u16*)(ws + alloc((size_t)HH * P2C * 2));
  u16* h_dd = (u16*)(ws + alloc((size_t)ND * HH * 2));
  u16* h_tds = (u16*)(ws + alloc((size_t)NT_ * HH * 2));
  u16* h_tdd = (u16*)(ws + alloc((size_t)ND * HH * 2));
  u16* h_dts = (u16*)(ws + alloc((size_t)ND * HH * 2));
  u16* h_dtd = (u16*)(ws + alloc((size_t)NT_ * HH * 2));
  u16* h_tt = (u16*)(ws + alloc((size_t)NT_ * HH * 2));
  float* es0 = (float*)(ws + alloc(ND * 4));
  float* ed0 = (float*)(ws + alloc(ND * 4));
  float* es1 = (float*)(ws + alloc(NT_ * 4));
  float* ed1 = (float*)(ws + alloc(ND * 4));
  float* es2 = (float*)(ws + alloc(ND * 4));
  float* ed2 = (float*)(ws + alloc(NT_ * 4));
  float* es3 = (float*)(ws + alloc(NT_ * 4));
  float* ed3 = (float*)(ws + alloc(NT_ * 4));
  int* hist = (int*)(ws + alloc((size_t)4 * NCH * NBK * 4));
  int* base = (int*)(ws + alloc((size_t)4 * (NBK + 1) * 4));
  int* offs_all = (int*)(ws + alloc((size_t)4 * 10001 * 4));
  unsigned int* binned = (unsigned int*)(ws + alloc((size_t)4 * EE * 4));
  u16* srcs = (u16*)(ws + alloc((size_t)4 * EE * 2));
  float* exfall = (float*)(ws + alloc((size_t)4 * EE * 4));
  u16* feat = (u16*)(ws + alloc((size_t)ND * HH * 2));
  u16* cellnorm = (u16*)(ws + alloc((size_t)BB * CF * 2));
  u16* big = (u16*)(ws + alloc((size_t)BB * P1C * 2));
  u16* mid = (u16*)(ws + alloc((size_t)BB * P2C * 2));
  u16* cellout = (u16*)(ws + alloc((size_t)BB * 256 * 2));
  u16* hidden = (u16*)(ws + alloc((size_t)BB * 512 * 2));
  u16* hiddennorm = (u16*)(ws + alloc((size_t)BB * 512 * 2));
  u16* h2 = (u16*)(ws + alloc((size_t)BB * HH * 2));

  // ---- fused transposes (12) ----
  TransArgs ta;
  const float* tw[12] = {dd_W, td_Ws, td_Wd, dt_Ws, dt_Wd, tt_W, r1_W1, r1_W2, r1_W3, r2_W1, r2_W2, r2_W3};
  u16* twt[12] = {wt_dd, wt_tds, wt_tdd, wt_dts, wt_dtd, wt_tt, wt1, wt2, wt3, wt4, wt5, wt6};
  int tk_[12] = {DF, TFD, DF, DF, TFD, TFD, CF, P1C, P2C, 512, P1C, P2C};
  int tn_[12] = {HH, HH, HH, HH, HH, HH, P1C, P2C, 256, P1C, P2C, HH};
  for (int i = 0; i < 12; ++i) { ta.W[i] = tw[i]; ta.Wt[i] = twt[i]; ta.K[i] = tk_[i]; ta.N[i] = tn_[i]; }
  transpose_all<<<dim3(1920, 12), dim3(32, 8), 0, stream>>>(ta);

  // ---- fused node GEMMs (6) ----
  Gemm6Args g6;
  const float* ga_[6] = {x_drug, x_target, x_drug, x_drug, x_target, x_target};
  const u16* gb_[6] = {wt_dd, wt_tds, wt_tdd, wt_dts, wt_dtd, wt_tt};
  u16* gc_[6] = {h_dd, h_tds, h_tdd, h_dts, h_dtd, h_tt};
  for (int i = 0; i < 6; ++i) { g6.A[i] = ga_[i]; g6.B[i] = gb_[i]; g6.C[i] = gc_[i]; }
  gemm6<<<dim3((ND + 127) / 128, 6), 256, 0, stream>>>(g6);

  // ---- fused attention logits (4 convs) ----
  EsedArgs ea;
  const u16* ehs[4] = {h_dd, h_tds, h_dts, h_tt};
  const u16* ehd[4] = {h_dd, h_tdd, h_dtd, h_tt};
  const float* eas[4] = {dd_as, td_as, dt_as, tt_as};
  const float* ead[4] = {dd_ad, td_ad, dt_ad, tt_ad};
  float* ees[4] = {es0, es1, es2, es3};
  float* eed[4] = {ed0, ed1, ed2, ed3};
  for (int i = 0; i < 4; ++i) {
    ea.hs[i] = ehs[i]; ea.hd[i] = ehd[i]; ea.as_[i] = eas[i]; ea.ad_[i] = ead[i];
    ea.es[i] = ees[i]; ea.ed[i] = eed[i];
  }
  esed4<<<dim3(10000, 4), 128, 0, stream>>>(ea);

  // ---- binned counting sort -> CSR (conv order: 0=dd, 1=td, 2=dt, 3=tt) ----
  EdgePtrs ep;
  ep.dst[0] = dst_dd; ep.dst[1] = dst_td; ep.dst[2] = dst_dt; ep.dst[3] = dst_tt;
  ep.src[0] = src_dd; ep.src[1] = src_td; ep.src[2] = src_dt; ep.src[3] = src_tt;
  sort_count<<<dim3(NCH, 4), 256, 0, stream>>>(ep, hist);
  sort_scan<<<4, 256, 0, stream>>>(hist, base, offs_all);
  sort_scatter<<<dim3(NCH, 4), 256, 0, stream>>>(ep, hist, base, binned);
  sort_bucket<<<dim3(NBK, 4), 256, 0, stream>>>(binned, base, offs_all, srcs);

  // ---- fused GAT (softmax + accumulate + bias + relu + output) ----
  GatArgs gaa;
  const u16* ghs[4] = {h_dd, h_tds, h_dts, h_tt};
  const float* gbias[4] = {dd_b, td_b, dt_b, tt_b};
  for (int i = 0; i < 4; ++i) {
    gaa.offs[i] = offs_all + (long)i * 10001;
    gaa.srcs[i] = srcs + (long)i * EE;
    gaa.es[i] = ees[i];
    gaa.ed[i] = eed[i];
    gaa.hs[i] = ghs[i];
    gaa.bias[i] = gbias[i];
  }
  gat2<<<dim3(10000, 2), 128, 0, stream>>>(gaa, out, feat, exfall);

  // ---- MLP chain ----
  rownorm_kernel<float><<<BB, 256, 0, stream>>>(cellf, cellnorm, CF);
  gemm_bt<u16, 1, 1><<<(BB / 128) * (P1C / 128), 256, 0, stream>>>(cellnorm, wt1, r1_b1, big, BB, P1C, CF);
  gemm_bt<u16, 1, 1><<<(BB / 128) * (P2C / 128), 256, 0, stream>>>(big, wt2, r1_b2, mid, BB, P2C, P1C);
  gemm_bt<u16, 1, 1><<<(BB / 128) * (256 / 128), 256, 0, stream>>>(mid, wt3, r1_b3, cellout, BB, 256, P2C);
  build_hidden_kernel<<<BB * 512 / 256, 256, 0, stream>>>(feat, drug1, drug2, cellout, hidden);
  rownorm_kernel<u16><<<BB, 256, 0, stream>>>(hidden, hiddennorm, 512);
  gemm_bt<u16, 1, 1><<<(BB / 128) * (P1C / 128), 256, 0, stream>>>(hiddennorm, wt4, r2_b1, big, BB, P1C, 512);
  gemm_bt<u16, 1, 1><<<(BB / 128) * (P2C / 128), 256, 0, stream>>>(big, wt5, r2_b2, mid, BB, P2C, P1C);
  gemm_bt<u16, 1, 1><<<(BB / 128) * (HH / 128), 256, 0, stream>>>(mid, wt6, r2_b3, h2, BB, HH, P2C);
  logits_kernel<<<BB, 128, 0, stream>>>(h2, cls_W, cls_b, out);
}

// Round 4
// 431.475 us; speedup vs baseline: 2.3913x; 1.2942x over previous
//
#include <hip/hip_runtime.h>

// Problem constants (fixed by the reference)
#define ND 10000
#define NT_ 10000
#define EE 500000
#define BB 8192
#define DF 256
#define TFD 256
#define HH 128
#define CF 954
#define CFP 960   // padded K for MFMA (zero-filled)
#define P1C 2048
#define P2C 512
#define MPAD 10112  // ND padded to multiple of 128

// sort constants
#define CHUNK 4096
#define NCH 123
#define NBK 157
#define MAXB 6144
#define GCAP 384   // max degree ~89 (Binomial(5e5,1e-4)); 384 is huge margin

typedef unsigned short u16;
typedef __attribute__((ext_vector_type(8))) short short8;
typedef __attribute__((ext_vector_type(4))) float f4;

#define AS1 __attribute__((address_space(1)))
#define AS3 __attribute__((address_space(3)))
#define GLOAD16(g, l) \
  __builtin_amdgcn_global_load_lds((const AS1 void*)(g), (AS3 void*)(l), 16, 0, 0)

__device__ inline u16 f2bf(float f) {
  unsigned int u = __builtin_bit_cast(unsigned int, f);
  unsigned int r = (u + 0x7FFFu + ((u >> 16) & 1u)) >> 16;
  return (u16)r;
}
__device__ inline float bf2f(u16 b) {
  return __builtin_bit_cast(float, ((unsigned int)b) << 16);
}
__device__ inline float ldval(float v) { return v; }
__device__ inline float ldval(u16 v) { return bf2f(v); }

__device__ inline void load8cvt(const float* p, u16* dst) {
#pragma unroll
  for (int i = 0; i < 4; ++i) {
    float2 v = reinterpret_cast<const float2*>(p)[i];
    dst[2 * i] = f2bf(v.x);
    dst[2 * i + 1] = f2bf(v.y);
  }
}

// ============ x fp32 -> bf16, rows padded to MPAD with zeros ================
__global__ void __launch_bounds__(256) xcvt_kernel(const float* __restrict__ xd,
                                                   const float* __restrict__ xt,
                                                   u16* __restrict__ xdb,
                                                   u16* __restrict__ xtb) {
  const float* X = blockIdx.y ? xt : xd;
  u16* Y = blockIdx.y ? xtb : xdb;
  long i = (long)blockIdx.x * 256 + threadIdx.x;  // one 8-elem chunk each
  long e = i * 8;
  int row = (int)(e >> 8);
  union { u16 u[8]; short8 v; } tv;
  if (row < ND) {
    load8cvt(X + e, tv.u);
  } else {
#pragma unroll
    for (int k = 0; k < 8; ++k) tv.u[k] = 0;
  }
  *reinterpret_cast<short8*>(Y + e) = tv.v;
}

// ============ fused weight transpose: fp32 [K,N] -> bf16 [N,Kp] (zero pad) ==
struct TransArgs {
  const float* W[12];
  u16* Wt[12];
  int K[12];
  int N[12];
  int Kp[12];
};

__global__ void __launch_bounds__(256) transpose_all(TransArgs ta) {
  const int id = blockIdx.y;
  const int K = ta.K[id], N = ta.N[id], Kp = ta.Kp[id];
  const int tn = (N + 31) >> 5, tk = (Kp + 31) >> 5;
  if ((int)blockIdx.x >= tn * tk) return;
  const float* W = ta.W[id];
  u16* Wt = ta.Wt[id];
  const int bn = (blockIdx.x % tn) << 5;
  const int bk = (blockIdx.x / tn) << 5;
  __shared__ u16 tile[32][33];
  const int tx = threadIdx.x;
  const int ty = threadIdx.y;
#pragma unroll
  for (int i = ty; i < 32; i += 8) {
    int k = bk + i, n = bn + tx;
    tile[i][tx] = (k < K && n < N) ? f2bf(W[(long)k * N + n]) : (u16)0;
  }
  __syncthreads();
#pragma unroll
  for (int i = ty; i < 32; i += 8) {
    int n = bn + i, k = bk + tx;
    if (n < N && k < Kp) Wt[(long)n * Kp + k] = tile[tx][i];
  }
}

// ============ m97-structure bf16 GEMM: global_load_lds + LDS-staged C =======
// C[M,N] = act(A[M,K] @ Bt[N,K]^T + bias).  M%128==0, N%128==0, K%32==0.
template <int ACT, int BIAS>
__global__ void __launch_bounds__(256) gemm_a16(const u16* __restrict__ A,
                                                const u16* __restrict__ Bt,
                                                const float* __restrict__ bias,
                                                u16* __restrict__ C, int M, int N, int K) {
  const int tiles_n = N >> 7;
  const int bm = blockIdx.x / tiles_n;
  const int bn = blockIdx.x % tiles_n;
  const long row0 = (long)bm << 7;
  const int col0 = bn << 7;
  __shared__ u16 As[128 * 32];
  __shared__ u16 Bs[128 * 32];
  const int t = threadIdx.x;
  const int lane = t & 63;
  const int w = t >> 6;
  const int wr = w >> 1, wc = w & 1;
  const int lr = lane & 15, lk = lane >> 4;
  // staging: chunk c covers tile rows [16c,16c+16); lane l -> row 16c+(l>>2),
  // col (l&3)*8 -> LDS offset within chunk = l*16B exactly (linear match).
  const int srow = lane >> 2;
  const int scol = (lane & 3) << 3;
  const u16* gA = A + (row0 + (w << 4) + srow) * K + scol;
  const u16* gA2 = A + (row0 + ((w + 4) << 4) + srow) * K + scol;
  const u16* gB = Bt + ((long)col0 + (w << 4) + srow) * K + scol;
  const u16* gB2 = Bt + ((long)col0 + ((w + 4) << 4) + srow) * K + scol;
  u16* lA = &As[(w << 4) * 32];
  u16* lA2 = &As[((w + 4) << 4) * 32];
  u16* lB = &Bs[(w << 4) * 32];
  u16* lB2 = &Bs[((w + 4) << 4) * 32];
  f4 acc[4][4] = {};
  const int nk = K >> 5;
  for (int kt = 0; kt < nk; ++kt) {
    __syncthreads();
    GLOAD16(gA, lA);
    GLOAD16(gA2, lA2);
    GLOAD16(gB, lB);
    GLOAD16(gB2, lB2);
    gA += 32; gA2 += 32; gB += 32; gB2 += 32;
    __syncthreads();
    short8 af[4], bf[4];
#pragma unroll
    for (int m = 0; m < 4; ++m)
      af[m] = *reinterpret_cast<const short8*>(&As[(((wr << 6) + (m << 4) + lr) << 5) + (lk << 3)]);
#pragma unroll
    for (int n = 0; n < 4; ++n)
      bf[n] = *reinterpret_cast<const short8*>(&Bs[(((wc << 6) + (n << 4) + lr) << 5) + (lk << 3)]);
#pragma unroll
    for (int m = 0; m < 4; ++m)
#pragma unroll
      for (int n = 0; n < 4; ++n)
        acc[m][n] = __builtin_amdgcn_mfma_f32_16x16x32_bf16(af[m], bf[n], acc[m][n], 0, 0, 0);
  }
  // ---- epilogue: stage 32-row groups through LDS for coalesced 16B stores --
  float bv[4];
#pragma unroll
  for (int n = 0; n < 4; ++n)
    bv[n] = BIAS ? bias[col0 + (wc << 6) + (n << 4) + lr] : 0.0f;
  __syncthreads();
  u16* Cs = As;  // reuse 8KB (32 rows x 128 cols)
  for (int g = 0; g < 4; ++g) {
    if (wr == (g >> 1)) {
#pragma unroll
      for (int mm = 0; mm < 2; ++mm) {
        const int m = ((g & 1) << 1) + mm;
#pragma unroll
        for (int n = 0; n < 4; ++n) {
#pragma unroll
          for (int r = 0; r < 4; ++r) {
            float x = acc[m][n][r] + bv[n];
            if (ACT) x = fmaxf(x, 0.0f);
            Cs[(((mm << 4) + (lk << 2) + r) << 7) + (wc << 6) + (n << 4) + lr] = f2bf(x);
          }
        }
      }
    }
    __syncthreads();
#pragma unroll
    for (int it = 0; it < 2; ++it) {
      const int c = t + (it << 8);  // 0..511 chunks of 16B
      const int rr = c >> 4, off = (c & 15) << 3;
      *reinterpret_cast<short8*>(&C[(row0 + (g << 5) + rr) * N + col0 + off]) =
          *reinterpret_cast<const short8*>(&Cs[(rr << 7) + off]);
    }
    __syncthreads();
  }
}

// ============ fused per-node attention logits (4 convs, h stride 384) =======
struct EsedArgs {
  const u16* hs[4];
  const u16* hd[4];
  const float* as_[4];
  const float* ad_[4];
  float* es[4];
  float* ed[4];
};

__global__ void __launch_bounds__(128) esed4(EsedArgs ea) {
  const int cv = blockIdx.y;
  const int row = blockIdx.x;
  const int t = threadIdx.x;
  float ps = bf2f(ea.hs[cv][(long)row * 384 + t]) * ea.as_[cv][t];
  float pd = bf2f(ea.hd[cv][(long)row * 384 + t]) * ea.ad_[cv][t];
#pragma unroll
  for (int o = 32; o > 0; o >>= 1) {
    ps += __shfl_down(ps, o);
    pd += __shfl_down(pd, o);
  }
  __shared__ float s0[2], s1[2];
  if ((t & 63) == 0) { s0[t >> 6] = ps; s1[t >> 6] = pd; }
  __syncthreads();
  if (t == 0) {
    ea.es[cv][row] = s0[0] + s0[1];
    ea.ed[cv][row] = s1[0] + s1[1];
  }
}

// ============ binned counting sort (coalesced CSR build) ====================
struct EdgePtrs {
  const int* dst[4];
  const int* src[4];
};

__global__ void __launch_bounds__(256) sort_count(EdgePtrs ep, int* __restrict__ hist) {
  const int cv = blockIdx.y, ch = blockIdx.x;
  __shared__ int h[NBK];
  for (int i = threadIdx.x; i < NBK; i += 256) h[i] = 0;
  __syncthreads();
  const int* dst = ep.dst[cv];
  const int e0 = ch * CHUNK;
  const int e1 = e0 + CHUNK < EE ? e0 + CHUNK : EE;
  for (int i = e0 + threadIdx.x; i < e1; i += 256) atomicAdd(&h[dst[i] >> 6], 1);
  __syncthreads();
  int* out = hist + ((long)cv * NCH + ch) * NBK;
  for (int i = threadIdx.x; i < NBK; i += 256) out[i] = h[i];
}

__global__ void __launch_bounds__(256) sort_scan(int* __restrict__ hist, int* __restrict__ base,
                                                 int* __restrict__ offs_all) {
  const int cv = blockIdx.x;
  int* H = hist + (long)cv * NCH * NBK;
  __shared__ int tot[NBK];
  for (int b = threadIdx.x; b < NBK; b += 256) {
    int run = 0;
    for (int ch = 0; ch < NCH; ++ch) {
      int v = H[ch * NBK + b];
      H[ch * NBK + b] = run;
      run += v;
    }
    tot[b] = run;
  }
  __syncthreads();
  if (threadIdx.x == 0) {
    int* B = base + cv * (NBK + 1);
    int run = 0;
    for (int b = 0; b < NBK; ++b) { B[b] = run; run += tot[b]; }
    B[NBK] = run;
    offs_all[(long)cv * 10001 + 10000] = run;
  }
}

__global__ void __launch_bounds__(256) sort_scatter(EdgePtrs ep, const int* __restrict__ hist,
                                                    const int* __restrict__ base,
                                                    unsigned int* __restrict__ binned) {
  const int cv = blockIdx.y, ch = blockIdx.x;
  __shared__ int lcnt[NBK];
  __shared__ int lofs[NBK];
  __shared__ int lcur[NBK];
  __shared__ int sofs[NBK];
  __shared__ unsigned int buf[CHUNK];
  for (int i = threadIdx.x; i < NBK; i += 256) lcnt[i] = 0;
  __syncthreads();
  const int* dst = ep.dst[cv];
  const int* src = ep.src[cv];
  const int e0 = ch * CHUNK;
  const int e1 = e0 + CHUNK < EE ? e0 + CHUNK : EE;
  const int n = e1 - e0;
  unsigned int pk[16];
#pragma unroll
  for (int u = 0; u < 16; ++u) {
    int i = e0 + u * 256 + threadIdx.x;
    unsigned int p = 0xFFFFFFFFu;
    if (i < e1) {
      int d = dst[i];
      p = ((unsigned int)d << 16) | (unsigned int)src[i];
      atomicAdd(&lcnt[d >> 6], 1);
    }
    pk[u] = p;
  }
  {
    const int* chOfs = hist + ((long)cv * NCH + ch) * NBK;
    const int* B = base + cv * (NBK + 1);
    for (int b = threadIdx.x; b < NBK; b += 256) sofs[b] = B[b] + chOfs[b];
  }
  __syncthreads();
  if (threadIdx.x == 0) {
    int run = 0;
    for (int b = 0; b < NBK; ++b) { lofs[b] = run; lcur[b] = run; run += lcnt[b]; }
  }
  __syncthreads();
#pragma unroll
  for (int u = 0; u < 16; ++u) {
    if (pk[u] != 0xFFFFFFFFu) {
      int b = pk[u] >> 22;
      int p = atomicAdd(&lcur[b], 1);
      buf[p] = pk[u];
    }
  }
  __syncthreads();
  unsigned int* outp = binned + (long)cv * EE;
  for (int i = threadIdx.x; i < n; i += 256) {
    unsigned int p = buf[i];
    int b = p >> 22;
    outp[sofs[b] + (i - lofs[b])] = p;
  }
}

__global__ void __launch_bounds__(256) sort_bucket(const unsigned int* __restrict__ binned,
                                                   const int* __restrict__ base,
                                                   int* __restrict__ offs_all,
                                                   u16* __restrict__ srcs) {
  const int cv = blockIdx.y, b = blockIdx.x;
  const int* B = base + cv * (NBK + 1);
  const int s0 = B[b], s1 = B[b + 1];
  int n = s1 - s0;
  if (n > MAXB) n = MAXB;
  __shared__ unsigned int buf[MAXB];
  __shared__ u16 obuf[MAXB];
  __shared__ int cnt[64], dofs[64], dcur[64];
  if (threadIdx.x < 64) cnt[threadIdx.x] = 0;
  __syncthreads();
  const unsigned int* inp = binned + (long)cv * EE + s0;
  for (int i = threadIdx.x; i < n; i += 256) {
    unsigned int p = inp[i];
    buf[i] = p;
    atomicAdd(&cnt[(p >> 16) & 63], 1);
  }
  __syncthreads();
  if (threadIdx.x == 0) {
    int run = 0;
    for (int i = 0; i < 64; ++i) { dofs[i] = run; dcur[i] = run; run += cnt[i]; }
  }
  __syncthreads();
  if (threadIdx.x < 64) {
    int d = (b << 6) + threadIdx.x;
    if (d < 10000) offs_all[(long)cv * 10001 + d] = s0 + dofs[threadIdx.x];
  }
  for (int i = threadIdx.x; i < n; i += 256) {
    unsigned int p = buf[i];
    int pos = atomicAdd(&dcur[(p >> 16) & 63], 1);
    obuf[pos] = (u16)(p & 0xFFFFu);
  }
  __syncthreads();
  u16* outp = srcs + (long)cv * EE + s0;
  for (int i = threadIdx.x; i < n; i += 256) outp[i] = obuf[i];
}

// ============ fused GAT: softmax + accumulate + bias + relu + out ===========
struct GatArgs {
  const int* offs[4];
  const u16* srcs[4];
  const float* es[4];
  const float* ed[4];
  const u16* hs[4];   // stride 384
  const float* bias[4];
};

__global__ void __launch_bounds__(128) gat2(GatArgs ga, float* __restrict__ out,
                                            u16* __restrict__ feat) {
  const int d = blockIdx.x;
  const int half = blockIdx.y;  // 0: drug (convs 0,1)  1: target (convs 2,3)
  const int t = threadIdx.x;
  __shared__ float al[GCAP];
  __shared__ u16 sl[GCAP];
  __shared__ float red[2];
  float a = 0.f;
#pragma unroll
  for (int q = 0; q < 2; ++q) {
    const int cv = half * 2 + q;
    const int* offs = ga.offs[cv];
    const int o0 = offs[d], o1 = offs[d + 1];
    const int deg = o1 - o0;
    const u16* sp = ga.srcs[cv] + o0;
    const float* es = ga.es[cv];
    const float edd = ga.ed[cv][d];
    const u16* hs = ga.hs[cv];
    const int degc = deg > GCAP ? GCAP : deg;
    __syncthreads();
    float part = 0.f;
    for (int j = t; j < degc; j += 128) {
      int s = sp[j];
      float e = es[s] + edd;
      e = e > 0.f ? e : 0.2f * e;
      float ex = __expf(e);
      al[j] = ex;
      sl[j] = (u16)s;
      part += ex;
    }
    for (int j = GCAP + t; j < deg; j += 128) {  // never taken for this data
      float e = es[sp[j]] + edd;
      e = e > 0.f ? e : 0.2f * e;
      part += __expf(e);
    }
#pragma unroll
    for (int o = 32; o > 0; o >>= 1) part += __shfl_down(part, o);
    if ((t & 63) == 0) red[t >> 6] = part;
    __syncthreads();
    const float inv = 1.0f / (red[0] + red[1] + 1e-16f);
#pragma unroll 4
    for (int j = 0; j < degc; ++j) {
      a += al[j] * inv * bf2f(hs[(long)sl[j] * 384 + t]);
    }
    for (int j = GCAP; j < deg; ++j) {  // never taken
      float e = es[sp[j]] + edd;
      e = e > 0.f ? e : 0.2f * e;
      a += __expf(e) * inv * bf2f(hs[(long)sp[j] * 384 + t]);
    }
  }
  const float* b1 = ga.bias[half * 2];
  const float* b2 = ga.bias[half * 2 + 1];
  float v = fmaxf(a + b1[t] + b2[t], 0.0f);
  out[16384 + (long)half * ND * HH + (long)d * HH + t] = v;
  if (half == 0) feat[(long)d * HH + t] = f2bf(v);
}

// ============ row L2-normalize -> bf16 (with zero pad to Kout) ==============
template <typename T>
__global__ void __launch_bounds__(256) rownorm_kernel(const T* __restrict__ X,
                                                      u16* __restrict__ Y, int Kin, int Kout) {
  const int row = blockIdx.x;
  const int t = threadIdx.x;
  const T* xr = X + (long)row * Kin;
  float ss = 0.f;
  for (int k = t; k < Kin; k += 256) {
    float v = ldval(xr[k]);
    ss += v * v;
  }
#pragma unroll
  for (int o = 32; o > 0; o >>= 1) ss += __shfl_down(ss, o);
  __shared__ float sh[4];
  if ((t & 63) == 0) sh[t >> 6] = ss;
  __syncthreads();
  float tot = sh[0] + sh[1] + sh[2] + sh[3];
  float inv = 1.0f / fmaxf(sqrtf(tot), 1e-12f);
  u16* yr = Y + (long)row * Kout;
  for (int k = t; k < Kin; k += 256) yr[k] = f2bf(ldval(xr[k]) * inv);
  for (int k = Kin + t; k < Kout; k += 256) yr[k] = 0;
}

// ============ hidden = [feat[id1], feat[id2], cell] =========================
__global__ void __launch_bounds__(256) build_hidden_kernel(const u16* __restrict__ feat,
                                                           const int* __restrict__ id1,
                                                           const int* __restrict__ id2,
                                                           const u16* __restrict__ cell,
                                                           u16* __restrict__ hidden) {
  int i = blockIdx.x * 256 + threadIdx.x;
  int row = i >> 9, col = i & 511;
  u16 v;
  if (col < 128) v = feat[(long)id1[row] * HH + col];
  else if (col < 256) v = feat[(long)id2[row] * HH + (col - 128)];
  else v = cell[(long)row * 256 + (col - 256)];
  hidden[i] = v;
}

// ============ logits: [B,128] @ [128,2] + b -> fp32 =========================
__global__ void __launch_bounds__(128) logits_kernel(const u16* __restrict__ h2,
                                                     const float* __restrict__ W,
                                                     const float* __restrict__ b,
                                                     float* __restrict__ out) {
  const int row = blockIdx.x;
  const int t = threadIdx.x;
  float hv = bf2f(h2[(long)row * HH + t]);
  float p0 = hv * W[2 * t], p1 = hv * W[2 * t + 1];
#pragma unroll
  for (int o = 32; o > 0; o >>= 1) {
    p0 += __shfl_down(p0, o);
    p1 += __shfl_down(p1, o);
  }
  __shared__ float sA[2], sB[2];
  if ((t & 63) == 0) { sA[t >> 6] = p0; sB[t >> 6] = p1; }
  __syncthreads();
  if (t == 0) {
    out[2 * row] = sA[0] + sA[1] + b[0];
    out[2 * row + 1] = sB[0] + sB[1] + b[1];
  }
}

extern "C" void kernel_launch(void* const* d_in, const int* in_sizes, int n_in,
                              void* d_out, int out_size, void* d_ws, size_t ws_size,
                              hipStream_t stream) {
  const float* x_drug = (const float*)d_in[0];
  const float* x_target = (const float*)d_in[1];
  const float* cellf = (const float*)d_in[2];
  const float* dd_W = (const float*)d_in[3];
  const float* dd_as = (const float*)d_in[4];
  const float* dd_ad = (const float*)d_in[5];
  const float* dd_b = (const float*)d_in[6];
  const float* dt_Ws = (const float*)d_in[7];
  const float* dt_Wd = (const float*)d_in[8];
  const float* dt_as = (const float*)d_in[9];
  const float* dt_ad = (const float*)d_in[10];
  const float* dt_b = (const float*)d_in[11];
  const float* td_Ws = (const float*)d_in[12];
  const float* td_Wd = (const float*)d_in[13];
  const float* td_as = (const float*)d_in[14];
  const float* td_ad = (const float*)d_in[15];
  const float* td_b = (const float*)d_in[16];
  const float* tt_W = (const float*)d_in[17];
  const float* tt_as = (const float*)d_in[18];
  const float* tt_ad = (const float*)d_in[19];
  const float* tt_b = (const float*)d_in[20];
  const float* r1_W1 = (const float*)d_in[21];
  const float* r1_b1 = (const float*)d_in[22];
  const float* r1_W2 = (const float*)d_in[23];
  const float* r1_b2 = (const float*)d_in[24];
  const float* r1_W3 = (const float*)d_in[25];
  const float* r1_b3 = (const float*)d_in[26];
  const float* r2_W1 = (const float*)d_in[27];
  const float* r2_b1 = (const float*)d_in[28];
  const float* r2_W2 = (const float*)d_in[29];
  const float* r2_b2 = (const float*)d_in[30];
  const float* r2_W3 = (const float*)d_in[31];
  const float* r2_b3 = (const float*)d_in[32];
  const float* cls_W = (const float*)d_in[33];
  const float* cls_b = (const float*)d_in[34];
  const int* src_dd = (const int*)d_in[35];
  const int* dst_dd = (const int*)d_in[36];
  const int* src_dt = (const int*)d_in[37];
  const int* dst_dt = (const int*)d_in[38];
  const int* src_td = (const int*)d_in[39];
  const int* dst_td = (const int*)d_in[40];
  const int* src_tt = (const int*)d_in[41];
  const int* dst_tt = (const int*)d_in[42];
  const int* drug1 = (const int*)d_in[43];
  const int* drug2 = (const int*)d_in[44];
  float* out = (float*)d_out;

  char* ws = (char*)d_ws;
  size_t cur = 0;
  auto alloc = [&](size_t b) {
    size_t r = cur;
    cur += (b + 255) & ~(size_t)255;
    return r;
  };

  // bf16 node inputs, padded to MPAD rows
  u16* xdb = (u16*)(ws + alloc((size_t)MPAD * DF * 2));
  u16* xtb = (u16*)(ws + alloc((size_t)MPAD * TFD * 2));
  // node weights packed: Bd rows [dd_W | td_Wd | dt_Ws], Bt6 [td_Ws | dt_Wd | tt_W]
  u16* Bd = (u16*)(ws + alloc((size_t)384 * DF * 2));
  u16* Bt6 = (u16*)(ws + alloc((size_t)384 * TFD * 2));
  u16* wt1 = (u16*)(ws + alloc((size_t)P1C * CFP * 2));
  u16* wt2 = (u16*)(ws + alloc((size_t)P2C * P1C * 2));
  u16* wt3 = (u16*)(ws + alloc((size_t)256 * P2C * 2));
  u16* wt4 = (u16*)(ws + alloc((size_t)P1C * 512 * 2));
  u16* wt5 = (u16*)(ws + alloc((size_t)P2C * P1C * 2));
  u16* wt6 = (u16*)(ws + alloc((size_t)HH * P2C * 2));
  // node features: [MPAD][384] per node type
  u16* h6d = (u16*)(ws + alloc((size_t)MPAD * 384 * 2));
  u16* h6t = (u16*)(ws + alloc((size_t)MPAD * 384 * 2));
  float* es0 = (float*)(ws + alloc(ND * 4));
  float* ed0 = (float*)(ws + alloc(ND * 4));
  float* es1 = (float*)(ws + alloc(NT_ * 4));
  float* ed1 = (float*)(ws + alloc(ND * 4));
  float* es2 = (float*)(ws + alloc(ND * 4));
  float* ed2 = (float*)(ws + alloc(NT_ * 4));
  float* es3 = (float*)(ws + alloc(NT_ * 4));
  float* ed3 = (float*)(ws + alloc(NT_ * 4));
  int* hist = (int*)(ws + alloc((size_t)4 * NCH * NBK * 4));
  int* base = (int*)(ws + alloc((size_t)4 * (NBK + 1) * 4));
  int* offs_all = (int*)(ws + alloc((size_t)4 * 10001 * 4));
  unsigned int* binned = (unsigned int*)(ws + alloc((size_t)4 * EE * 4));
  u16* srcs = (u16*)(ws + alloc((size_t)4 * EE * 2));
  u16* feat = (u16*)(ws + alloc((size_t)ND * HH * 2));
  u16* cellnorm = (u16*)(ws + alloc((size_t)BB * CFP * 2));
  u16* big = (u16*)(ws + alloc((size_t)BB * P1C * 2));
  u16* mid = (u16*)(ws + alloc((size_t)BB * P2C * 2));
  u16* cellout = (u16*)(ws + alloc((size_t)BB * 256 * 2));
  u16* hidden = (u16*)(ws + alloc((size_t)BB * 512 * 2));
  u16* hiddennorm = (u16*)(ws + alloc((size_t)BB * 512 * 2));
  u16* h2 = (u16*)(ws + alloc((size_t)BB * HH * 2));

  // ---- x fp32 -> bf16 (padded rows) ----
  xcvt_kernel<<<dim3(MPAD * DF / 8 / 256, 2), 256, 0, stream>>>(x_drug, x_target, xdb, xtb);

  // ---- fused transposes (12) ----
  TransArgs ta;
  const float* tw[12] = {dd_W, td_Wd, dt_Ws, td_Ws, dt_Wd, tt_W, r1_W1, r1_W2, r1_W3, r2_W1, r2_W2, r2_W3};
  u16* twt[12] = {Bd, Bd + 128 * 256, Bd + 2 * 128 * 256, Bt6, Bt6 + 128 * 256, Bt6 + 2 * 128 * 256,
                  wt1, wt2, wt3, wt4, wt5, wt6};
  int tk_[12] = {DF, DF, DF, TFD, TFD, TFD, CF, P1C, P2C, 512, P1C, P2C};
  int tn_[12] = {HH, HH, HH, HH, HH, HH, P1C, P2C, 256, P1C, P2C, HH};
  int tp_[12] = {DF, DF, DF, TFD, TFD, TFD, CFP, P1C, P2C, 512, P1C, P2C};
  for (int i = 0; i < 12; ++i) {
    ta.W[i] = tw[i]; ta.Wt[i] = twt[i]; ta.K[i] = tk_[i]; ta.N[i] = tn_[i]; ta.Kp[i] = tp_[i];
  }
  transpose_all<<<dim3(1920, 12), dim3(32, 8), 0, stream>>>(ta);

  // ---- node GEMMs: [MPAD,256] x [256,384] -> h6 (stride 384) ----
  gemm_a16<0, 0><<<(MPAD / 128) * 3, 256, 0, stream>>>(xdb, Bd, nullptr, h6d, MPAD, 384, DF);
  gemm_a16<0, 0><<<(MPAD / 128) * 3, 256, 0, stream>>>(xtb, Bt6, nullptr, h6t, MPAD, 384, TFD);

  // h layout: h_dd=h6d+0, h_tdd=h6d+128, h_dts=h6d+256, h_tds=h6t+0, h_dtd=h6t+128, h_tt=h6t+256
  const u16* h_dd = h6d;
  const u16* h_tdd = h6d + 128;
  const u16* h_dts = h6d + 256;
  const u16* h_tds = h6t;
  const u16* h_dtd = h6t + 128;
  const u16* h_tt = h6t + 256;

  // ---- fused attention logits (4 convs) ----
  EsedArgs ea;
  const u16* ehs[4] = {h_dd, h_tds, h_dts, h_tt};
  const u16* ehd[4] = {h_dd, h_tdd, h_dtd, h_tt};
  const float* eas[4] = {dd_as, td_as, dt_as, tt_as};
  const float* ead[4] = {dd_ad, td_ad, dt_ad, tt_ad};
  float* ees[4] = {es0, es1, es2, es3};
  float* eed[4] = {ed0, ed1, ed2, ed3};
  for (int i = 0; i < 4; ++i) {
    ea.hs[i] = ehs[i]; ea.hd[i] = ehd[i]; ea.as_[i] = eas[i]; ea.ad_[i] = ead[i];
    ea.es[i] = ees[i]; ea.ed[i] = eed[i];
  }
  esed4<<<dim3(10000, 4), 128, 0, stream>>>(ea);

  // ---- binned counting sort -> CSR (conv order: 0=dd, 1=td, 2=dt, 3=tt) ----
  EdgePtrs ep;
  ep.dst[0] = dst_dd; ep.dst[1] = dst_td; ep.dst[2] = dst_dt; ep.dst[3] = dst_tt;
  ep.src[0] = src_dd; ep.src[1] = src_td; ep.src[2] = src_dt; ep.src[3] = src_tt;
  sort_count<<<dim3(NCH, 4), 256, 0, stream>>>(ep, hist);
  sort_scan<<<4, 256, 0, stream>>>(hist, base, offs_all);
  sort_scatter<<<dim3(NCH, 4), 256, 0, stream>>>(ep, hist, base, binned);
  sort_bucket<<<dim3(NBK, 4), 256, 0, stream>>>(binned, base, offs_all, srcs);

  // ---- fused GAT ----
  GatArgs gaa;
  const u16* ghs[4] = {h_dd, h_tds, h_dts, h_tt};
  const float* gbias[4] = {dd_b, td_b, dt_b, tt_b};
  for (int i = 0; i < 4; ++i) {
    gaa.offs[i] = offs_all + (long)i * 10001;
    gaa.srcs[i] = srcs + (long)i * EE;
    gaa.es[i] = ees[i];
    gaa.ed[i] = eed[i];
    gaa.hs[i] = ghs[i];
    gaa.bias[i] = gbias[i];
  }
  gat2<<<dim3(10000, 2), 128, 0, stream>>>(gaa, out, feat);

  // ---- MLP chain (all K mult of 32 via CFP pad) ----
  rownorm_kernel<float><<<BB, 256, 0, stream>>>(cellf, cellnorm, CF, CFP);
  gemm_a16<1, 1><<<(BB / 128) * (P1C / 128), 256, 0, stream>>>(cellnorm, wt1, r1_b1, big, BB, P1C, CFP);
  gemm_a16<1, 1><<<(BB / 128) * (P2C / 128), 256, 0, stream>>>(big, wt2, r1_b2, mid, BB, P2C, P1C);
  gemm_a16<1, 1><<<(BB / 128) * (256 / 128), 256, 0, stream>>>(mid, wt3, r1_b3, cellout, BB, 256, P2C);
  build_hidden_kernel<<<BB * 512 / 256, 256, 0, stream>>>(feat, drug1, drug2, cellout, hidden);
  rownorm_kernel<u16><<<BB, 256, 0, stream>>>(hidden, hiddennorm, 512, 512);
  gemm_a16<1, 1><<<(BB / 128) * (P1C / 128), 256, 0, stream>>>(hiddennorm, wt4, r2_b1, big, BB, P1C, 512);
  gemm_a16<1, 1><<<(BB / 128) * (P2C / 128), 256, 0, stream>>>(big, wt5, r2_b2, mid, BB, P2C, P1C);
  gemm_a16<1, 1><<<(BB / 128) * (HH / 128), 256, 0, stream>>>(mid, wt6, r2_b3, h2, BB, HH, P2C);
  logits_kernel<<<BB, 128, 0, stream>>>(h2, cls_W, cls_b, out);
}

// Round 5
// 408.781 us; speedup vs baseline: 2.5241x; 1.0555x over previous
//
#include <hip/hip_runtime.h>

// Problem constants (fixed by the reference)
#define ND 10000
#define NT_ 10000
#define EE 500000
#define BB 8192
#define DF 256
#define TFD 256
#define HH 128
#define CF 954
#define CFP 960   // padded K for MFMA (zero-filled)
#define P1C 2048
#define P2C 512
#define MPAD 10112  // ND padded to multiple of 128

// sort constants
#define CHUNK 4096
#define NCH 123
#define NBK 157
#define MAXB 6144
#define GCAP 256   // max degree ~82 (Binomial(5e5,1e-4)); big margin + fallback

typedef unsigned short u16;
typedef __attribute__((ext_vector_type(8))) short short8;
typedef __attribute__((ext_vector_type(4))) float f4;

#define AS1 __attribute__((address_space(1)))
#define AS3 __attribute__((address_space(3)))
#define GLOAD16(g, l) \
  __builtin_amdgcn_global_load_lds((const AS1 void*)(g), (AS3 void*)(l), 16, 0, 0)

__device__ inline u16 f2bf(float f) {
  unsigned int u = __builtin_bit_cast(unsigned int, f);
  unsigned int r = (u + 0x7FFFu + ((u >> 16) & 1u)) >> 16;
  return (u16)r;
}
__device__ inline float bf2f(u16 b) {
  return __builtin_bit_cast(float, ((unsigned int)b) << 16);
}
__device__ inline float ldval(float v) { return v; }
__device__ inline float ldval(u16 v) { return bf2f(v); }

__device__ inline void load8cvt(const float* p, u16* dst) {
#pragma unroll
  for (int i = 0; i < 4; ++i) {
    float2 v = reinterpret_cast<const float2*>(p)[i];
    dst[2 * i] = f2bf(v.x);
    dst[2 * i + 1] = f2bf(v.y);
  }
}

// ============ x fp32 -> bf16, rows padded to MPAD with zeros ================
__global__ void __launch_bounds__(256) xcvt_kernel(const float* __restrict__ xd,
                                                   const float* __restrict__ xt,
                                                   u16* __restrict__ xdb,
                                                   u16* __restrict__ xtb) {
  const float* X = blockIdx.y ? xt : xd;
  u16* Y = blockIdx.y ? xtb : xdb;
  long i = (long)blockIdx.x * 256 + threadIdx.x;  // one 8-elem chunk each
  long e = i * 8;
  int row = (int)(e >> 8);
  union { u16 u[8]; short8 v; } tv;
  if (row < ND) {
    load8cvt(X + e, tv.u);
  } else {
#pragma unroll
    for (int k = 0; k < 8; ++k) tv.u[k] = 0;
  }
  *reinterpret_cast<short8*>(Y + e) = tv.v;
}

// ============ fused weight transpose: fp32 [K,N] -> bf16 [N,Kp] (zero pad) ==
struct TransArgs {
  const float* W[12];
  u16* Wt[12];
  int K[12];
  int N[12];
  int Kp[12];
};

__global__ void __launch_bounds__(256) transpose_all(TransArgs ta) {
  const int id = blockIdx.y;
  const int K = ta.K[id], N = ta.N[id], Kp = ta.Kp[id];
  const int tn = (N + 31) >> 5, tk = (Kp + 31) >> 5;
  if ((int)blockIdx.x >= tn * tk) return;
  const float* W = ta.W[id];
  u16* Wt = ta.Wt[id];
  const int bn = (blockIdx.x % tn) << 5;
  const int bk = (blockIdx.x / tn) << 5;
  __shared__ u16 tile[32][33];
  const int tx = threadIdx.x;
  const int ty = threadIdx.y;
#pragma unroll
  for (int i = ty; i < 32; i += 8) {
    int k = bk + i, n = bn + tx;
    tile[i][tx] = (k < K && n < N) ? f2bf(W[(long)k * N + n]) : (u16)0;
  }
  __syncthreads();
#pragma unroll
  for (int i = ty; i < 32; i += 8) {
    int n = bn + i, k = bk + tx;
    if (n < N && k < Kp) Wt[(long)n * Kp + k] = tile[tx][i];
  }
}

// ============ m97-structure bf16 GEMM: global_load_lds + LDS-staged C =======
// C[M,N] = act(A[M,K] @ Bt[N,K]^T + bias).  M%128==0, N%128==0, K%32==0.
template <int ACT, int BIAS>
__global__ void __launch_bounds__(256) gemm_a16(const u16* __restrict__ A,
                                                const u16* __restrict__ Bt,
                                                const float* __restrict__ bias,
                                                u16* __restrict__ C, int M, int N, int K) {
  const int tiles_n = N >> 7;
  const int bm = blockIdx.x / tiles_n;
  const int bn = blockIdx.x % tiles_n;
  const long row0 = (long)bm << 7;
  const int col0 = bn << 7;
  __shared__ u16 As[128 * 32];
  __shared__ u16 Bs[128 * 32];
  const int t = threadIdx.x;
  const int lane = t & 63;
  const int w = t >> 6;
  const int wr = w >> 1, wc = w & 1;
  const int lr = lane & 15, lk = lane >> 4;
  const int srow = lane >> 2;
  const int scol = (lane & 3) << 3;
  const u16* gA = A + (row0 + (w << 4) + srow) * K + scol;
  const u16* gA2 = A + (row0 + ((w + 4) << 4) + srow) * K + scol;
  const u16* gB = Bt + ((long)col0 + (w << 4) + srow) * K + scol;
  const u16* gB2 = Bt + ((long)col0 + ((w + 4) << 4) + srow) * K + scol;
  u16* lA = &As[(w << 4) * 32];
  u16* lA2 = &As[((w + 4) << 4) * 32];
  u16* lB = &Bs[(w << 4) * 32];
  u16* lB2 = &Bs[((w + 4) << 4) * 32];
  f4 acc[4][4] = {};
  const int nk = K >> 5;
  for (int kt = 0; kt < nk; ++kt) {
    __syncthreads();
    GLOAD16(gA, lA);
    GLOAD16(gA2, lA2);
    GLOAD16(gB, lB);
    GLOAD16(gB2, lB2);
    gA += 32; gA2 += 32; gB += 32; gB2 += 32;
    __syncthreads();
    short8 af[4], bf[4];
#pragma unroll
    for (int m = 0; m < 4; ++m)
      af[m] = *reinterpret_cast<const short8*>(&As[(((wr << 6) + (m << 4) + lr) << 5) + (lk << 3)]);
#pragma unroll
    for (int n = 0; n < 4; ++n)
      bf[n] = *reinterpret_cast<const short8*>(&Bs[(((wc << 6) + (n << 4) + lr) << 5) + (lk << 3)]);
#pragma unroll
    for (int m = 0; m < 4; ++m)
#pragma unroll
      for (int n = 0; n < 4; ++n)
        acc[m][n] = __builtin_amdgcn_mfma_f32_16x16x32_bf16(af[m], bf[n], acc[m][n], 0, 0, 0);
  }
  float bv[4];
#pragma unroll
  for (int n = 0; n < 4; ++n)
    bv[n] = BIAS ? bias[col0 + (wc << 6) + (n << 4) + lr] : 0.0f;
  __syncthreads();
  u16* Cs = As;  // reuse 8KB (32 rows x 128 cols)
  for (int g = 0; g < 4; ++g) {
    if (wr == (g >> 1)) {
#pragma unroll
      for (int mm = 0; mm < 2; ++mm) {
        const int m = ((g & 1) << 1) + mm;
#pragma unroll
        for (int n = 0; n < 4; ++n) {
#pragma unroll
          for (int r = 0; r < 4; ++r) {
            float x = acc[m][n][r] + bv[n];
            if (ACT) x = fmaxf(x, 0.0f);
            Cs[(((mm << 4) + (lk << 2) + r) << 7) + (wc << 6) + (n << 4) + lr] = f2bf(x);
          }
        }
      }
    }
    __syncthreads();
#pragma unroll
    for (int it = 0; it < 2; ++it) {
      const int c = t + (it << 8);
      const int rr = c >> 4, off = (c & 15) << 3;
      *reinterpret_cast<short8*>(&C[(row0 + (g << 5) + rr) * N + col0 + off]) =
          *reinterpret_cast<const short8*>(&Cs[(rr << 7) + off]);
    }
    __syncthreads();
  }
}

// ============ fused per-node attention logits (4 convs, h stride 384) =======
struct EsedArgs {
  const u16* hs[4];
  const u16* hd[4];
  const float* as_[4];
  const float* ad_[4];
  float* es[4];
  float* ed[4];
};

__global__ void __launch_bounds__(128) esed4(EsedArgs ea) {
  const int cv = blockIdx.y;
  const int row = blockIdx.x;
  const int t = threadIdx.x;
  float ps = bf2f(ea.hs[cv][(long)row * 384 + t]) * ea.as_[cv][t];
  float pd = bf2f(ea.hd[cv][(long)row * 384 + t]) * ea.ad_[cv][t];
#pragma unroll
  for (int o = 32; o > 0; o >>= 1) {
    ps += __shfl_down(ps, o);
    pd += __shfl_down(pd, o);
  }
  __shared__ float s0[2], s1[2];
  if ((t & 63) == 0) { s0[t >> 6] = ps; s1[t >> 6] = pd; }
  __syncthreads();
  if (t == 0) {
    ea.es[cv][row] = s0[0] + s0[1];
    ea.ed[cv][row] = s1[0] + s1[1];
  }
}

// ============ binned counting sort (coalesced CSR build) ====================
struct EdgePtrs {
  const int* dst[4];
  const int* src[4];
};

__global__ void __launch_bounds__(256) sort_count(EdgePtrs ep, int* __restrict__ hist) {
  const int cv = blockIdx.y, ch = blockIdx.x;
  __shared__ int h[NBK];
  for (int i = threadIdx.x; i < NBK; i += 256) h[i] = 0;
  __syncthreads();
  const int* dst = ep.dst[cv];
  const int e0 = ch * CHUNK;
  const int e1 = e0 + CHUNK < EE ? e0 + CHUNK : EE;
  for (int i = e0 + threadIdx.x; i < e1; i += 256) atomicAdd(&h[dst[i] >> 6], 1);
  __syncthreads();
  int* out = hist + ((long)cv * NCH + ch) * NBK;
  for (int i = threadIdx.x; i < NBK; i += 256) out[i] = h[i];
}

__global__ void __launch_bounds__(256) sort_scan(int* __restrict__ hist, int* __restrict__ base,
                                                 int* __restrict__ offs_all) {
  const int cv = blockIdx.x;
  int* H = hist + (long)cv * NCH * NBK;
  __shared__ int tot[NBK];
  for (int b = threadIdx.x; b < NBK; b += 256) {
    int run = 0;
    for (int ch = 0; ch < NCH; ++ch) {
      int v = H[ch * NBK + b];
      H[ch * NBK + b] = run;
      run += v;
    }
    tot[b] = run;
  }
  __syncthreads();
  if (threadIdx.x == 0) {
    int* B = base + cv * (NBK + 1);
    int run = 0;
    for (int b = 0; b < NBK; ++b) { B[b] = run; run += tot[b]; }
    B[NBK] = run;
    offs_all[(long)cv * 10001 + 10000] = run;
  }
}

__global__ void __launch_bounds__(256) sort_scatter(EdgePtrs ep, const int* __restrict__ hist,
                                                    const int* __restrict__ base,
                                                    unsigned int* __restrict__ binned) {
  const int cv = blockIdx.y, ch = blockIdx.x;
  __shared__ int lcnt[NBK];
  __shared__ int lofs[NBK];
  __shared__ int lcur[NBK];
  __shared__ int sofs[NBK];
  __shared__ unsigned int buf[CHUNK];
  for (int i = threadIdx.x; i < NBK; i += 256) lcnt[i] = 0;
  __syncthreads();
  const int* dst = ep.dst[cv];
  const int* src = ep.src[cv];
  const int e0 = ch * CHUNK;
  const int e1 = e0 + CHUNK < EE ? e0 + CHUNK : EE;
  const int n = e1 - e0;
  unsigned int pk[16];
#pragma unroll
  for (int u = 0; u < 16; ++u) {
    int i = e0 + u * 256 + threadIdx.x;
    unsigned int p = 0xFFFFFFFFu;
    if (i < e1) {
      int d = dst[i];
      p = ((unsigned int)d << 16) | (unsigned int)src[i];
      atomicAdd(&lcnt[d >> 6], 1);
    }
    pk[u] = p;
  }
  {
    const int* chOfs = hist + ((long)cv * NCH + ch) * NBK;
    const int* B = base + cv * (NBK + 1);
    for (int b = threadIdx.x; b < NBK; b += 256) sofs[b] = B[b] + chOfs[b];
  }
  __syncthreads();
  if (threadIdx.x == 0) {
    int run = 0;
    for (int b = 0; b < NBK; ++b) { lofs[b] = run; lcur[b] = run; run += lcnt[b]; }
  }
  __syncthreads();
#pragma unroll
  for (int u = 0; u < 16; ++u) {
    if (pk[u] != 0xFFFFFFFFu) {
      int b = pk[u] >> 22;
      int p = atomicAdd(&lcur[b], 1);
      buf[p] = pk[u];
    }
  }
  __syncthreads();
  unsigned int* outp = binned + (long)cv * EE;
  for (int i = threadIdx.x; i < n; i += 256) {
    unsigned int p = buf[i];
    int b = p >> 22;
    outp[sofs[b] + (i - lofs[b])] = p;
  }
}

__global__ void __launch_bounds__(256) sort_bucket(const unsigned int* __restrict__ binned,
                                                   const int* __restrict__ base,
                                                   int* __restrict__ offs_all,
                                                   u16* __restrict__ srcs) {
  const int cv = blockIdx.y, b = blockIdx.x;
  const int* B = base + cv * (NBK + 1);
  const int s0 = B[b], s1 = B[b + 1];
  int n = s1 - s0;
  if (n > MAXB) n = MAXB;
  __shared__ unsigned int buf[MAXB];
  __shared__ u16 obuf[MAXB];
  __shared__ int cnt[64], dofs[64], dcur[64];
  if (threadIdx.x < 64) cnt[threadIdx.x] = 0;
  __syncthreads();
  const unsigned int* inp = binned + (long)cv * EE + s0;
  for (int i = threadIdx.x; i < n; i += 256) {
    unsigned int p = inp[i];
    buf[i] = p;
    atomicAdd(&cnt[(p >> 16) & 63], 1);
  }
  __syncthreads();
  if (threadIdx.x == 0) {
    int run = 0;
    for (int i = 0; i < 64; ++i) { dofs[i] = run; dcur[i] = run; run += cnt[i]; }
  }
  __syncthreads();
  if (threadIdx.x < 64) {
    int d = (b << 6) + threadIdx.x;
    if (d < 10000) offs_all[(long)cv * 10001 + d] = s0 + dofs[threadIdx.x];
  }
  for (int i = threadIdx.x; i < n; i += 256) {
    unsigned int p = buf[i];
    int pos = atomicAdd(&dcur[(p >> 16) & 63], 1);
    obuf[pos] = (u16)(p & 0xFFFFu);
  }
  __syncthreads();
  u16* outp = srcs + (long)cv * EE + s0;
  for (int i = threadIdx.x; i < n; i += 256) outp[i] = obuf[i];
}

// ============ fused GAT: wave-per-dst, 2 rows per wave-iteration ============
struct GatArgs {
  const int* offs[4];
  const u16* srcs[4];
  const float* es[4];
  const float* ed[4];
  const u16* hs[4];   // stride 384
  const float* bias[4];
};

// 256 threads = 4 waves; wave w handles dst = blockIdx.x*4 + w, half=blockIdx.y.
// Lane l: features fl=(l&31)*4 .. +3; lanes 0-31 edge 2k, lanes 32-63 edge 2k+1.
__global__ void __launch_bounds__(256) gat3(GatArgs ga, float* __restrict__ out,
                                            u16* __restrict__ feat) {
  const int t = threadIdx.x;
  const int w = t >> 6;
  const int lane = t & 63;
  const int hi = lane >> 5;
  const int fl = (lane & 31) << 2;
  const int d = blockIdx.x * 4 + w;
  const int half = blockIdx.y;
  __shared__ float al[4][GCAP + 2];
  __shared__ u16 sl[4][GCAP + 2];
  float a0 = 0.f, a1 = 0.f, a2 = 0.f, a3 = 0.f;
#pragma unroll
  for (int q = 0; q < 2; ++q) {
    const int cv = half * 2 + q;
    const int* offs = ga.offs[cv];
    const int o0 = offs[d], o1 = offs[d + 1];
    const int deg = o1 - o0;
    const u16* sp = ga.srcs[cv] + o0;
    const float* es = ga.es[cv];
    const float edd = ga.ed[cv][d];
    const u16* hs = ga.hs[cv];
    const int degc = deg > GCAP ? GCAP : deg;
    __syncthreads();  // al/sl free from previous q
    // phase 1: exp + sum
    float part = 0.f;
    for (int j = lane; j < degc; j += 64) {
      int s = sp[j];
      float e = es[s] + edd;
      e = e > 0.f ? e : 0.2f * e;
      float ex = __expf(e);
      al[w][j] = ex;
      sl[w][j] = (u16)s;
      part += ex;
    }
    for (int j = GCAP + lane; j < deg; j += 64) {  // never taken for this data
      float e = es[sp[j]] + edd;
      e = e > 0.f ? e : 0.2f * e;
      part += __expf(e);
    }
#pragma unroll
    for (int o = 32; o > 0; o >>= 1) part += __shfl_down(part, o);
    const float inv = 1.0f / (__shfl(part, 0) + 1e-16f);
    // fold inv into al; pad odd slot
    for (int j = lane; j < degc; j += 64) al[w][j] *= inv;
    if (lane == 0 && (degc & 1)) { al[w][degc] = 0.f; sl[w][degc] = 0; }
    __syncthreads();
    // phase 3: paired gather-accumulate
    const int npair = (degc + 1) >> 1;
#pragma unroll 4
    for (int k = 0; k < npair; ++k) {
      const int j = 2 * k + hi;
      const float wgt = al[w][j];
      const int s = sl[w][j];
      ushort4 v = *reinterpret_cast<const ushort4*>(hs + (long)s * 384 + fl);
      a0 += wgt * bf2f(v.x);
      a1 += wgt * bf2f(v.y);
      a2 += wgt * bf2f(v.z);
      a3 += wgt * bf2f(v.w);
    }
    if (hi == 0) {
      for (int j = GCAP; j < deg; ++j) {  // never taken
        int s = sp[j];
        float e = es[s] + edd;
        e = e > 0.f ? e : 0.2f * e;
        float wgt = __expf(e) * inv;
        ushort4 v = *reinterpret_cast<const ushort4*>(hs + (long)s * 384 + fl);
        a0 += wgt * bf2f(v.x); a1 += wgt * bf2f(v.y);
        a2 += wgt * bf2f(v.z); a3 += wgt * bf2f(v.w);
      }
    }
  }
  // cross-half reduce
  a0 += __shfl_xor(a0, 32);
  a1 += __shfl_xor(a1, 32);
  a2 += __shfl_xor(a2, 32);
  a3 += __shfl_xor(a3, 32);
  if (hi == 0) {
    const float* b1 = ga.bias[half * 2];
    const float* b2 = ga.bias[half * 2 + 1];
    float4 bb1 = *reinterpret_cast<const float4*>(b1 + fl);
    float4 bb2 = *reinterpret_cast<const float4*>(b2 + fl);
    float4 r;
    r.x = fmaxf(a0 + bb1.x + bb2.x, 0.0f);
    r.y = fmaxf(a1 + bb1.y + bb2.y, 0.0f);
    r.z = fmaxf(a2 + bb1.z + bb2.z, 0.0f);
    r.w = fmaxf(a3 + bb1.w + bb2.w, 0.0f);
    *reinterpret_cast<float4*>(out + 16384 + (long)half * ND * HH + (long)d * HH + fl) = r;
    if (half == 0) {
      ushort4 fv;
      fv.x = f2bf(r.x); fv.y = f2bf(r.y); fv.z = f2bf(r.z); fv.w = f2bf(r.w);
      *reinterpret_cast<ushort4*>(feat + (long)d * HH + fl) = fv;
    }
  }
}

// ============ row L2-normalize -> bf16 (with zero pad to Kout) ==============
template <typename T>
__global__ void __launch_bounds__(256) rownorm_kernel(const T* __restrict__ X,
                                                      u16* __restrict__ Y, int Kin, int Kout) {
  const int row = blockIdx.x;
  const int t = threadIdx.x;
  const T* xr = X + (long)row * Kin;
  float ss = 0.f;
  for (int k = t; k < Kin; k += 256) {
    float v = ldval(xr[k]);
    ss += v * v;
  }
#pragma unroll
  for (int o = 32; o > 0; o >>= 1) ss += __shfl_down(ss, o);
  __shared__ float sh[4];
  if ((t & 63) == 0) sh[t >> 6] = ss;
  __syncthreads();
  float tot = sh[0] + sh[1] + sh[2] + sh[3];
  float inv = 1.0f / fmaxf(sqrtf(tot), 1e-12f);
  u16* yr = Y + (long)row * Kout;
  for (int k = t; k < Kin; k += 256) yr[k] = f2bf(ldval(xr[k]) * inv);
  for (int k = Kin + t; k < Kout; k += 256) yr[k] = 0;
}

// ============ hidden = [feat[id1], feat[id2], cell] =========================
__global__ void __launch_bounds__(256) build_hidden_kernel(const u16* __restrict__ feat,
                                                           const int* __restrict__ id1,
                                                           const int* __restrict__ id2,
                                                           const u16* __restrict__ cell,
                                                           u16* __restrict__ hidden) {
  int i = blockIdx.x * 256 + threadIdx.x;
  int row = i >> 9, col = i & 511;
  u16 v;
  if (col < 128) v = feat[(long)id1[row] * HH + col];
  else if (col < 256) v = feat[(long)id2[row] * HH + (col - 128)];
  else v = cell[(long)row * 256 + (col - 256)];
  hidden[i] = v;
}

// ============ logits: [B,128] @ [128,2] + b -> fp32 =========================
__global__ void __launch_bounds__(128) logits_kernel(const u16* __restrict__ h2,
                                                     const float* __restrict__ W,
                                                     const float* __restrict__ b,
                                                     float* __restrict__ out) {
  const int row = blockIdx.x;
  const int t = threadIdx.x;
  float hv = bf2f(h2[(long)row * HH + t]);
  float p0 = hv * W[2 * t], p1 = hv * W[2 * t + 1];
#pragma unroll
  for (int o = 32; o > 0; o >>= 1) {
    p0 += __shfl_down(p0, o);
    p1 += __shfl_down(p1, o);
  }
  __shared__ float sA[2], sB[2];
  if ((t & 63) == 0) { sA[t >> 6] = p0; sB[t >> 6] = p1; }
  __syncthreads();
  if (t == 0) {
    out[2 * row] = sA[0] + sA[1] + b[0];
    out[2 * row + 1] = sB[0] + sB[1] + b[1];
  }
}

extern "C" void kernel_launch(void* const* d_in, const int* in_sizes, int n_in,
                              void* d_out, int out_size, void* d_ws, size_t ws_size,
                              hipStream_t stream) {
  const float* x_drug = (const float*)d_in[0];
  const float* x_target = (const float*)d_in[1];
  const float* cellf = (const float*)d_in[2];
  const float* dd_W = (const float*)d_in[3];
  const float* dd_as = (const float*)d_in[4];
  const float* dd_ad = (const float*)d_in[5];
  const float* dd_b = (const float*)d_in[6];
  const float* dt_Ws = (const float*)d_in[7];
  const float* dt_Wd = (const float*)d_in[8];
  const float* dt_as = (const float*)d_in[9];
  const float* dt_ad = (const float*)d_in[10];
  const float* dt_b = (const float*)d_in[11];
  const float* td_Ws = (const float*)d_in[12];
  const float* td_Wd = (const float*)d_in[13];
  const float* td_as = (const float*)d_in[14];
  const float* td_ad = (const float*)d_in[15];
  const float* td_b = (const float*)d_in[16];
  const float* tt_W = (const float*)d_in[17];
  const float* tt_as = (const float*)d_in[18];
  const float* tt_ad = (const float*)d_in[19];
  const float* tt_b = (const float*)d_in[20];
  const float* r1_W1 = (const float*)d_in[21];
  const float* r1_b1 = (const float*)d_in[22];
  const float* r1_W2 = (const float*)d_in[23];
  const float* r1_b2 = (const float*)d_in[24];
  const float* r1_W3 = (const float*)d_in[25];
  const float* r1_b3 = (const float*)d_in[26];
  const float* r2_W1 = (const float*)d_in[27];
  const float* r2_b1 = (const float*)d_in[28];
  const float* r2_W2 = (const float*)d_in[29];
  const float* r2_b2 = (const float*)d_in[30];
  const float* r2_W3 = (const float*)d_in[31];
  const float* r2_b3 = (const float*)d_in[32];
  const float* cls_W = (const float*)d_in[33];
  const float* cls_b = (const float*)d_in[34];
  const int* src_dd = (const int*)d_in[35];
  const int* dst_dd = (const int*)d_in[36];
  const int* src_dt = (const int*)d_in[37];
  const int* dst_dt = (const int*)d_in[38];
  const int* src_td = (const int*)d_in[39];
  const int* dst_td = (const int*)d_in[40];
  const int* src_tt = (const int*)d_in[41];
  const int* dst_tt = (const int*)d_in[42];
  const int* drug1 = (const int*)d_in[43];
  const int* drug2 = (const int*)d_in[44];
  float* out = (float*)d_out;

  char* ws = (char*)d_ws;
  size_t cur = 0;
  auto alloc = [&](size_t b) {
    size_t r = cur;
    cur += (b + 255) & ~(size_t)255;
    return r;
  };

  u16* xdb = (u16*)(ws + alloc((size_t)MPAD * DF * 2));
  u16* xtb = (u16*)(ws + alloc((size_t)MPAD * TFD * 2));
  u16* Bd = (u16*)(ws + alloc((size_t)384 * DF * 2));
  u16* Bt6 = (u16*)(ws + alloc((size_t)384 * TFD * 2));
  u16* wt1 = (u16*)(ws + alloc((size_t)P1C * CFP * 2));
  u16* wt2 = (u16*)(ws + alloc((size_t)P2C * P1C * 2));
  u16* wt3 = (u16*)(ws + alloc((size_t)256 * P2C * 2));
  u16* wt4 = (u16*)(ws + alloc((size_t)P1C * 512 * 2));
  u16* wt5 = (u16*)(ws + alloc((size_t)P2C * P1C * 2));
  u16* wt6 = (u16*)(ws + alloc((size_t)HH * P2C * 2));
  u16* h6d = (u16*)(ws + alloc((size_t)MPAD * 384 * 2));
  u16* h6t = (u16*)(ws + alloc((size_t)MPAD * 384 * 2));
  float* es0 = (float*)(ws + alloc(ND * 4));
  float* ed0 = (float*)(ws + alloc(ND * 4));
  float* es1 = (float*)(ws + alloc(NT_ * 4));
  float* ed1 = (float*)(ws + alloc(ND * 4));
  float* es2 = (float*)(ws + alloc(ND * 4));
  float* ed2 = (float*)(ws + alloc(NT_ * 4));
  float* es3 = (float*)(ws + alloc(NT_ * 4));
  float* ed3 = (float*)(ws + alloc(NT_ * 4));
  int* hist = (int*)(ws + alloc((size_t)4 * NCH * NBK * 4));
  int* base = (int*)(ws + alloc((size_t)4 * (NBK + 1) * 4));
  int* offs_all = (int*)(ws + alloc((size_t)4 * 10001 * 4));
  unsigned int* binned = (unsigned int*)(ws + alloc((size_t)4 * EE * 4));
  u16* srcs = (u16*)(ws + alloc((size_t)4 * EE * 2));
  u16* feat = (u16*)(ws + alloc((size_t)ND * HH * 2));
  u16* cellnorm = (u16*)(ws + alloc((size_t)BB * CFP * 2));
  u16* big = (u16*)(ws + alloc((size_t)BB * P1C * 2));
  u16* mid = (u16*)(ws + alloc((size_t)BB * P2C * 2));
  u16* cellout = (u16*)(ws + alloc((size_t)BB * 256 * 2));
  u16* hidden = (u16*)(ws + alloc((size_t)BB * 512 * 2));
  u16* hiddennorm = (u16*)(ws + alloc((size_t)BB * 512 * 2));
  u16* h2 = (u16*)(ws + alloc((size_t)BB * HH * 2));

  // ---- x fp32 -> bf16 (padded rows) ----
  xcvt_kernel<<<dim3(MPAD * DF / 8 / 256, 2), 256, 0, stream>>>(x_drug, x_target, xdb, xtb);

  // ---- fused transposes (12) ----
  TransArgs ta;
  const float* tw[12] = {dd_W, td_Wd, dt_Ws, td_Ws, dt_Wd, tt_W, r1_W1, r1_W2, r1_W3, r2_W1, r2_W2, r2_W3};
  u16* twt[12] = {Bd, Bd + 128 * 256, Bd + 2 * 128 * 256, Bt6, Bt6 + 128 * 256, Bt6 + 2 * 128 * 256,
                  wt1, wt2, wt3, wt4, wt5, wt6};
  int tk_[12] = {DF, DF, DF, TFD, TFD, TFD, CF, P1C, P2C, 512, P1C, P2C};
  int tn_[12] = {HH, HH, HH, HH, HH, HH, P1C, P2C, 256, P1C, P2C, HH};
  int tp_[12] = {DF, DF, DF, TFD, TFD, TFD, CFP, P1C, P2C, 512, P1C, P2C};
  for (int i = 0; i < 12; ++i) {
    ta.W[i] = tw[i]; ta.Wt[i] = twt[i]; ta.K[i] = tk_[i]; ta.N[i] = tn_[i]; ta.Kp[i] = tp_[i];
  }
  transpose_all<<<dim3(1920, 12), dim3(32, 8), 0, stream>>>(ta);

  // ---- node GEMMs: [MPAD,256] x [256,384] -> h6 (stride 384) ----
  gemm_a16<0, 0><<<(MPAD / 128) * 3, 256, 0, stream>>>(xdb, Bd, nullptr, h6d, MPAD, 384, DF);
  gemm_a16<0, 0><<<(MPAD / 128) * 3, 256, 0, stream>>>(xtb, Bt6, nullptr, h6t, MPAD, 384, TFD);

  const u16* h_dd = h6d;
  const u16* h_tdd = h6d + 128;
  const u16* h_dts = h6d + 256;
  const u16* h_tds = h6t;
  const u16* h_dtd = h6t + 128;
  const u16* h_tt = h6t + 256;

  // ---- fused attention logits (4 convs) ----
  EsedArgs ea;
  const u16* ehs[4] = {h_dd, h_tds, h_dts, h_tt};
  const u16* ehd[4] = {h_dd, h_tdd, h_dtd, h_tt};
  const float* eas[4] = {dd_as, td_as, dt_as, tt_as};
  const float* ead[4] = {dd_ad, td_ad, dt_ad, tt_ad};
  float* ees[4] = {es0, es1, es2, es3};
  float* eed[4] = {ed0, ed1, ed2, ed3};
  for (int i = 0; i < 4; ++i) {
    ea.hs[i] = ehs[i]; ea.hd[i] = ehd[i]; ea.as_[i] = eas[i]; ea.ad_[i] = ead[i];
    ea.es[i] = ees[i]; ea.ed[i] = eed[i];
  }
  esed4<<<dim3(10000, 4), 128, 0, stream>>>(ea);

  // ---- binned counting sort -> CSR (conv order: 0=dd, 1=td, 2=dt, 3=tt) ----
  EdgePtrs ep;
  ep.dst[0] = dst_dd; ep.dst[1] = dst_td; ep.dst[2] = dst_dt; ep.dst[3] = dst_tt;
  ep.src[0] = src_dd; ep.src[1] = src_td; ep.src[2] = src_dt; ep.src[3] = src_tt;
  sort_count<<<dim3(NCH, 4), 256, 0, stream>>>(ep, hist);
  sort_scan<<<4, 256, 0, stream>>>(hist, base, offs_all);
  sort_scatter<<<dim3(NCH, 4), 256, 0, stream>>>(ep, hist, base, binned);
  sort_bucket<<<dim3(NBK, 4), 256, 0, stream>>>(binned, base, offs_all, srcs);

  // ---- fused GAT (wave-per-dst) ----
  GatArgs gaa;
  const u16* ghs[4] = {h_dd, h_tds, h_dts, h_tt};
  const float* gbias[4] = {dd_b, td_b, dt_b, tt_b};
  for (int i = 0; i < 4; ++i) {
    gaa.offs[i] = offs_all + (long)i * 10001;
    gaa.srcs[i] = srcs + (long)i * EE;
    gaa.es[i] = ees[i];
    gaa.ed[i] = eed[i];
    gaa.hs[i] = ghs[i];
    gaa.bias[i] = gbias[i];
  }
  gat3<<<dim3(2500, 2), 256, 0, stream>>>(gaa, out, feat);

  // ---- MLP chain (all K mult of 32 via CFP pad) ----
  rownorm_kernel<float><<<BB, 256, 0, stream>>>(cellf, cellnorm, CF, CFP);
  gemm_a16<1, 1><<<(BB / 128) * (P1C / 128), 256, 0, stream>>>(cellnorm, wt1, r1_b1, big, BB, P1C, CFP);
  gemm_a16<1, 1><<<(BB / 128) * (P2C / 128), 256, 0, stream>>>(big, wt2, r1_b2, mid, BB, P2C, P1C);
  gemm_a16<1, 1><<<(BB / 128) * (256 / 128), 256, 0, stream>>>(mid, wt3, r1_b3, cellout, BB, 256, P2C);
  build_hidden_kernel<<<BB * 512 / 256, 256, 0, stream>>>(feat, drug1, drug2, cellout, hidden);
  rownorm_kernel<u16><<<BB, 256, 0, stream>>>(hidden, hiddennorm, 512, 512);
  gemm_a16<1, 1><<<(BB / 128) * (P1C / 128), 256, 0, stream>>>(hiddennorm, wt4, r2_b1, big, BB, P1C, 512);
  gemm_a16<1, 1><<<(BB / 128) * (P2C / 128), 256, 0, stream>>>(big, wt5, r2_b2, mid, BB, P2C, P1C);
  gemm_a16<1, 1><<<(BB / 128) * (HH / 128), 256, 0, stream>>>(mid, wt6, r2_b3, h2, BB, HH, P2C);
  logits_kernel<<<BB, 128, 0, stream>>>(h2, cls_W, cls_b, out);
}

// Round 6
// 357.652 us; speedup vs baseline: 2.8849x; 1.1430x over previous
//
#include <hip/hip_runtime.h>

// Problem constants (fixed by the reference)
#define ND 10000
#define NT_ 10000
#define EE 500000
#define BB 8192
#define DF 256
#define TFD 256
#define HH 128
#define CF 954
#define CFP 960   // padded K for MFMA (zero-filled)
#define P1C 2048
#define P2C 512
#define MPAD 10112  // ND padded to multiple of 128

// sort constants
#define CHUNK 4096
#define NCH 123
#define NBK 157
#define MAXB 6144
#define GCAP 256   // max degree ~82 (Binomial(5e5,1e-4)); big margin + fallback

typedef unsigned short u16;
typedef __attribute__((ext_vector_type(8))) short short8;
typedef __attribute__((ext_vector_type(4))) float f4;

#define AS1 __attribute__((address_space(1)))
#define AS3 __attribute__((address_space(3)))
#define GLOAD16(g, l) \
  __builtin_amdgcn_global_load_lds((const AS1 void*)(g), (AS3 void*)(l), 16, 0, 0)

__device__ inline u16 f2bf(float f) {
  unsigned int u = __builtin_bit_cast(unsigned int, f);
  unsigned int r = (u + 0x7FFFu + ((u >> 16) & 1u)) >> 16;
  return (u16)r;
}
__device__ inline float bf2f(u16 b) {
  return __builtin_bit_cast(float, ((unsigned int)b) << 16);
}
__device__ inline float ldval(float v) { return v; }
__device__ inline float ldval(u16 v) { return bf2f(v); }

__device__ inline void load8cvt(const float* p, u16* dst) {
#pragma unroll
  for (int i = 0; i < 4; ++i) {
    float2 v = reinterpret_cast<const float2*>(p)[i];
    dst[2 * i] = f2bf(v.x);
    dst[2 * i + 1] = f2bf(v.y);
  }
}

// ============ x fp32 -> bf16, rows padded to MPAD with zeros ================
__global__ void __launch_bounds__(256) xcvt_kernel(const float* __restrict__ xd,
                                                   const float* __restrict__ xt,
                                                   u16* __restrict__ xdb,
                                                   u16* __restrict__ xtb) {
  const float* X = blockIdx.y ? xt : xd;
  u16* Y = blockIdx.y ? xtb : xdb;
  long i = (long)blockIdx.x * 256 + threadIdx.x;  // one 8-elem chunk each
  long e = i * 8;
  int row = (int)(e >> 8);
  union { u16 u[8]; short8 v; } tv;
  if (row < ND) {
    load8cvt(X + e, tv.u);
  } else {
#pragma unroll
    for (int k = 0; k < 8; ++k) tv.u[k] = 0;
  }
  *reinterpret_cast<short8*>(Y + e) = tv.v;
}

// ============ fused weight transpose: fp32 [K,N] -> bf16 [N,Kp] (zero pad) ==
struct TransArgs {
  const float* W[12];
  u16* Wt[12];
  int K[12];
  int N[12];
  int Kp[12];
};

__global__ void __launch_bounds__(256) transpose_all(TransArgs ta) {
  const int id = blockIdx.y;
  const int K = ta.K[id], N = ta.N[id], Kp = ta.Kp[id];
  const int tn = (N + 31) >> 5, tk = (Kp + 31) >> 5;
  if ((int)blockIdx.x >= tn * tk) return;
  const float* W = ta.W[id];
  u16* Wt = ta.Wt[id];
  const int bn = (blockIdx.x % tn) << 5;
  const int bk = (blockIdx.x / tn) << 5;
  __shared__ u16 tile[32][33];
  const int tx = threadIdx.x;
  const int ty = threadIdx.y;
#pragma unroll
  for (int i = ty; i < 32; i += 8) {
    int k = bk + i, n = bn + tx;
    tile[i][tx] = (k < K && n < N) ? f2bf(W[(long)k * N + n]) : (u16)0;
  }
  __syncthreads();
#pragma unroll
  for (int i = ty; i < 32; i += 8) {
    int n = bn + i, k = bk + tx;
    if (n < N && k < Kp) Wt[(long)n * Kp + k] = tile[tx][i];
  }
}

// ============ T3-minimal double-buffered bf16 GEMM (m97 staging + dbuf) =====
// C[M,N] = act(A[M,K] @ Bt[N,K]^T + bias).  M%128==0, N%128==0, K%32==0.
// Per K-tile: stage next tile into buf^1 (async), compute buf, ONE barrier.
template <int ACT, int BIAS>
__global__ void __launch_bounds__(256) gemm_db(const u16* __restrict__ A,
                                               const u16* __restrict__ Bt,
                                               const float* __restrict__ bias,
                                               u16* __restrict__ C, int M, int N, int K) {
  const int tiles_n = N >> 7;
  const int bm = blockIdx.x / tiles_n;
  const int bn = blockIdx.x % tiles_n;
  const long row0 = (long)bm << 7;
  const int col0 = bn << 7;
  // layout: buf b: A at sh + b*8192, B at sh + b*8192 + 4096 (u16 units)
  __shared__ u16 sh[16384];  // 32 KB
  const int t = threadIdx.x;
  const int lane = t & 63;
  const int w = t >> 6;
  const int wr = w >> 1, wc = w & 1;
  const int lr = lane & 15, lk = lane >> 4;
  const int srow = lane >> 2;         // staging row within 16-row chunk
  const int scol = (lane & 3) << 3;   // staging col (8 elems)
  const u16* gA0 = A + (row0 + (w << 4) + srow) * K + scol;
  const u16* gA1 = A + (row0 + ((w + 4) << 4) + srow) * K + scol;
  const u16* gB0 = Bt + ((long)col0 + (w << 4) + srow) * K + scol;
  const u16* gB1 = Bt + ((long)col0 + ((w + 4) << 4) + srow) * K + scol;
  const int lofsA0 = (w << 4) * 32;          // u16 offsets inside a tile
  const int lofsA1 = ((w + 4) << 4) * 32;
  f4 acc[4][4] = {};
  const int nk = K >> 5;

#define STAGE4(kt_, b_)                                     \
  do {                                                      \
    const int ko = (kt_) << 5;                              \
    u16* ab = sh + (b_) * 8192;                             \
    u16* bb = ab + 4096;                                    \
    GLOAD16(gA0 + ko, ab + lofsA0);                         \
    GLOAD16(gA1 + ko, ab + lofsA1);                         \
    GLOAD16(gB0 + ko, bb + lofsA0);                         \
    GLOAD16(gB1 + ko, bb + lofsA1);                         \
  } while (0)

  // prologue: tile 0 into buf 0
  STAGE4(0, 0);
  __syncthreads();  // implicit vmcnt(0): tile 0 resident
  int cur = 0;
  for (int kt = 0; kt < nk; ++kt) {
    if (kt + 1 < nk) STAGE4(kt + 1, cur ^ 1);  // async into the idle buffer
    const u16* Ab = sh + cur * 8192;
    const u16* Bb = Ab + 4096;
    short8 af[4], bf[4];
#pragma unroll
    for (int m = 0; m < 4; ++m)
      af[m] = *reinterpret_cast<const short8*>(&Ab[(((wr << 6) + (m << 4) + lr) << 5) + (lk << 3)]);
#pragma unroll
    for (int n = 0; n < 4; ++n)
      bf[n] = *reinterpret_cast<const short8*>(&Bb[(((wc << 6) + (n << 4) + lr) << 5) + (lk << 3)]);
#pragma unroll
    for (int m = 0; m < 4; ++m)
#pragma unroll
      for (int n = 0; n < 4; ++n)
        acc[m][n] = __builtin_amdgcn_mfma_f32_16x16x32_bf16(af[m], bf[n], acc[m][n], 0, 0, 0);
    __syncthreads();  // drains this wave's loads (next tile) + LDS reads; aligns waves
    cur ^= 1;
  }
#undef STAGE4

  // ---- epilogue: full 128x128 C tile staged once through the 32KB LDS ----
  float bv[4];
#pragma unroll
  for (int n = 0; n < 4; ++n)
    bv[n] = BIAS ? bias[col0 + (wc << 6) + (n << 4) + lr] : 0.0f;
  // sh is free (loop ended with barrier)
#pragma unroll
  for (int m = 0; m < 4; ++m) {
#pragma unroll
    for (int n = 0; n < 4; ++n) {
      const int col = (wc << 6) + (n << 4) + lr;
#pragma unroll
      for (int r = 0; r < 4; ++r) {
        const int row = (wr << 6) + (m << 4) + (lk << 2) + r;
        float x = acc[m][n][r] + bv[n];
        if (ACT) x = fmaxf(x, 0.0f);
        sh[(row << 7) + col] = f2bf(x);
      }
    }
  }
  __syncthreads();
#pragma unroll
  for (int i = 0; i < 8; ++i) {
    const int c = t + (i << 8);       // 0..2047 chunks of 16B
    const int rr = c >> 4, off = (c & 15) << 3;
    *reinterpret_cast<short8*>(&C[(row0 + rr) * N + col0 + off]) =
        *reinterpret_cast<const short8*>(&sh[(rr << 7) + off]);
  }
}

// ============ fused per-node attention logits (4 convs, h stride 384) =======
struct EsedArgs {
  const u16* hs[4];
  const u16* hd[4];
  const float* as_[4];
  const float* ad_[4];
  float* es[4];
  float* ed[4];
};

__global__ void __launch_bounds__(128) esed4(EsedArgs ea) {
  const int cv = blockIdx.y;
  const int row = blockIdx.x;
  const int t = threadIdx.x;
  float ps = bf2f(ea.hs[cv][(long)row * 384 + t]) * ea.as_[cv][t];
  float pd = bf2f(ea.hd[cv][(long)row * 384 + t]) * ea.ad_[cv][t];
#pragma unroll
  for (int o = 32; o > 0; o >>= 1) {
    ps += __shfl_down(ps, o);
    pd += __shfl_down(pd, o);
  }
  __shared__ float s0[2], s1[2];
  if ((t & 63) == 0) { s0[t >> 6] = ps; s1[t >> 6] = pd; }
  __syncthreads();
  if (t == 0) {
    ea.es[cv][row] = s0[0] + s0[1];
    ea.ed[cv][row] = s1[0] + s1[1];
  }
}

// ============ binned counting sort (coalesced CSR build) ====================
struct EdgePtrs {
  const int* dst[4];
  const int* src[4];
};

__global__ void __launch_bounds__(256) sort_count(EdgePtrs ep, int* __restrict__ hist) {
  const int cv = blockIdx.y, ch = blockIdx.x;
  __shared__ int h[NBK];
  for (int i = threadIdx.x; i < NBK; i += 256) h[i] = 0;
  __syncthreads();
  const int* dst = ep.dst[cv];
  const int e0 = ch * CHUNK;
  const int e1 = e0 + CHUNK < EE ? e0 + CHUNK : EE;
  for (int i = e0 + threadIdx.x; i < e1; i += 256) atomicAdd(&h[dst[i] >> 6], 1);
  __syncthreads();
  int* out = hist + ((long)cv * NCH + ch) * NBK;
  for (int i = threadIdx.x; i < NBK; i += 256) out[i] = h[i];
}

__global__ void __launch_bounds__(256) sort_scan(int* __restrict__ hist, int* __restrict__ base,
                                                 int* __restrict__ offs_all) {
  const int cv = blockIdx.x;
  int* H = hist + (long)cv * NCH * NBK;
  __shared__ int tot[NBK];
  for (int b = threadIdx.x; b < NBK; b += 256) {
    int run = 0;
    for (int ch = 0; ch < NCH; ++ch) {
      int v = H[ch * NBK + b];
      H[ch * NBK + b] = run;
      run += v;
    }
    tot[b] = run;
  }
  __syncthreads();
  if (threadIdx.x == 0) {
    int* B = base + cv * (NBK + 1);
    int run = 0;
    for (int b = 0; b < NBK; ++b) { B[b] = run; run += tot[b]; }
    B[NBK] = run;
    offs_all[(long)cv * 10001 + 10000] = run;
  }
}

__global__ void __launch_bounds__(256) sort_scatter(EdgePtrs ep, const int* __restrict__ hist,
                                                    const int* __restrict__ base,
                                                    unsigned int* __restrict__ binned) {
  const int cv = blockIdx.y, ch = blockIdx.x;
  __shared__ int lcnt[NBK];
  __shared__ int lofs[NBK];
  __shared__ int lcur[NBK];
  __shared__ int sofs[NBK];
  __shared__ unsigned int buf[CHUNK];
  for (int i = threadIdx.x; i < NBK; i += 256) lcnt[i] = 0;
  __syncthreads();
  const int* dst = ep.dst[cv];
  const int* src = ep.src[cv];
  const int e0 = ch * CHUNK;
  const int e1 = e0 + CHUNK < EE ? e0 + CHUNK : EE;
  const int n = e1 - e0;
  unsigned int pk[16];
#pragma unroll
  for (int u = 0; u < 16; ++u) {
    int i = e0 + u * 256 + threadIdx.x;
    unsigned int p = 0xFFFFFFFFu;
    if (i < e1) {
      int d = dst[i];
      p = ((unsigned int)d << 16) | (unsigned int)src[i];
      atomicAdd(&lcnt[d >> 6], 1);
    }
    pk[u] = p;
  }
  {
    const int* chOfs = hist + ((long)cv * NCH + ch) * NBK;
    const int* B = base + cv * (NBK + 1);
    for (int b = threadIdx.x; b < NBK; b += 256) sofs[b] = B[b] + chOfs[b];
  }
  __syncthreads();
  if (threadIdx.x == 0) {
    int run = 0;
    for (int b = 0; b < NBK; ++b) { lofs[b] = run; lcur[b] = run; run += lcnt[b]; }
  }
  __syncthreads();
#pragma unroll
  for (int u = 0; u < 16; ++u) {
    if (pk[u] != 0xFFFFFFFFu) {
      int b = pk[u] >> 22;
      int p = atomicAdd(&lcur[b], 1);
      buf[p] = pk[u];
    }
  }
  __syncthreads();
  unsigned int* outp = binned + (long)cv * EE;
  for (int i = threadIdx.x; i < n; i += 256) {
    unsigned int p = buf[i];
    int b = p >> 22;
    outp[sofs[b] + (i - lofs[b])] = p;
  }
}

__global__ void __launch_bounds__(256) sort_bucket(const unsigned int* __restrict__ binned,
                                                   const int* __restrict__ base,
                                                   int* __restrict__ offs_all,
                                                   u16* __restrict__ srcs) {
  const int cv = blockIdx.y, b = blockIdx.x;
  const int* B = base + cv * (NBK + 1);
  const int s0 = B[b], s1 = B[b + 1];
  int n = s1 - s0;
  if (n > MAXB) n = MAXB;
  __shared__ unsigned int buf[MAXB];
  __shared__ u16 obuf[MAXB];
  __shared__ int cnt[64], dofs[64], dcur[64];
  if (threadIdx.x < 64) cnt[threadIdx.x] = 0;
  __syncthreads();
  const unsigned int* inp = binned + (long)cv * EE + s0;
  for (int i = threadIdx.x; i < n; i += 256) {
    unsigned int p = inp[i];
    buf[i] = p;
    atomicAdd(&cnt[(p >> 16) & 63], 1);
  }
  __syncthreads();
  if (threadIdx.x == 0) {
    int run = 0;
    for (int i = 0; i < 64; ++i) { dofs[i] = run; dcur[i] = run; run += cnt[i]; }
  }
  __syncthreads();
  if (threadIdx.x < 64) {
    int d = (b << 6) + threadIdx.x;
    if (d < 10000) offs_all[(long)cv * 10001 + d] = s0 + dofs[threadIdx.x];
  }
  for (int i = threadIdx.x; i < n; i += 256) {
    unsigned int p = buf[i];
    int pos = atomicAdd(&dcur[(p >> 16) & 63], 1);
    obuf[pos] = (u16)(p & 0xFFFFu);
  }
  __syncthreads();
  u16* outp = srcs + (long)cv * EE + s0;
  for (int i = threadIdx.x; i < n; i += 256) outp[i] = obuf[i];
}

// ============ fused GAT: wave-per-dst, 2 rows per wave-iteration ============
struct GatArgs {
  const int* offs[4];
  const u16* srcs[4];
  const float* es[4];
  const float* ed[4];
  const u16* hs[4];   // stride 384
  const float* bias[4];
};

// 256 threads = 4 waves; wave w handles dst = blockIdx.x*4 + w, half=blockIdx.y.
// Lane l: features fl=(l&31)*4 .. +3; lanes 0-31 edge 2k, lanes 32-63 edge 2k+1.
__global__ void __launch_bounds__(256) gat3(GatArgs ga, float* __restrict__ out,
                                            u16* __restrict__ feat) {
  const int t = threadIdx.x;
  const int w = t >> 6;
  const int lane = t & 63;
  const int hi = lane >> 5;
  const int fl = (lane & 31) << 2;
  const int d = blockIdx.x * 4 + w;
  const int half = blockIdx.y;
  __shared__ float al[4][GCAP + 2];
  __shared__ u16 sl[4][GCAP + 2];
  float a0 = 0.f, a1 = 0.f, a2 = 0.f, a3 = 0.f;
#pragma unroll
  for (int q = 0; q < 2; ++q) {
    const int cv = half * 2 + q;
    const int* offs = ga.offs[cv];
    const int o0 = offs[d], o1 = offs[d + 1];
    const int deg = o1 - o0;
    const u16* sp = ga.srcs[cv] + o0;
    const float* es = ga.es[cv];
    const float edd = ga.ed[cv][d];
    const u16* hs = ga.hs[cv];
    const int degc = deg > GCAP ? GCAP : deg;
    __syncthreads();  // al/sl free from previous q
    float part = 0.f;
    for (int j = lane; j < degc; j += 64) {
      int s = sp[j];
      float e = es[s] + edd;
      e = e > 0.f ? e : 0.2f * e;
      float ex = __expf(e);
      al[w][j] = ex;
      sl[w][j] = (u16)s;
      part += ex;
    }
    for (int j = GCAP + lane; j < deg; j += 64) {  // never taken for this data
      float e = es[sp[j]] + edd;
      e = e > 0.f ? e : 0.2f * e;
      part += __expf(e);
    }
#pragma unroll
    for (int o = 32; o > 0; o >>= 1) part += __shfl_down(part, o);
    const float inv = 1.0f / (__shfl(part, 0) + 1e-16f);
    for (int j = lane; j < degc; j += 64) al[w][j] *= inv;
    if (lane == 0 && (degc & 1)) { al[w][degc] = 0.f; sl[w][degc] = 0; }
    __syncthreads();
    const int npair = (degc + 1) >> 1;
#pragma unroll 4
    for (int k = 0; k < npair; ++k) {
      const int j = 2 * k + hi;
      const float wgt = al[w][j];
      const int s = sl[w][j];
      ushort4 v = *reinterpret_cast<const ushort4*>(hs + (long)s * 384 + fl);
      a0 += wgt * bf2f(v.x);
      a1 += wgt * bf2f(v.y);
      a2 += wgt * bf2f(v.z);
      a3 += wgt * bf2f(v.w);
    }
    if (hi == 0) {
      for (int j = GCAP; j < deg; ++j) {  // never taken
        int s = sp[j];
        float e = es[s] + edd;
        e = e > 0.f ? e : 0.2f * e;
        float wgt = __expf(e) * inv;
        ushort4 v = *reinterpret_cast<const ushort4*>(hs + (long)s * 384 + fl);
        a0 += wgt * bf2f(v.x); a1 += wgt * bf2f(v.y);
        a2 += wgt * bf2f(v.z); a3 += wgt * bf2f(v.w);
      }
    }
  }
  a0 += __shfl_xor(a0, 32);
  a1 += __shfl_xor(a1, 32);
  a2 += __shfl_xor(a2, 32);
  a3 += __shfl_xor(a3, 32);
  if (hi == 0) {
    const float* b1 = ga.bias[half * 2];
    const float* b2 = ga.bias[half * 2 + 1];
    float4 bb1 = *reinterpret_cast<const float4*>(b1 + fl);
    float4 bb2 = *reinterpret_cast<const float4*>(b2 + fl);
    float4 r;
    r.x = fmaxf(a0 + bb1.x + bb2.x, 0.0f);
    r.y = fmaxf(a1 + bb1.y + bb2.y, 0.0f);
    r.z = fmaxf(a2 + bb1.z + bb2.z, 0.0f);
    r.w = fmaxf(a3 + bb1.w + bb2.w, 0.0f);
    *reinterpret_cast<float4*>(out + 16384 + (long)half * ND * HH + (long)d * HH + fl) = r;
    if (half == 0) {
      ushort4 fv;
      fv.x = f2bf(r.x); fv.y = f2bf(r.y); fv.z = f2bf(r.z); fv.w = f2bf(r.w);
      *reinterpret_cast<ushort4*>(feat + (long)d * HH + fl) = fv;
    }
  }
}

// ============ row L2-normalize -> bf16 (with zero pad to Kout) ==============
template <typename T>
__global__ void __launch_bounds__(256) rownorm_kernel(const T* __restrict__ X,
                                                      u16* __restrict__ Y, int Kin, int Kout) {
  const int row = blockIdx.x;
  const int t = threadIdx.x;
  const T* xr = X + (long)row * Kin;
  float ss = 0.f;
  for (int k = t; k < Kin; k += 256) {
    float v = ldval(xr[k]);
    ss += v * v;
  }
#pragma unroll
  for (int o = 32; o > 0; o >>= 1) ss += __shfl_down(ss, o);
  __shared__ float sh[4];
  if ((t & 63) == 0) sh[t >> 6] = ss;
  __syncthreads();
  float tot = sh[0] + sh[1] + sh[2] + sh[3];
  float inv = 1.0f / fmaxf(sqrtf(tot), 1e-12f);
  u16* yr = Y + (long)row * Kout;
  for (int k = t; k < Kin; k += 256) yr[k] = f2bf(ldval(xr[k]) * inv);
  for (int k = Kin + t; k < Kout; k += 256) yr[k] = 0;
}

// ============ hidden = [feat[id1], feat[id2], cell] =========================
__global__ void __launch_bounds__(256) build_hidden_kernel(const u16* __restrict__ feat,
                                                           const int* __restrict__ id1,
                                                           const int* __restrict__ id2,
                                                           const u16* __restrict__ cell,
                                                           u16* __restrict__ hidden) {
  int i = blockIdx.x * 256 + threadIdx.x;
  int row = i >> 9, col = i & 511;
  u16 v;
  if (col < 128) v = feat[(long)id1[row] * HH + col];
  else if (col < 256) v = feat[(long)id2[row] * HH + (col - 128)];
  else v = cell[(long)row * 256 + (col - 256)];
  hidden[i] = v;
}

// ============ logits: [B,128] @ [128,2] + b -> fp32 =========================
__global__ void __launch_bounds__(128) logits_kernel(const u16* __restrict__ h2,
                                                     const float* __restrict__ W,
                                                     const float* __restrict__ b,
                                                     float* __restrict__ out) {
  const int row = blockIdx.x;
  const int t = threadIdx.x;
  float hv = bf2f(h2[(long)row * HH + t]);
  float p0 = hv * W[2 * t], p1 = hv * W[2 * t + 1];
#pragma unroll
  for (int o = 32; o > 0; o >>= 1) {
    p0 += __shfl_down(p0, o);
    p1 += __shfl_down(p1, o);
  }
  __shared__ float sA[2], sB[2];
  if ((t & 63) == 0) { sA[t >> 6] = p0; sB[t >> 6] = p1; }
  __syncthreads();
  if (t == 0) {
    out[2 * row] = sA[0] + sA[1] + b[0];
    out[2 * row + 1] = sB[0] + sB[1] + b[1];
  }
}

extern "C" void kernel_launch(void* const* d_in, const int* in_sizes, int n_in,
                              void* d_out, int out_size, void* d_ws, size_t ws_size,
                              hipStream_t stream) {
  const float* x_drug = (const float*)d_in[0];
  const float* x_target = (const float*)d_in[1];
  const float* cellf = (const float*)d_in[2];
  const float* dd_W = (const float*)d_in[3];
  const float* dd_as = (const float*)d_in[4];
  const float* dd_ad = (const float*)d_in[5];
  const float* dd_b = (const float*)d_in[6];
  const float* dt_Ws = (const float*)d_in[7];
  const float* dt_Wd = (const float*)d_in[8];
  const float* dt_as = (const float*)d_in[9];
  const float* dt_ad = (const float*)d_in[10];
  const float* dt_b = (const float*)d_in[11];
  const float* td_Ws = (const float*)d_in[12];
  const float* td_Wd = (const float*)d_in[13];
  const float* td_as = (const float*)d_in[14];
  const float* td_ad = (const float*)d_in[15];
  const float* td_b = (const float*)d_in[16];
  const float* tt_W = (const float*)d_in[17];
  const float* tt_as = (const float*)d_in[18];
  const float* tt_ad = (const float*)d_in[19];
  const float* tt_b = (const float*)d_in[20];
  const float* r1_W1 = (const float*)d_in[21];
  const float* r1_b1 = (const float*)d_in[22];
  const float* r1_W2 = (const float*)d_in[23];
  const float* r1_b2 = (const float*)d_in[24];
  const float* r1_W3 = (const float*)d_in[25];
  const float* r1_b3 = (const float*)d_in[26];
  const float* r2_W1 = (const float*)d_in[27];
  const float* r2_b1 = (const float*)d_in[28];
  const float* r2_W2 = (const float*)d_in[29];
  const float* r2_b2 = (const float*)d_in[30];
  const float* r2_W3 = (const float*)d_in[31];
  const float* r2_b3 = (const float*)d_in[32];
  const float* cls_W = (const float*)d_in[33];
  const float* cls_b = (const float*)d_in[34];
  const int* src_dd = (const int*)d_in[35];
  const int* dst_dd = (const int*)d_in[36];
  const int* src_dt = (const int*)d_in[37];
  const int* dst_dt = (const int*)d_in[38];
  const int* src_td = (const int*)d_in[39];
  const int* dst_td = (const int*)d_in[40];
  const int* src_tt = (const int*)d_in[41];
  const int* dst_tt = (const int*)d_in[42];
  const int* drug1 = (const int*)d_in[43];
  const int* drug2 = (const int*)d_in[44];
  float* out = (float*)d_out;

  char* ws = (char*)d_ws;
  size_t cur = 0;
  auto alloc = [&](size_t b) {
    size_t r = cur;
    cur += (b + 255) & ~(size_t)255;
    return r;
  };

  u16* xdb = (u16*)(ws + alloc((size_t)MPAD * DF * 2));
  u16* xtb = (u16*)(ws + alloc((size_t)MPAD * TFD * 2));
  u16* Bd = (u16*)(ws + alloc((size_t)384 * DF * 2));
  u16* Bt6 = (u16*)(ws + alloc((size_t)384 * TFD * 2));
  u16* wt1 = (u16*)(ws + alloc((size_t)P1C * CFP * 2));
  u16* wt2 = (u16*)(ws + alloc((size_t)P2C * P1C * 2));
  u16* wt3 = (u16*)(ws + alloc((size_t)256 * P2C * 2));
  u16* wt4 = (u16*)(ws + alloc((size_t)P1C * 512 * 2));
  u16* wt5 = (u16*)(ws + alloc((size_t)P2C * P1C * 2));
  u16* wt6 = (u16*)(ws + alloc((size_t)HH * P2C * 2));
  u16* h6d = (u16*)(ws + alloc((size_t)MPAD * 384 * 2));
  u16* h6t = (u16*)(ws + alloc((size_t)MPAD * 384 * 2));
  float* es0 = (float*)(ws + alloc(ND * 4));
  float* ed0 = (float*)(ws + alloc(ND * 4));
  float* es1 = (float*)(ws + alloc(NT_ * 4));
  float* ed1 = (float*)(ws + alloc(ND * 4));
  float* es2 = (float*)(ws + alloc(ND * 4));
  float* ed2 = (float*)(ws + alloc(NT_ * 4));
  float* es3 = (float*)(ws + alloc(NT_ * 4));
  float* ed3 = (float*)(ws + alloc(NT_ * 4));
  int* hist = (int*)(ws + alloc((size_t)4 * NCH * NBK * 4));
  int* base = (int*)(ws + alloc((size_t)4 * (NBK + 1) * 4));
  int* offs_all = (int*)(ws + alloc((size_t)4 * 10001 * 4));
  unsigned int* binned = (unsigned int*)(ws + alloc((size_t)4 * EE * 4));
  u16* srcs = (u16*)(ws + alloc((size_t)4 * EE * 2));
  u16* feat = (u16*)(ws + alloc((size_t)ND * HH * 2));
  u16* cellnorm = (u16*)(ws + alloc((size_t)BB * CFP * 2));
  u16* big = (u16*)(ws + alloc((size_t)BB * P1C * 2));
  u16* mid = (u16*)(ws + alloc((size_t)BB * P2C * 2));
  u16* cellout = (u16*)(ws + alloc((size_t)BB * 256 * 2));
  u16* hidden = (u16*)(ws + alloc((size_t)BB * 512 * 2));
  u16* hiddennorm = (u16*)(ws + alloc((size_t)BB * 512 * 2));
  u16* h2 = (u16*)(ws + alloc((size_t)BB * HH * 2));

  // ---- x fp32 -> bf16 (padded rows) ----
  xcvt_kernel<<<dim3(MPAD * DF / 8 / 256, 2), 256, 0, stream>>>(x_drug, x_target, xdb, xtb);

  // ---- fused transposes (12) ----
  TransArgs ta;
  const float* tw[12] = {dd_W, td_Wd, dt_Ws, td_Ws, dt_Wd, tt_W, r1_W1, r1_W2, r1_W3, r2_W1, r2_W2, r2_W3};
  u16* twt[12] = {Bd, Bd + 128 * 256, Bd + 2 * 128 * 256, Bt6, Bt6 + 128 * 256, Bt6 + 2 * 128 * 256,
                  wt1, wt2, wt3, wt4, wt5, wt6};
  int tk_[12] = {DF, DF, DF, TFD, TFD, TFD, CF, P1C, P2C, 512, P1C, P2C};
  int tn_[12] = {HH, HH, HH, HH, HH, HH, P1C, P2C, 256, P1C, P2C, HH};
  int tp_[12] = {DF, DF, DF, TFD, TFD, TFD, CFP, P1C, P2C, 512, P1C, P2C};
  for (int i = 0; i < 12; ++i) {
    ta.W[i] = tw[i]; ta.Wt[i] = twt[i]; ta.K[i] = tk_[i]; ta.N[i] = tn_[i]; ta.Kp[i] = tp_[i];
  }
  transpose_all<<<dim3(1920, 12), dim3(32, 8), 0, stream>>>(ta);

  // ---- node GEMMs: [MPAD,256] x [256,384] -> h6 (stride 384) ----
  gemm_db<0, 0><<<(MPAD / 128) * 3, 256, 0, stream>>>(xdb, Bd, nullptr, h6d, MPAD, 384, DF);
  gemm_db<0, 0><<<(MPAD / 128) * 3, 256, 0, stream>>>(xtb, Bt6, nullptr, h6t, MPAD, 384, TFD);

  const u16* h_dd = h6d;
  const u16* h_tdd = h6d + 128;
  const u16* h_dts = h6d + 256;
  const u16* h_tds = h6t;
  const u16* h_dtd = h6t + 128;
  const u16* h_tt = h6t + 256;

  // ---- fused attention logits (4 convs) ----
  EsedArgs ea;
  const u16* ehs[4] = {h_dd, h_tds, h_dts, h_tt};
  const u16* ehd[4] = {h_dd, h_tdd, h_dtd, h_tt};
  const float* eas[4] = {dd_as, td_as, dt_as, tt_as};
  const float* ead[4] = {dd_ad, td_ad, dt_ad, tt_ad};
  float* ees[4] = {es0, es1, es2, es3};
  float* eed[4] = {ed0, ed1, ed2, ed3};
  for (int i = 0; i < 4; ++i) {
    ea.hs[i] = ehs[i]; ea.hd[i] = ehd[i]; ea.as_[i] = eas[i]; ea.ad_[i] = ead[i];
    ea.es[i] = ees[i]; ea.ed[i] = eed[i];
  }
  esed4<<<dim3(10000, 4), 128, 0, stream>>>(ea);

  // ---- binned counting sort -> CSR (conv order: 0=dd, 1=td, 2=dt, 3=tt) ----
  EdgePtrs ep;
  ep.dst[0] = dst_dd; ep.dst[1] = dst_td; ep.dst[2] = dst_dt; ep.dst[3] = dst_tt;
  ep.src[0] = src_dd; ep.src[1] = src_td; ep.src[2] = src_dt; ep.src[3] = src_tt;
  sort_count<<<dim3(NCH, 4), 256, 0, stream>>>(ep, hist);
  sort_scan<<<4, 256, 0, stream>>>(hist, base, offs_all);
  sort_scatter<<<dim3(NCH, 4), 256, 0, stream>>>(ep, hist, base, binned);
  sort_bucket<<<dim3(NBK, 4), 256, 0, stream>>>(binned, base, offs_all, srcs);

  // ---- fused GAT (wave-per-dst) ----
  GatArgs gaa;
  const u16* ghs[4] = {h_dd, h_tds, h_dts, h_tt};
  const float* gbias[4] = {dd_b, td_b, dt_b, tt_b};
  for (int i = 0; i < 4; ++i) {
    gaa.offs[i] = offs_all + (long)i * 10001;
    gaa.srcs[i] = srcs + (long)i * EE;
    gaa.es[i] = ees[i];
    gaa.ed[i] = eed[i];
    gaa.hs[i] = ghs[i];
    gaa.bias[i] = gbias[i];
  }
  gat3<<<dim3(2500, 2), 256, 0, stream>>>(gaa, out, feat);

  // ---- MLP chain (all K mult of 32 via CFP pad) ----
  rownorm_kernel<float><<<BB, 256, 0, stream>>>(cellf, cellnorm, CF, CFP);
  gemm_db<1, 1><<<(BB / 128) * (P1C / 128), 256, 0, stream>>>(cellnorm, wt1, r1_b1, big, BB, P1C, CFP);
  gemm_db<1, 1><<<(BB / 128) * (P2C / 128), 256, 0, stream>>>(big, wt2, r1_b2, mid, BB, P2C, P1C);
  gemm_db<1, 1><<<(BB / 128) * (256 / 128), 256, 0, stream>>>(mid, wt3, r1_b3, cellout, BB, 256, P2C);
  build_hidden_kernel<<<BB * 512 / 256, 256, 0, stream>>>(feat, drug1, drug2, cellout, hidden);
  rownorm_kernel<u16><<<BB, 256, 0, stream>>>(hidden, hiddennorm, 512, 512);
  gemm_db<1, 1><<<(BB / 128) * (P1C / 128), 256, 0, stream>>>(hiddennorm, wt4, r2_b1, big, BB, P1C, 512);
  gemm_db<1, 1><<<(BB / 128) * (P2C / 128), 256, 0, stream>>>(big, wt5, r2_b2, mid, BB, P2C, P1C);
  gemm_db<1, 1><<<(BB / 128) * (HH / 128), 256, 0, stream>>>(mid, wt6, r2_b3, h2, BB, HH, P2C);
  logits_kernel<<<BB, 128, 0, stream>>>(h2, cls_W, cls_b, out);
}

// Round 8
// 342.954 us; speedup vs baseline: 3.0086x; 1.0429x over previous
//
#include <hip/hip_runtime.h>

// Problem constants (fixed by the reference)
#define ND 10000
#define NT_ 10000
#define EE 500000
#define BB 8192
#define DF 256
#define TFD 256
#define HH 128
#define CF 954
#define CFP 960   // padded K for MFMA (zero-filled)
#define P1C 2048
#define P2C 512
#define MPAD 10112  // ND padded to multiple of 128 (and 64)

// sort constants
#define CHUNK 4096
#define NCH 123
#define NBK 157
#define MAXB 6144
#define GCAP 256   // max degree ~82 (Binomial(5e5,1e-4)); big margin + fallback

typedef unsigned short u16;
typedef __attribute__((ext_vector_type(8))) short short8;
typedef __attribute__((ext_vector_type(4))) float f4;

#define AS1 __attribute__((address_space(1)))
#define AS3 __attribute__((address_space(3)))
#define GLOAD16(g, l) \
  __builtin_amdgcn_global_load_lds((const AS1 void*)(g), (AS3 void*)(l), 16, 0, 0)

__device__ inline u16 f2bf(float f) {
  unsigned int u = __builtin_bit_cast(unsigned int, f);
  unsigned int r = (u + 0x7FFFu + ((u >> 16) & 1u)) >> 16;
  return (u16)r;
}
__device__ inline float bf2f(u16 b) {
  return __builtin_bit_cast(float, ((unsigned int)b) << 16);
}
__device__ inline float ldval(float v) { return v; }
__device__ inline float ldval(u16 v) { return bf2f(v); }

__device__ inline void load8cvt(const float* p, u16* dst) {
#pragma unroll
  for (int i = 0; i < 4; ++i) {
    float2 v = reinterpret_cast<const float2*>(p)[i];
    dst[2 * i] = f2bf(v.x);
    dst[2 * i + 1] = f2bf(v.y);
  }
}

// ============ x fp32 -> bf16, rows padded to MPAD with zeros ================
__global__ void __launch_bounds__(256) xcvt_kernel(const float* __restrict__ xd,
                                                   const float* __restrict__ xt,
                                                   u16* __restrict__ xdb,
                                                   u16* __restrict__ xtb) {
  const float* X = blockIdx.y ? xt : xd;
  u16* Y = blockIdx.y ? xtb : xdb;
  long i = (long)blockIdx.x * 256 + threadIdx.x;  // one 8-elem chunk each
  long e = i * 8;
  int row = (int)(e >> 8);
  union { u16 u[8]; short8 v; } tv;
  if (row < ND) {
    load8cvt(X + e, tv.u);
  } else {
#pragma unroll
    for (int k = 0; k < 8; ++k) tv.u[k] = 0;
  }
  *reinterpret_cast<short8*>(Y + e) = tv.v;
}

// ============ fused weight transpose: fp32 [K,N] -> bf16 [N,Kp] (zero pad) ==
struct TransArgs {
  const float* W[12];
  u16* Wt[12];
  int K[12];
  int N[12];
  int Kp[12];
};

__global__ void __launch_bounds__(256) transpose_all(TransArgs ta) {
  const int id = blockIdx.y;
  const int K = ta.K[id], N = ta.N[id], Kp = ta.Kp[id];
  const int tn = (N + 31) >> 5, tk = (Kp + 31) >> 5;
  if ((int)blockIdx.x >= tn * tk) return;
  const float* W = ta.W[id];
  u16* Wt = ta.Wt[id];
  const int bn = (blockIdx.x % tn) << 5;
  const int bk = (blockIdx.x / tn) << 5;
  __shared__ u16 tile[32][33];
  const int tx = threadIdx.x;
  const int ty = threadIdx.y;
#pragma unroll
  for (int i = ty; i < 32; i += 8) {
    int k = bk + i, n = bn + tx;
    tile[i][tx] = (k < K && n < N) ? f2bf(W[(long)k * N + n]) : (u16)0;
  }
  __syncthreads();
#pragma unroll
  for (int i = ty; i < 32; i += 8) {
    int n = bn + i, k = bk + tx;
    if (n < N && k < Kp) Wt[(long)n * Kp + k] = tile[tx][i];
  }
}

// ============ T3-minimal double-buffered bf16 GEMM, 128x128 tile ============
// C[M,N] = act(A[M,K] @ Bt[N,K]^T + bias).  M%128==0, N%128==0, K%32==0.
template <int ACT, int BIAS>
__global__ void __launch_bounds__(256) gemm_db(const u16* __restrict__ A,
                                               const u16* __restrict__ Bt,
                                               const float* __restrict__ bias,
                                               u16* __restrict__ C, int M, int N, int K) {
  const int tiles_n = N >> 7;
  const int bm = blockIdx.x / tiles_n;
  const int bn = blockIdx.x % tiles_n;
  const long row0 = (long)bm << 7;
  const int col0 = bn << 7;
  __shared__ u16 sh[16384];  // 32 KB: buf b: A at b*8192, B at b*8192+4096
  const int t = threadIdx.x;
  const int lane = t & 63;
  const int w = t >> 6;
  const int wr = w >> 1, wc = w & 1;
  const int lr = lane & 15, lk = lane >> 4;
  const int srow = lane >> 2;
  const int scol = (lane & 3) << 3;
  const u16* gA0 = A + (row0 + (w << 4) + srow) * K + scol;
  const u16* gA1 = A + (row0 + ((w + 4) << 4) + srow) * K + scol;
  const u16* gB0 = Bt + ((long)col0 + (w << 4) + srow) * K + scol;
  const u16* gB1 = Bt + ((long)col0 + ((w + 4) << 4) + srow) * K + scol;
  const int lofs0 = (w << 4) * 32;
  const int lofs1 = ((w + 4) << 4) * 32;
  f4 acc[4][4] = {};
  const int nk = K >> 5;

#define STAGE4(kt_, b_)                                     \
  do {                                                      \
    const int ko = (kt_) << 5;                              \
    u16* ab = sh + (b_) * 8192;                             \
    u16* bb = ab + 4096;                                    \
    GLOAD16(gA0 + ko, ab + lofs0);                          \
    GLOAD16(gA1 + ko, ab + lofs1);                          \
    GLOAD16(gB0 + ko, bb + lofs0);                          \
    GLOAD16(gB1 + ko, bb + lofs1);                          \
  } while (0)

  STAGE4(0, 0);
  __syncthreads();
  int cur = 0;
  for (int kt = 0; kt < nk; ++kt) {
    if (kt + 1 < nk) STAGE4(kt + 1, cur ^ 1);
    const u16* Ab = sh + cur * 8192;
    const u16* Bb = Ab + 4096;
    short8 af[4], bf[4];
#pragma unroll
    for (int m = 0; m < 4; ++m)
      af[m] = *reinterpret_cast<const short8*>(&Ab[(((wr << 6) + (m << 4) + lr) << 5) + (lk << 3)]);
#pragma unroll
    for (int n = 0; n < 4; ++n)
      bf[n] = *reinterpret_cast<const short8*>(&Bb[(((wc << 6) + (n << 4) + lr) << 5) + (lk << 3)]);
#pragma unroll
    for (int m = 0; m < 4; ++m)
#pragma unroll
      for (int n = 0; n < 4; ++n)
        acc[m][n] = __builtin_amdgcn_mfma_f32_16x16x32_bf16(af[m], bf[n], acc[m][n], 0, 0, 0);
    __syncthreads();
    cur ^= 1;
  }
#undef STAGE4

  float bv[4];
#pragma unroll
  for (int n = 0; n < 4; ++n)
    bv[n] = BIAS ? bias[col0 + (wc << 6) + (n << 4) + lr] : 0.0f;
#pragma unroll
  for (int m = 0; m < 4; ++m) {
#pragma unroll
    for (int n = 0; n < 4; ++n) {
      const int col = (wc << 6) + (n << 4) + lr;
#pragma unroll
      for (int r = 0; r < 4; ++r) {
        const int row = (wr << 6) + (m << 4) + (lk << 2) + r;
        float x = acc[m][n][r] + bv[n];
        if (ACT) x = fmaxf(x, 0.0f);
        sh[(row << 7) + col] = f2bf(x);
      }
    }
  }
  __syncthreads();
#pragma unroll
  for (int i = 0; i < 8; ++i) {
    const int c = t + (i << 8);
    const int rr = c >> 4, off = (c & 15) << 3;
    *reinterpret_cast<short8*>(&C[(row0 + rr) * N + col0 + off]) =
        *reinterpret_cast<const short8*>(&sh[(rr << 7) + off]);
  }
}

// ============ 64x128-tile dbuf GEMM for small-N / occupancy-starved shapes ==
// Same structure; 24KB LDS -> up to 6 blocks/CU. M%64==0, N%128==0, K%32==0.
template <int ACT, int BIAS>
__global__ void __launch_bounds__(256) gemm_db64(const u16* __restrict__ A,
                                                 const u16* __restrict__ Bt,
                                                 const float* __restrict__ bias,
                                                 u16* __restrict__ C, int M, int N, int K) {
  const int tiles_n = N >> 7;
  const int bm = blockIdx.x / tiles_n;
  const int bn = blockIdx.x % tiles_n;
  const long row0 = (long)bm << 6;  // 64-row tile
  const int col0 = bn << 7;
  __shared__ u16 sh[12288];  // 24KB: buf b at b*6144; A [64][32] then B [128][32]
  const int t = threadIdx.x;
  const int lane = t & 63;
  const int w = t >> 6;
  const int wr = w >> 1, wc = w & 1;  // wave -> 32-row x 64-col quadrant
  const int lr = lane & 15, lk = lane >> 4;
  const int srow = lane >> 2;
  const int scol = (lane & 3) << 3;
  const u16* gA0 = A + (row0 + (w << 4) + srow) * K + scol;   // w<4 -> rows 0..63
  const u16* gB0 = Bt + ((long)col0 + (w << 4) + srow) * K + scol;
  const u16* gB1 = Bt + ((long)col0 + ((w + 4) << 4) + srow) * K + scol;
  const int lofs0 = (w << 4) * 32;
  const int lofs1 = ((w + 4) << 4) * 32;
  f4 acc[2][4] = {};
  const int nk = K >> 5;

#define STAGE3(kt_, b_)                                     \
  do {                                                      \
    const int ko = (kt_) << 5;                              \
    u16* ab = sh + (b_) * 6144;                             \
    u16* bb = ab + 2048;                                    \
    GLOAD16(gA0 + ko, ab + lofs0);                          \
    GLOAD16(gB0 + ko, bb + lofs0);                          \
    GLOAD16(gB1 + ko, bb + lofs1);                          \
  } while (0)

  STAGE3(0, 0);
  __syncthreads();
  int cur = 0;
  for (int kt = 0; kt < nk; ++kt) {
    if (kt + 1 < nk) STAGE3(kt + 1, cur ^ 1);
    const u16* Ab = sh + cur * 6144;
    const u16* Bb = Ab + 2048;
    short8 af[2], bf[4];
#pragma unroll
    for (int m = 0; m < 2; ++m)
      af[m] = *reinterpret_cast<const short8*>(&Ab[(((wr << 5) + (m << 4) + lr) << 5) + (lk << 3)]);
#pragma unroll
    for (int n = 0; n < 4; ++n)
      bf[n] = *reinterpret_cast<const short8*>(&Bb[(((wc << 6) + (n << 4) + lr) << 5) + (lk << 3)]);
#pragma unroll
    for (int m = 0; m < 2; ++m)
#pragma unroll
      for (int n = 0; n < 4; ++n)
        acc[m][n] = __builtin_amdgcn_mfma_f32_16x16x32_bf16(af[m], bf[n], acc[m][n], 0, 0, 0);
    __syncthreads();
    cur ^= 1;
  }
#undef STAGE3

  float bv[4];
#pragma unroll
  for (int n = 0; n < 4; ++n)
    bv[n] = BIAS ? bias[col0 + (wc << 6) + (n << 4) + lr] : 0.0f;
  // epilogue: stage 64x128 C (16KB) in sh, then coalesced 16B stores
#pragma unroll
  for (int m = 0; m < 2; ++m) {
#pragma unroll
    for (int n = 0; n < 4; ++n) {
      const int col = (wc << 6) + (n << 4) + lr;
#pragma unroll
      for (int r = 0; r < 4; ++r) {
        const int row = (wr << 5) + (m << 4) + (lk << 2) + r;
        float x = acc[m][n][r] + bv[n];
        if (ACT) x = fmaxf(x, 0.0f);
        sh[(row << 7) + col] = f2bf(x);
      }
    }
  }
  __syncthreads();
#pragma unroll
  for (int i = 0; i < 4; ++i) {
    const int c = t + (i << 8);       // 0..1023 chunks of 16B
    const int rr = c >> 4, off = (c & 15) << 3;
    *reinterpret_cast<short8*>(&C[(row0 + rr) * N + col0 + off]) =
        *reinterpret_cast<const short8*>(&sh[(rr << 7) + off]);
  }
}

// ============ fused per-node attention logits (4 convs, h stride 384) =======
struct EsedArgs {
  const u16* hs[4];
  const u16* hd[4];
  const float* as_[4];
  const float* ad_[4];
  float* es[4];
  float* ed[4];
};

__global__ void __launch_bounds__(128) esed4(EsedArgs ea) {
  const int cv = blockIdx.y;
  const int row = blockIdx.x;
  const int t = threadIdx.x;
  float ps = bf2f(ea.hs[cv][(long)row * 384 + t]) * ea.as_[cv][t];
  float pd = bf2f(ea.hd[cv][(long)row * 384 + t]) * ea.ad_[cv][t];
#pragma unroll
  for (int o = 32; o > 0; o >>= 1) {
    ps += __shfl_down(ps, o);
    pd += __shfl_down(pd, o);
  }
  __shared__ float s0[2], s1[2];
  if ((t & 63) == 0) { s0[t >> 6] = ps; s1[t >> 6] = pd; }
  __syncthreads();
  if (t == 0) {
    ea.es[cv][row] = s0[0] + s0[1];
    ea.ed[cv][row] = s1[0] + s1[1];
  }
}

// ============ binned counting sort (coalesced CSR build) ====================
struct EdgePtrs {
  const int* dst[4];
  const int* src[4];
};

__global__ void __launch_bounds__(256) sort_count(EdgePtrs ep, int* __restrict__ hist) {
  const int cv = blockIdx.y, ch = blockIdx.x;
  __shared__ int h[NBK];
  for (int i = threadIdx.x; i < NBK; i += 256) h[i] = 0;
  __syncthreads();
  const int* dst = ep.dst[cv];
  const int e0 = ch * CHUNK;
  const int e1 = e0 + CHUNK < EE ? e0 + CHUNK : EE;
  for (int i = e0 + threadIdx.x; i < e1; i += 256) atomicAdd(&h[dst[i] >> 6], 1);
  __syncthreads();
  int* out = hist + ((long)cv * NCH + ch) * NBK;
  for (int i = threadIdx.x; i < NBK; i += 256) out[i] = h[i];
}

__global__ void __launch_bounds__(256) sort_scan(int* __restrict__ hist, int* __restrict__ base,
                                                 int* __restrict__ offs_all) {
  const int cv = blockIdx.x;
  int* H = hist + (long)cv * NCH * NBK;
  __shared__ int tot[NBK];
  for (int b = threadIdx.x; b < NBK; b += 256) {
    int run = 0;
    for (int ch = 0; ch < NCH; ++ch) {
      int v = H[ch * NBK + b];
      H[ch * NBK + b] = run;
      run += v;
    }
    tot[b] = run;
  }
  __syncthreads();
  if (threadIdx.x == 0) {
    int* B = base + cv * (NBK + 1);
    int run = 0;
    for (int b = 0; b < NBK; ++b) { B[b] = run; run += tot[b]; }
    B[NBK] = run;
    offs_all[(long)cv * 10001 + 10000] = run;
  }
}

__global__ void __launch_bounds__(256) sort_scatter(EdgePtrs ep, const int* __restrict__ hist,
                                                    const int* __restrict__ base,
                                                    unsigned int* __restrict__ binned) {
  const int cv = blockIdx.y, ch = blockIdx.x;
  __shared__ int lcnt[NBK];
  __shared__ int lofs[NBK];
  __shared__ int lcur[NBK];
  __shared__ int sofs[NBK];
  __shared__ unsigned int buf[CHUNK];
  for (int i = threadIdx.x; i < NBK; i += 256) lcnt[i] = 0;
  __syncthreads();
  const int* dst = ep.dst[cv];
  const int* src = ep.src[cv];
  const int e0 = ch * CHUNK;
  const int e1 = e0 + CHUNK < EE ? e0 + CHUNK : EE;
  const int n = e1 - e0;
  unsigned int pk[16];
#pragma unroll
  for (int u = 0; u < 16; ++u) {
    int i = e0 + u * 256 + threadIdx.x;
    unsigned int p = 0xFFFFFFFFu;
    if (i < e1) {
      int d = dst[i];
      p = ((unsigned int)d << 16) | (unsigned int)src[i];
      atomicAdd(&lcnt[d >> 6], 1);
    }
    pk[u] = p;
  }
  {
    const int* chOfs = hist + ((long)cv * NCH + ch) * NBK;
    const int* B = base + cv * (NBK + 1);
    for (int b = threadIdx.x; b < NBK; b += 256) sofs[b] = B[b] + chOfs[b];
  }
  __syncthreads();
  if (threadIdx.x == 0) {
    int run = 0;
    for (int b = 0; b < NBK; ++b) { lofs[b] = run; lcur[b] = run; run += lcnt[b]; }
  }
  __syncthreads();
#pragma unroll
  for (int u = 0; u < 16; ++u) {
    if (pk[u] != 0xFFFFFFFFu) {
      int b = pk[u] >> 22;
      int p = atomicAdd(&lcur[b], 1);
      buf[p] = pk[u];
    }
  }
  __syncthreads();
  unsigned int* outp = binned + (long)cv * EE;
  for (int i = threadIdx.x; i < n; i += 256) {
    unsigned int p = buf[i];
    int b = p >> 22;
    outp[sofs[b] + (i - lofs[b])] = p;
  }
}

__global__ void __launch_bounds__(256) sort_bucket(const unsigned int* __restrict__ binned,
                                                   const int* __restrict__ base,
                                                   int* __restrict__ offs_all,
                                                   u16* __restrict__ srcs) {
  const int cv = blockIdx.y, b = blockIdx.x;
  const int* B = base + cv * (NBK + 1);
  const int s0 = B[b], s1 = B[b + 1];
  int n = s1 - s0;
  if (n > MAXB) n = MAXB;
  __shared__ unsigned int buf[MAXB];
  __shared__ u16 obuf[MAXB];
  __shared__ int cnt[64], dofs[64], dcur[64];
  if (threadIdx.x < 64) cnt[threadIdx.x] = 0;
  __syncthreads();
  const unsigned int* inp = binned + (long)cv * EE + s0;
  for (int i = threadIdx.x; i < n; i += 256) {
    unsigned int p = inp[i];
    buf[i] = p;
    atomicAdd(&cnt[(p >> 16) & 63], 1);
  }
  __syncthreads();
  if (threadIdx.x == 0) {
    int run = 0;
    for (int i = 0; i < 64; ++i) { dofs[i] = run; dcur[i] = run; run += cnt[i]; }
  }
  __syncthreads();
  if (threadIdx.x < 64) {
    int d = (b << 6) + threadIdx.x;
    if (d < 10000) offs_all[(long)cv * 10001 + d] = s0 + dofs[threadIdx.x];
  }
  for (int i = threadIdx.x; i < n; i += 256) {
    unsigned int p = buf[i];
    int pos = atomicAdd(&dcur[(p >> 16) & 63], 1);
    obuf[pos] = (u16)(p & 0xFFFFu);
  }
  __syncthreads();
  u16* outp = srcs + (long)cv * EE + s0;
  for (int i = threadIdx.x; i < n; i += 256) outp[i] = obuf[i];
}

// ============ fused GAT: wave-per-dst, 2 rows per wave-iteration ============
struct GatArgs {
  const int* offs[4];
  const u16* srcs[4];
  const float* es[4];
  const float* ed[4];
  const u16* hs[4];   // stride 384
  const float* bias[4];
};

__global__ void __launch_bounds__(256) gat3(GatArgs ga, float* __restrict__ out,
                                            u16* __restrict__ feat) {
  const int t = threadIdx.x;
  const int w = t >> 6;
  const int lane = t & 63;
  const int hi = lane >> 5;
  const int fl = (lane & 31) << 2;
  const int d = blockIdx.x * 4 + w;
  const int half = blockIdx.y;
  __shared__ float al[4][GCAP + 2];
  __shared__ u16 sl[4][GCAP + 2];
  float a0 = 0.f, a1 = 0.f, a2 = 0.f, a3 = 0.f;
#pragma unroll
  for (int q = 0; q < 2; ++q) {
    const int cv = half * 2 + q;
    const int* offs = ga.offs[cv];
    const int o0 = offs[d], o1 = offs[d + 1];
    const int deg = o1 - o0;
    const u16* sp = ga.srcs[cv] + o0;
    const float* es = ga.es[cv];
    const float edd = ga.ed[cv][d];
    const u16* hs = ga.hs[cv];
    const int degc = deg > GCAP ? GCAP : deg;
    __syncthreads();
    float part = 0.f;
    for (int j = lane; j < degc; j += 64) {
      int s = sp[j];
      float e = es[s] + edd;
      e = e > 0.f ? e : 0.2f * e;
      float ex = __expf(e);
      al[w][j] = ex;
      sl[w][j] = (u16)s;
      part += ex;
    }
    for (int j = GCAP + lane; j < deg; j += 64) {  // never taken for this data
      float e = es[sp[j]] + edd;
      e = e > 0.f ? e : 0.2f * e;
      part += __expf(e);
    }
#pragma unroll
    for (int o = 32; o > 0; o >>= 1) part += __shfl_down(part, o);
    const float inv = 1.0f / (__shfl(part, 0) + 1e-16f);
    for (int j = lane; j < degc; j += 64) al[w][j] *= inv;
    if (lane == 0 && (degc & 1)) { al[w][degc] = 0.f; sl[w][degc] = 0; }
    __syncthreads();
    const int npair = (degc + 1) >> 1;
#pragma unroll 4
    for (int k = 0; k < npair; ++k) {
      const int j = 2 * k + hi;
      const float wgt = al[w][j];
      const int s = sl[w][j];
      ushort4 v = *reinterpret_cast<const ushort4*>(hs + (long)s * 384 + fl);
      a0 += wgt * bf2f(v.x);
      a1 += wgt * bf2f(v.y);
      a2 += wgt * bf2f(v.z);
      a3 += wgt * bf2f(v.w);
    }
    if (hi == 0) {
      for (int j = GCAP; j < deg; ++j) {  // never taken
        int s = sp[j];
        float e = es[s] + edd;
        e = e > 0.f ? e : 0.2f * e;
        float wgt = __expf(e) * inv;
        ushort4 v = *reinterpret_cast<const ushort4*>(hs + (long)s * 384 + fl);
        a0 += wgt * bf2f(v.x); a1 += wgt * bf2f(v.y);
        a2 += wgt * bf2f(v.z); a3 += wgt * bf2f(v.w);
      }
    }
  }
  a0 += __shfl_xor(a0, 32);
  a1 += __shfl_xor(a1, 32);
  a2 += __shfl_xor(a2, 32);
  a3 += __shfl_xor(a3, 32);
  if (hi == 0) {
    const float* b1 = ga.bias[half * 2];
    const float* b2 = ga.bias[half * 2 + 1];
    float4 bb1 = *reinterpret_cast<const float4*>(b1 + fl);
    float4 bb2 = *reinterpret_cast<const float4*>(b2 + fl);
    float4 r;
    r.x = fmaxf(a0 + bb1.x + bb2.x, 0.0f);
    r.y = fmaxf(a1 + bb1.y + bb2.y, 0.0f);
    r.z = fmaxf(a2 + bb1.z + bb2.z, 0.0f);
    r.w = fmaxf(a3 + bb1.w + bb2.w, 0.0f);
    *reinterpret_cast<float4*>(out + 16384 + (long)half * ND * HH + (long)d * HH + fl) = r;
    if (half == 0) {
      ushort4 fv;
      fv.x = f2bf(r.x); fv.y = f2bf(r.y); fv.z = f2bf(r.z); fv.w = f2bf(r.w);
      *reinterpret_cast<ushort4*>(feat + (long)d * HH + fl) = fv;
    }
  }
}

// ============ row L2-normalize -> bf16 (with zero pad to Kout) ==============
template <typename T>
__global__ void __launch_bounds__(256) rownorm_kernel(const T* __restrict__ X,
                                                      u16* __restrict__ Y, int Kin, int Kout) {
  const int row = blockIdx.x;
  const int t = threadIdx.x;
  const T* xr = X + (long)row * Kin;
  float ss = 0.f;
  for (int k = t; k < Kin; k += 256) {
    float v = ldval(xr[k]);
    ss += v * v;
  }
#pragma unroll
  for (int o = 32; o > 0; o >>= 1) ss += __shfl_down(ss, o);
  __shared__ float sh[4];
  if ((t & 63) == 0) sh[t >> 6] = ss;
  __syncthreads();
  float tot = sh[0] + sh[1] + sh[2] + sh[3];
  float inv = 1.0f / fmaxf(sqrtf(tot), 1e-12f);
  u16* yr = Y + (long)row * Kout;
  for (int k = t; k < Kin; k += 256) yr[k] = f2bf(ldval(xr[k]) * inv);
  for (int k = Kin + t; k < Kout; k += 256) yr[k] = 0;
}

// ============ hidden = [feat[id1], feat[id2], cell] =========================
__global__ void __launch_bounds__(256) build_hidden_kernel(const u16* __restrict__ feat,
                                                           const int* __restrict__ id1,
                                                           const int* __restrict__ id2,
                                                           const u16* __restrict__ cell,
                                                           u16* __restrict__ hidden) {
  int i = blockIdx.x * 256 + threadIdx.x;
  int row = i >> 9, col = i & 511;
  u16 v;
  if (col < 128) v = feat[(long)id1[row] * HH + col];
  else if (col < 256) v = feat[(long)id2[row] * HH + (col - 128)];
  else v = cell[(long)row * 256 + (col - 256)];
  hidden[i] = v;
}

// ============ logits: [B,128] @ [128,2] + b -> fp32 =========================
__global__ void __launch_bounds__(128) logits_kernel(const u16* __restrict__ h2,
                                                     const float* __restrict__ W,
                                                     const float* __restrict__ b,
                                                     float* __restrict__ out) {
  const int row = blockIdx.x;
  const int t = threadIdx.x;
  float hv = bf2f(h2[(long)row * HH + t]);
  float p0 = hv * W[2 * t], p1 = hv * W[2 * t + 1];
#pragma unroll
  for (int o = 32; o > 0; o >>= 1) {
    p0 += __shfl_down(p0, o);
    p1 += __shfl_down(p1, o);
  }
  __shared__ float sA[2], sB[2];
  if ((t & 63) == 0) { sA[t >> 6] = p0; sB[t >> 6] = p1; }
  __syncthreads();
  if (t == 0) {
    out[2 * row] = sA[0] + sA[1] + b[0];
    out[2 * row + 1] = sB[0] + sB[1] + b[1];
  }
}

extern "C" void kernel_launch(void* const* d_in, const int* in_sizes, int n_in,
                              void* d_out, int out_size, void* d_ws, size_t ws_size,
                              hipStream_t stream) {
  const float* x_drug = (const float*)d_in[0];
  const float* x_target = (const float*)d_in[1];
  const float* cellf = (const float*)d_in[2];
  const float* dd_W = (const float*)d_in[3];
  const float* dd_as = (const float*)d_in[4];
  const float* dd_ad = (const float*)d_in[5];
  const float* dd_b = (const float*)d_in[6];
  const float* dt_Ws = (const float*)d_in[7];
  const float* dt_Wd = (const float*)d_in[8];
  const float* dt_as = (const float*)d_in[9];
  const float* dt_ad = (const float*)d_in[10];
  const float* dt_b = (const float*)d_in[11];
  const float* td_Ws = (const float*)d_in[12];
  const float* td_Wd = (const float*)d_in[13];
  const float* td_as = (const float*)d_in[14];
  const float* td_ad = (const float*)d_in[15];
  const float* td_b = (const float*)d_in[16];
  const float* tt_W = (const float*)d_in[17];
  const float* tt_as = (const float*)d_in[18];
  const float* tt_ad = (const float*)d_in[19];
  const float* tt_b = (const float*)d_in[20];
  const float* r1_W1 = (const float*)d_in[21];
  const float* r1_b1 = (const float*)d_in[22];
  const float* r1_W2 = (const float*)d_in[23];
  const float* r1_b2 = (const float*)d_in[24];
  const float* r1_W3 = (const float*)d_in[25];
  const float* r1_b3 = (const float*)d_in[26];
  const float* r2_W1 = (const float*)d_in[27];
  const float* r2_b1 = (const float*)d_in[28];
  const float* r2_W2 = (const float*)d_in[29];
  const float* r2_b2 = (const float*)d_in[30];
  const float* r2_W3 = (const float*)d_in[31];
  const float* r2_b3 = (const float*)d_in[32];
  const float* cls_W = (const float*)d_in[33];
  const float* cls_b = (const float*)d_in[34];
  const int* src_dd = (const int*)d_in[35];
  const int* dst_dd = (const int*)d_in[36];
  const int* src_dt = (const int*)d_in[37];
  const int* dst_dt = (const int*)d_in[38];
  const int* src_td = (const int*)d_in[39];
  const int* dst_td = (const int*)d_in[40];
  const int* src_tt = (const int*)d_in[41];
  const int* dst_tt = (const int*)d_in[42];
  const int* drug1 = (const int*)d_in[43];
  const int* drug2 = (const int*)d_in[44];
  float* out = (float*)d_out;

  char* ws = (char*)d_ws;
  size_t cur = 0;
  auto alloc = [&](size_t b) {
    size_t r = cur;
    cur += (b + 255) & ~(size_t)255;
    return r;
  };

  u16* xdb = (u16*)(ws + alloc((size_t)MPAD * DF * 2));
  u16* xtb = (u16*)(ws + alloc((size_t)MPAD * TFD * 2));
  u16* Bd = (u16*)(ws + alloc((size_t)384 * DF * 2));
  u16* Bt6 = (u16*)(ws + alloc((size_t)384 * TFD * 2));
  u16* wt1 = (u16*)(ws + alloc((size_t)P1C * CFP * 2));
  u16* wt2 = (u16*)(ws + alloc((size_t)P2C * P1C * 2));
  u16* wt3 = (u16*)(ws + alloc((size_t)256 * P2C * 2));
  u16* wt4 = (u16*)(ws + alloc((size_t)P1C * 512 * 2));
  u16* wt5 = (u16*)(ws + alloc((size_t)P2C * P1C * 2));
  u16* wt6 = (u16*)(ws + alloc((size_t)HH * P2C * 2));
  u16* h6d = (u16*)(ws + alloc((size_t)MPAD * 384 * 2));
  u16* h6t = (u16*)(ws + alloc((size_t)MPAD * 384 * 2));
  float* es0 = (float*)(ws + alloc(ND * 4));
  float* ed0 = (float*)(ws + alloc(ND * 4));
  float* es1 = (float*)(ws + alloc(NT_ * 4));
  float* ed1 = (float*)(ws + alloc(ND * 4));
  float* es2 = (float*)(ws + alloc(ND * 4));
  float* ed2 = (float*)(ws + alloc(NT_ * 4));
  float* es3 = (float*)(ws + alloc(NT_ * 4));
  float* ed3 = (float*)(ws + alloc(NT_ * 4));
  int* hist = (int*)(ws + alloc((size_t)4 * NCH * NBK * 4));
  int* base = (int*)(ws + alloc((size_t)4 * (NBK + 1) * 4));
  int* offs_all = (int*)(ws + alloc((size_t)4 * 10001 * 4));
  unsigned int* binned = (unsigned int*)(ws + alloc((size_t)4 * EE * 4));
  u16* srcs = (u16*)(ws + alloc((size_t)4 * EE * 2));
  u16* feat = (u16*)(ws + alloc((size_t)ND * HH * 2));
  u16* cellnorm = (u16*)(ws + alloc((size_t)BB * CFP * 2));
  u16* big = (u16*)(ws + alloc((size_t)BB * P1C * 2));
  u16* mid = (u16*)(ws + alloc((size_t)BB * P2C * 2));
  u16* cellout = (u16*)(ws + alloc((size_t)BB * 256 * 2));
  u16* hidden = (u16*)(ws + alloc((size_t)BB * 512 * 2));
  u16* hiddennorm = (u16*)(ws + alloc((size_t)BB * 512 * 2));
  u16* h2 = (u16*)(ws + alloc((size_t)BB * HH * 2));

  // ---- x fp32 -> bf16 (padded rows) ----
  xcvt_kernel<<<dim3(MPAD * DF / 8 / 256, 2), 256, 0, stream>>>(x_drug, x_target, xdb, xtb);

  // ---- fused transposes (12) ----
  TransArgs ta;
  const float* tw[12] = {dd_W, td_Wd, dt_Ws, td_Ws, dt_Wd, tt_W, r1_W1, r1_W2, r1_W3, r2_W1, r2_W2, r2_W3};
  u16* twt[12] = {Bd, Bd + 128 * 256, Bd + 2 * 128 * 256, Bt6, Bt6 + 128 * 256, Bt6 + 2 * 128 * 256,
                  wt1, wt2, wt3, wt4, wt5, wt6};
  int tk_[12] = {DF, DF, DF, TFD, TFD, TFD, CF, P1C, P2C, 512, P1C, P2C};
  int tn_[12] = {HH, HH, HH, HH, HH, HH, P1C, P2C, 256, P1C, P2C, HH};
  int tp_[12] = {DF, DF, DF, TFD, TFD, TFD, CFP, P1C, P2C, 512, P1C, P2C};
  for (int i = 0; i < 12; ++i) {
    ta.W[i] = tw[i]; ta.Wt[i] = twt[i]; ta.K[i] = tk_[i]; ta.N[i] = tn_[i]; ta.Kp[i] = tp_[i];
  }
  transpose_all<<<dim3(1920, 12), dim3(32, 8), 0, stream>>>(ta);

  // ---- node GEMMs: [MPAD,256] x [256,384] -> h6 (stride 384), 64-row tiles --
  gemm_db64<0, 0><<<(MPAD / 64) * 3, 256, 0, stream>>>(xdb, Bd, nullptr, h6d, MPAD, 384, DF);
  gemm_db64<0, 0><<<(MPAD / 64) * 3, 256, 0, stream>>>(xtb, Bt6, nullptr, h6t, MPAD, 384, TFD);

  const u16* h_dd = h6d;
  const u16* h_tdd = h6d + 128;
  const u16* h_dts = h6d + 256;
  const u16* h_tds = h6t;
  const u16* h_dtd = h6t + 128;
  const u16* h_tt = h6t + 256;

  // ---- fused attention logits (4 convs) ----
  EsedArgs ea;
  const u16* ehs[4] = {h_dd, h_tds, h_dts, h_tt};
  const u16* ehd[4] = {h_dd, h_tdd, h_dtd, h_tt};
  const float* eas[4] = {dd_as, td_as, dt_as, tt_as};
  const float* ead[4] = {dd_ad, td_ad, dt_ad, tt_ad};
  float* ees[4] = {es0, es1, es2, es3};
  float* eed[4] = {ed0, ed1, ed2, ed3};
  for (int i = 0; i < 4; ++i) {
    ea.hs[i] = ehs[i]; ea.hd[i] = ehd[i]; ea.as_[i] = eas[i]; ea.ad_[i] = ead[i];
    ea.es[i] = ees[i]; ea.ed[i] = eed[i];
  }
  esed4<<<dim3(10000, 4), 128, 0, stream>>>(ea);

  // ---- binned counting sort -> CSR (conv order: 0=dd, 1=td, 2=dt, 3=tt) ----
  EdgePtrs ep;
  ep.dst[0] = dst_dd; ep.dst[1] = dst_td; ep.dst[2] = dst_dt; ep.dst[3] = dst_tt;
  ep.src[0] = src_dd; ep.src[1] = src_td; ep.src[2] = src_dt; ep.src[3] = src_tt;
  sort_count<<<dim3(NCH, 4), 256, 0, stream>>>(ep, hist);
  sort_scan<<<4, 256, 0, stream>>>(hist, base, offs_all);
  sort_scatter<<<dim3(NCH, 4), 256, 0, stream>>>(ep, hist, base, binned);
  sort_bucket<<<dim3(NBK, 4), 256, 0, stream>>>(binned, base, offs_all, srcs);

  // ---- fused GAT (wave-per-dst) ----
  GatArgs gaa;
  const u16* ghs[4] = {h_dd, h_tds, h_dts, h_tt};
  const float* gbias[4] = {dd_b, td_b, dt_b, tt_b};
  for (int i = 0; i < 4; ++i) {
    gaa.offs[i] = offs_all + (long)i * 10001;
    gaa.srcs[i] = srcs + (long)i * EE;
    gaa.es[i] = ees[i];
    gaa.ed[i] = eed[i];
    gaa.hs[i] = ghs[i];
    gaa.bias[i] = gbias[i];
  }
  gat3<<<dim3(2500, 2), 256, 0, stream>>>(gaa, out, feat);

  // ---- MLP chain ----
  rownorm_kernel<float><<<BB, 256, 0, stream>>>(cellf, cellnorm, CF, CFP);
  // GEMM1: N=2048 (1024-block grid) -> 128x128 tile
  gemm_db<1, 1><<<(BB / 128) * (P1C / 128), 256, 0, stream>>>(cellnorm, wt1, r1_b1, big, BB, P1C, CFP);
  // GEMM2: N=512, K=2048 -> 64-row tiles (512 blocks, 2/CU)
  gemm_db64<1, 1><<<(BB / 64) * (P2C / 128), 256, 0, stream>>>(big, wt2, r1_b2, mid, BB, P2C, P1C);
  // GEMM3: N=256 -> 64-row tiles
  gemm_db64<1, 1><<<(BB / 64) * (256 / 128), 256, 0, stream>>>(mid, wt3, r1_b3, cellout, BB, 256, P2C);
  build_hidden_kernel<<<BB * 512 / 256, 256, 0, stream>>>(feat, drug1, drug2, cellout, hidden);
  rownorm_kernel<u16><<<BB, 256, 0, stream>>>(hidden, hiddennorm, 512, 512);
  // GEMM4: N=2048 -> 128x128 tile
  gemm_db<1, 1><<<(BB / 128) * (P1C / 128), 256, 0, stream>>>(hiddennorm, wt4, r2_b1, big, BB, P1C, 512);
  // GEMM5: N=512, K=2048 -> 64-row tiles
  gemm_db64<1, 1><<<(BB / 64) * (P2C / 128), 256, 0, stream>>>(big, wt5, r2_b2, mid, BB, P2C, P1C);
  // GEMM6: N=128 -> 64-row tiles
  gemm_db64<1, 1><<<(BB / 64) * (HH / 128), 256, 0, stream>>>(mid, wt6, r2_b3, h2, BB, HH, P2C);
  logits_kernel<<<BB, 128, 0, stream>>>(h2, cls_W, cls_b, out);
}

// Round 9
// 316.555 us; speedup vs baseline: 3.2595x; 1.0834x over previous
//
#include <hip/hip_runtime.h>

// Problem constants (fixed by the reference)
#define ND 10000
#define NT_ 10000
#define EE 500000
#define BB 8192
#define DF 256
#define TFD 256
#define HH 128
#define CF 954
#define CFP 960   // padded K for MFMA (zero-filled)
#define P1C 2048
#define P2C 512
#define MPAD 10112  // ND padded to multiple of 128 (and 64)

// sort constants
#define CHUNK 4096
#define NCH 123
#define NBK 157
#define MAXB 6144
#define GCAP 256   // max degree ~82 (Binomial(5e5,1e-4)); big margin + fallback

typedef unsigned short u16;
typedef __attribute__((ext_vector_type(8))) short short8;
typedef __attribute__((ext_vector_type(4))) float f4;

#define AS1 __attribute__((address_space(1)))
#define AS3 __attribute__((address_space(3)))
#define GLOAD16(g, l) \
  __builtin_amdgcn_global_load_lds((const AS1 void*)(g), (AS3 void*)(l), 16, 0, 0)

__device__ inline u16 f2bf(float f) {
  unsigned int u = __builtin_bit_cast(unsigned int, f);
  unsigned int r = (u + 0x7FFFu + ((u >> 16) & 1u)) >> 16;
  return (u16)r;
}
__device__ inline float bf2f(u16 b) {
  return __builtin_bit_cast(float, ((unsigned int)b) << 16);
}
__device__ inline float ldval(float v) { return v; }
__device__ inline float ldval(u16 v) { return bf2f(v); }

__device__ inline void load8cvt(const float* p, u16* dst) {
#pragma unroll
  for (int i = 0; i < 4; ++i) {
    float2 v = reinterpret_cast<const float2*>(p)[i];
    dst[2 * i] = f2bf(v.x);
    dst[2 * i + 1] = f2bf(v.y);
  }
}

// T1: XCD chunked swizzle (bijective when nwg % 8 == 0; identity otherwise)
__device__ inline int xcd_swz(int bid, int nwg) {
  return ((nwg & 7) == 0) ? ((bid & 7) * (nwg >> 3) + (bid >> 3)) : bid;
}

// ============ x fp32 -> bf16, rows padded to MPAD with zeros ================
__global__ void __launch_bounds__(256) xcvt_kernel(const float* __restrict__ xd,
                                                   const float* __restrict__ xt,
                                                   u16* __restrict__ xdb,
                                                   u16* __restrict__ xtb) {
  const float* X = blockIdx.y ? xt : xd;
  u16* Y = blockIdx.y ? xtb : xdb;
  long i = (long)blockIdx.x * 256 + threadIdx.x;  // one 8-elem chunk each
  long e = i * 8;
  int row = (int)(e >> 8);
  union { u16 u[8]; short8 v; } tv;
  if (row < ND) {
    load8cvt(X + e, tv.u);
  } else {
#pragma unroll
    for (int k = 0; k < 8; ++k) tv.u[k] = 0;
  }
  *reinterpret_cast<short8*>(Y + e) = tv.v;
}

// ============ fused weight transpose: fp32 [K,N] -> bf16 [N,Kp] (zero pad) ==
struct TransArgs {
  const float* W[12];
  u16* Wt[12];
  int K[12];
  int N[12];
  int Kp[12];
};

__global__ void __launch_bounds__(256) transpose_all(TransArgs ta) {
  const int id = blockIdx.y;
  const int K = ta.K[id], N = ta.N[id], Kp = ta.Kp[id];
  const int tn = (N + 31) >> 5, tk = (Kp + 31) >> 5;
  if ((int)blockIdx.x >= tn * tk) return;
  const float* W = ta.W[id];
  u16* Wt = ta.Wt[id];
  const int bn = (blockIdx.x % tn) << 5;
  const int bk = (blockIdx.x / tn) << 5;
  __shared__ u16 tile[32][33];
  const int tx = threadIdx.x;
  const int ty = threadIdx.y;
#pragma unroll
  for (int i = ty; i < 32; i += 8) {
    int k = bk + i, n = bn + tx;
    tile[i][tx] = (k < K && n < N) ? f2bf(W[(long)k * N + n]) : (u16)0;
  }
  __syncthreads();
#pragma unroll
  for (int i = ty; i < 32; i += 8) {
    int n = bn + i, k = bk + tx;
    if (n < N && k < Kp) Wt[(long)n * Kp + k] = tile[tx][i];
  }
}

// ============ T3-minimal double-buffered bf16 GEMM, 128x128 tile ============
// C[M,N] = act((A[M,K] @ Bt[N,K]^T) * rs[row] + bias).  M%128, N%128, K%32 == 0.
template <int ACT, int BIAS, int RSCALE>
__global__ void __launch_bounds__(256) gemm_db(const u16* __restrict__ A,
                                               const u16* __restrict__ Bt,
                                               const float* __restrict__ bias,
                                               const float* __restrict__ rs,
                                               u16* __restrict__ C, int M, int N, int K) {
  const int bid = xcd_swz(blockIdx.x, gridDim.x);
  const int tiles_n = N >> 7;
  const int bm = bid / tiles_n;
  const int bn = bid % tiles_n;
  const long row0 = (long)bm << 7;
  const int col0 = bn << 7;
  __shared__ u16 sh[16384];  // 32 KB: buf b: A at b*8192, B at b*8192+4096
  const int t = threadIdx.x;
  const int lane = t & 63;
  const int w = t >> 6;
  const int wr = w >> 1, wc = w & 1;
  const int lr = lane & 15, lk = lane >> 4;
  const int srow = lane >> 2;
  const int scol = (lane & 3) << 3;
  const u16* gA0 = A + (row0 + (w << 4) + srow) * K + scol;
  const u16* gA1 = A + (row0 + ((w + 4) << 4) + srow) * K + scol;
  const u16* gB0 = Bt + ((long)col0 + (w << 4) + srow) * K + scol;
  const u16* gB1 = Bt + ((long)col0 + ((w + 4) << 4) + srow) * K + scol;
  const int lofs0 = (w << 4) * 32;
  const int lofs1 = ((w + 4) << 4) * 32;
  f4 acc[4][4] = {};
  const int nk = K >> 5;

#define STAGE4(kt_, b_)                                     \
  do {                                                      \
    const int ko = (kt_) << 5;                              \
    u16* ab = sh + (b_) * 8192;                             \
    u16* bb = ab + 4096;                                    \
    GLOAD16(gA0 + ko, ab + lofs0);                          \
    GLOAD16(gA1 + ko, ab + lofs1);                          \
    GLOAD16(gB0 + ko, bb + lofs0);                          \
    GLOAD16(gB1 + ko, bb + lofs1);                          \
  } while (0)

  STAGE4(0, 0);
  __syncthreads();
  int cur = 0;
  for (int kt = 0; kt < nk; ++kt) {
    if (kt + 1 < nk) STAGE4(kt + 1, cur ^ 1);
    const u16* Ab = sh + cur * 8192;
    const u16* Bb = Ab + 4096;
    short8 af[4], bf[4];
#pragma unroll
    for (int m = 0; m < 4; ++m)
      af[m] = *reinterpret_cast<const short8*>(&Ab[(((wr << 6) + (m << 4) + lr) << 5) + (lk << 3)]);
#pragma unroll
    for (int n = 0; n < 4; ++n)
      bf[n] = *reinterpret_cast<const short8*>(&Bb[(((wc << 6) + (n << 4) + lr) << 5) + (lk << 3)]);
#pragma unroll
    for (int m = 0; m < 4; ++m)
#pragma unroll
      for (int n = 0; n < 4; ++n)
        acc[m][n] = __builtin_amdgcn_mfma_f32_16x16x32_bf16(af[m], bf[n], acc[m][n], 0, 0, 0);
    __syncthreads();
    cur ^= 1;
  }
#undef STAGE4

  float bv[4];
#pragma unroll
  for (int n = 0; n < 4; ++n)
    bv[n] = BIAS ? bias[col0 + (wc << 6) + (n << 4) + lr] : 0.0f;
#pragma unroll
  for (int m = 0; m < 4; ++m) {
#pragma unroll
    for (int r = 0; r < 4; ++r) {
      const int row = (wr << 6) + (m << 4) + (lk << 2) + r;
      const float rsv = RSCALE ? rs[row0 + row] : 1.0f;
#pragma unroll
      for (int n = 0; n < 4; ++n) {
        const int col = (wc << 6) + (n << 4) + lr;
        float x = acc[m][n][r];
        if (RSCALE) x *= rsv;
        x += bv[n];
        if (ACT) x = fmaxf(x, 0.0f);
        sh[(row << 7) + col] = f2bf(x);
      }
    }
  }
  __syncthreads();
#pragma unroll
  for (int i = 0; i < 8; ++i) {
    const int c = t + (i << 8);
    const int rr = c >> 4, off = (c & 15) << 3;
    *reinterpret_cast<short8*>(&C[(row0 + rr) * N + col0 + off]) =
        *reinterpret_cast<const short8*>(&sh[(rr << 7) + off]);
  }
}

// ============ 64x128-tile dbuf GEMM for small-N / occupancy-starved shapes ==
template <int ACT, int BIAS>
__global__ void __launch_bounds__(256) gemm_db64(const u16* __restrict__ A,
                                                 const u16* __restrict__ Bt,
                                                 const float* __restrict__ bias,
                                                 u16* __restrict__ C, int M, int N, int K) {
  const int bid = xcd_swz(blockIdx.x, gridDim.x);
  const int tiles_n = N >> 7;
  const int bm = bid / tiles_n;
  const int bn = bid % tiles_n;
  const long row0 = (long)bm << 6;  // 64-row tile
  const int col0 = bn << 7;
  __shared__ u16 sh[12288];  // 24KB: buf b at b*6144; A [64][32] then B [128][32]
  const int t = threadIdx.x;
  const int lane = t & 63;
  const int w = t >> 6;
  const int wr = w >> 1, wc = w & 1;
  const int lr = lane & 15, lk = lane >> 4;
  const int srow = lane >> 2;
  const int scol = (lane & 3) << 3;
  const u16* gA0 = A + (row0 + (w << 4) + srow) * K + scol;
  const u16* gB0 = Bt + ((long)col0 + (w << 4) + srow) * K + scol;
  const u16* gB1 = Bt + ((long)col0 + ((w + 4) << 4) + srow) * K + scol;
  const int lofs0 = (w << 4) * 32;
  const int lofs1 = ((w + 4) << 4) * 32;
  f4 acc[2][4] = {};
  const int nk = K >> 5;

#define STAGE3(kt_, b_)                                     \
  do {                                                      \
    const int ko = (kt_) << 5;                              \
    u16* ab = sh + (b_) * 6144;                             \
    u16* bb = ab + 2048;                                    \
    GLOAD16(gA0 + ko, ab + lofs0);                          \
    GLOAD16(gB0 + ko, bb + lofs0);                          \
    GLOAD16(gB1 + ko, bb + lofs1);                          \
  } while (0)

  STAGE3(0, 0);
  __syncthreads();
  int cur = 0;
  for (int kt = 0; kt < nk; ++kt) {
    if (kt + 1 < nk) STAGE3(kt + 1, cur ^ 1);
    const u16* Ab = sh + cur * 6144;
    const u16* Bb = Ab + 2048;
    short8 af[2], bf[4];
#pragma unroll
    for (int m = 0; m < 2; ++m)
      af[m] = *reinterpret_cast<const short8*>(&Ab[(((wr << 5) + (m << 4) + lr) << 5) + (lk << 3)]);
#pragma unroll
    for (int n = 0; n < 4; ++n)
      bf[n] = *reinterpret_cast<const short8*>(&Bb[(((wc << 6) + (n << 4) + lr) << 5) + (lk << 3)]);
#pragma unroll
    for (int m = 0; m < 2; ++m)
#pragma unroll
      for (int n = 0; n < 4; ++n)
        acc[m][n] = __builtin_amdgcn_mfma_f32_16x16x32_bf16(af[m], bf[n], acc[m][n], 0, 0, 0);
    __syncthreads();
    cur ^= 1;
  }
#undef STAGE3

  float bv[4];
#pragma unroll
  for (int n = 0; n < 4; ++n)
    bv[n] = BIAS ? bias[col0 + (wc << 6) + (n << 4) + lr] : 0.0f;
#pragma unroll
  for (int m = 0; m < 2; ++m) {
#pragma unroll
    for (int n = 0; n < 4; ++n) {
      const int col = (wc << 6) + (n << 4) + lr;
#pragma unroll
      for (int r = 0; r < 4; ++r) {
        const int row = (wr << 5) + (m << 4) + (lk << 2) + r;
        float x = acc[m][n][r] + bv[n];
        if (ACT) x = fmaxf(x, 0.0f);
        sh[(row << 7) + col] = f2bf(x);
      }
    }
  }
  __syncthreads();
#pragma unroll
  for (int i = 0; i < 4; ++i) {
    const int c = t + (i << 8);       // 0..1023 chunks of 16B
    const int rr = c >> 4, off = (c & 15) << 3;
    *reinterpret_cast<short8*>(&C[(row0 + rr) * N + col0 + off]) =
        *reinterpret_cast<const short8*>(&sh[(rr << 7) + off]);
  }
}

// ============ node GEMM (64x128 dbuf) + fused attention-logit dots ==========
// Per bn slice: e0 = h . a0 (es), e1 = h . a1 (ed); nullptr = skip.
struct NodeEd {
  const float* a0[3];
  const float* a1[3];
  float* e0[3];
  float* e1[3];
};

__global__ void __launch_bounds__(256) gemm_node(const u16* __restrict__ A,
                                                 const u16* __restrict__ Bt,
                                                 u16* __restrict__ C, NodeEd ne) {
  const int M = MPAD, N = 384, K = 256;
  const int bid = blockIdx.x;  // 474 blocks: no swizzle (474 % 8 != 0)
  const int tiles_n = 3;
  const int bm = bid / tiles_n;
  const int bn = bid % tiles_n;
  const long row0 = (long)bm << 6;
  const int col0 = bn << 7;
  __shared__ u16 sh[12288];
  const int t = threadIdx.x;
  const int lane = t & 63;
  const int w = t >> 6;
  const int wr = w >> 1, wc = w & 1;
  const int lr = lane & 15, lk = lane >> 4;
  const int srow = lane >> 2;
  const int scol = (lane & 3) << 3;
  const u16* gA0 = A + (row0 + (w << 4) + srow) * K + scol;
  const u16* gB0 = Bt + ((long)col0 + (w << 4) + srow) * K + scol;
  const u16* gB1 = Bt + ((long)col0 + ((w + 4) << 4) + srow) * K + scol;
  const int lofs0 = (w << 4) * 32;
  const int lofs1 = ((w + 4) << 4) * 32;
  f4 acc[2][4] = {};
  const int nk = K >> 5;

#define STAGE3(kt_, b_)                                     \
  do {                                                      \
    const int ko = (kt_) << 5;                              \
    u16* ab = sh + (b_) * 6144;                             \
    u16* bb = ab + 2048;                                    \
    GLOAD16(gA0 + ko, ab + lofs0);                          \
    GLOAD16(gB0 + ko, bb + lofs0);                          \
    GLOAD16(gB1 + ko, bb + lofs1);                          \
  } while (0)

  STAGE3(0, 0);
  __syncthreads();
  int cur = 0;
  for (int kt = 0; kt < nk; ++kt) {
    if (kt + 1 < nk) STAGE3(kt + 1, cur ^ 1);
    const u16* Ab = sh + cur * 6144;
    const u16* Bb = Ab + 2048;
    short8 af[2], bf[4];
#pragma unroll
    for (int m = 0; m < 2; ++m)
      af[m] = *reinterpret_cast<const short8*>(&Ab[(((wr << 5) + (m << 4) + lr) << 5) + (lk << 3)]);
#pragma unroll
    for (int n = 0; n < 4; ++n)
      bf[n] = *reinterpret_cast<const short8*>(&Bb[(((wc << 6) + (n << 4) + lr) << 5) + (lk << 3)]);
#pragma unroll
    for (int m = 0; m < 2; ++m)
#pragma unroll
      for (int n = 0; n < 4; ++n)
        acc[m][n] = __builtin_amdgcn_mfma_f32_16x16x32_bf16(af[m], bf[n], acc[m][n], 0, 0, 0);
    __syncthreads();
    cur ^= 1;
  }
#undef STAGE3

#pragma unroll
  for (int m = 0; m < 2; ++m) {
#pragma unroll
    for (int n = 0; n < 4; ++n) {
      const int col = (wc << 6) + (n << 4) + lr;
#pragma unroll
      for (int r = 0; r < 4; ++r) {
        const int row = (wr << 5) + (m << 4) + (lk << 2) + r;
        sh[(row << 7) + col] = f2bf(acc[m][n][r]);
      }
    }
  }
  __syncthreads();
#pragma unroll
  for (int i = 0; i < 4; ++i) {
    const int c = t + (i << 8);
    const int rr = c >> 4, off = (c & 15) << 3;
    *reinterpret_cast<short8*>(&C[(row0 + rr) * N + col0 + off]) =
        *reinterpret_cast<const short8*>(&sh[(rr << 7) + off]);
  }
  // ---- fused es/ed dots: thread t -> row t>>2, col-quarter t&3 (32 cols) ----
  const float* a0 = ne.a0[bn];
  const float* a1 = ne.a1[bn];
  if (a0 || a1) {
    const int r = t >> 2, qq = t & 3;
    const u16* hrow = sh + (r << 7) + (qq << 5);
    float p0 = 0.f, p1 = 0.f;
#pragma unroll
    for (int c = 0; c < 32; ++c) {
      float hv = bf2f(hrow[c]);
      if (a0) p0 += hv * a0[(qq << 5) + c];
      if (a1) p1 += hv * a1[(qq << 5) + c];
    }
    p0 += __shfl_xor(p0, 1); p0 += __shfl_xor(p0, 2);
    p1 += __shfl_xor(p1, 1); p1 += __shfl_xor(p1, 2);
    const int grow = (int)row0 + r;
    if (qq == 0 && grow < ND) {
      if (ne.e0[bn]) ne.e0[bn][grow] = p0;
      if (ne.e1[bn]) ne.e1[bn][grow] = p1;
    }
  }
}

// ============ binned counting sort (coalesced CSR build) ====================
struct EdgePtrs {
  const int* dst[4];
  const int* src[4];
};

__global__ void __launch_bounds__(256) sort_count(EdgePtrs ep, int* __restrict__ hist) {
  const int cv = blockIdx.y, ch = blockIdx.x;
  __shared__ int h[NBK];
  for (int i = threadIdx.x; i < NBK; i += 256) h[i] = 0;
  __syncthreads();
  const int* dst = ep.dst[cv];
  const int e0 = ch * CHUNK;
  const int e1 = e0 + CHUNK < EE ? e0 + CHUNK : EE;
  for (int i = e0 + threadIdx.x; i < e1; i += 256) atomicAdd(&h[dst[i] >> 6], 1);
  __syncthreads();
  int* out = hist + ((long)cv * NCH + ch) * NBK;
  for (int i = threadIdx.x; i < NBK; i += 256) out[i] = h[i];
}

__global__ void __launch_bounds__(256) sort_scan(int* __restrict__ hist, int* __restrict__ base,
                                                 int* __restrict__ offs_all) {
  const int cv = blockIdx.x;
  int* H = hist + (long)cv * NCH * NBK;
  __shared__ int tot[NBK];
  for (int b = threadIdx.x; b < NBK; b += 256) {
    int run = 0;
    for (int ch = 0; ch < NCH; ++ch) {
      int v = H[ch * NBK + b];
      H[ch * NBK + b] = run;
      run += v;
    }
    tot[b] = run;
  }
  __syncthreads();
  if (threadIdx.x == 0) {
    int* B = base + cv * (NBK + 1);
    int run = 0;
    for (int b = 0; b < NBK; ++b) { B[b] = run; run += tot[b]; }
    B[NBK] = run;
    offs_all[(long)cv * 10001 + 10000] = run;
  }
}

__global__ void __launch_bounds__(256) sort_scatter(EdgePtrs ep, const int* __restrict__ hist,
                                                    const int* __restrict__ base,
                                                    unsigned int* __restrict__ binned) {
  const int cv = blockIdx.y, ch = blockIdx.x;
  __shared__ int lcnt[NBK];
  __shared__ int lofs[NBK];
  __shared__ int lcur[NBK];
  __shared__ int sofs[NBK];
  __shared__ unsigned int buf[CHUNK];
  for (int i = threadIdx.x; i < NBK; i += 256) lcnt[i] = 0;
  __syncthreads();
  const int* dst = ep.dst[cv];
  const int* src = ep.src[cv];
  const int e0 = ch * CHUNK;
  const int e1 = e0 + CHUNK < EE ? e0 + CHUNK : EE;
  const int n = e1 - e0;
  unsigned int pk[16];
#pragma unroll
  for (int u = 0; u < 16; ++u) {
    int i = e0 + u * 256 + threadIdx.x;
    unsigned int p = 0xFFFFFFFFu;
    if (i < e1) {
      int d = dst[i];
      p = ((unsigned int)d << 16) | (unsigned int)src[i];
      atomicAdd(&lcnt[d >> 6], 1);
    }
    pk[u] = p;
  }
  {
    const int* chOfs = hist + ((long)cv * NCH + ch) * NBK;
    const int* B = base + cv * (NBK + 1);
    for (int b = threadIdx.x; b < NBK; b += 256) sofs[b] = B[b] + chOfs[b];
  }
  __syncthreads();
  if (threadIdx.x == 0) {
    int run = 0;
    for (int b = 0; b < NBK; ++b) { lofs[b] = run; lcur[b] = run; run += lcnt[b]; }
  }
  __syncthreads();
#pragma unroll
  for (int u = 0; u < 16; ++u) {
    if (pk[u] != 0xFFFFFFFFu) {
      int b = pk[u] >> 22;
      int p = atomicAdd(&lcur[b], 1);
      buf[p] = pk[u];
    }
  }
  __syncthreads();
  unsigned int* outp = binned + (long)cv * EE;
  for (int i = threadIdx.x; i < n; i += 256) {
    unsigned int p = buf[i];
    int b = p >> 22;
    outp[sofs[b] + (i - lofs[b])] = p;
  }
}

__global__ void __launch_bounds__(256) sort_bucket(const unsigned int* __restrict__ binned,
                                                   const int* __restrict__ base,
                                                   int* __restrict__ offs_all,
                                                   u16* __restrict__ srcs) {
  const int cv = blockIdx.y, b = blockIdx.x;
  const int* B = base + cv * (NBK + 1);
  const int s0 = B[b], s1 = B[b + 1];
  int n = s1 - s0;
  if (n > MAXB) n = MAXB;
  __shared__ unsigned int buf[MAXB];
  __shared__ u16 obuf[MAXB];
  __shared__ int cnt[64], dofs[64], dcur[64];
  if (threadIdx.x < 64) cnt[threadIdx.x] = 0;
  __syncthreads();
  const unsigned int* inp = binned + (long)cv * EE + s0;
  for (int i = threadIdx.x; i < n; i += 256) {
    unsigned int p = inp[i];
    buf[i] = p;
    atomicAdd(&cnt[(p >> 16) & 63], 1);
  }
  __syncthreads();
  if (threadIdx.x == 0) {
    int run = 0;
    for (int i = 0; i < 64; ++i) { dofs[i] = run; dcur[i] = run; run += cnt[i]; }
  }
  __syncthreads();
  if (threadIdx.x < 64) {
    int d = (b << 6) + threadIdx.x;
    if (d < 10000) offs_all[(long)cv * 10001 + d] = s0 + dofs[threadIdx.x];
  }
  for (int i = threadIdx.x; i < n; i += 256) {
    unsigned int p = buf[i];
    int pos = atomicAdd(&dcur[(p >> 16) & 63], 1);
    obuf[pos] = (u16)(p & 0xFFFFu);
  }
  __syncthreads();
  u16* outp = srcs + (long)cv * EE + s0;
  for (int i = threadIdx.x; i < n; i += 256) outp[i] = obuf[i];
}

// ============ fused GAT: wave-per-dst, 2 rows per wave-iteration ============
struct GatArgs {
  const int* offs[4];
  const u16* srcs[4];
  const float* es[4];
  const float* ed[4];
  const u16* hs[4];   // stride 384
  const float* bias[4];
};

__global__ void __launch_bounds__(256) gat3(GatArgs ga, float* __restrict__ out,
                                            u16* __restrict__ feat) {
  const int t = threadIdx.x;
  const int w = t >> 6;
  const int lane = t & 63;
  const int hi = lane >> 5;
  const int fl = (lane & 31) << 2;
  const int d = blockIdx.x * 4 + w;
  const int half = blockIdx.y;
  __shared__ float al[4][GCAP + 2];
  __shared__ u16 sl[4][GCAP + 2];
  float a0 = 0.f, a1 = 0.f, a2 = 0.f, a3 = 0.f;
#pragma unroll
  for (int q = 0; q < 2; ++q) {
    const int cv = half * 2 + q;
    const int* offs = ga.offs[cv];
    const int o0 = offs[d], o1 = offs[d + 1];
    const int deg = o1 - o0;
    const u16* sp = ga.srcs[cv] + o0;
    const float* es = ga.es[cv];
    const float edd = ga.ed[cv][d];
    const u16* hs = ga.hs[cv];
    const int degc = deg > GCAP ? GCAP : deg;
    __syncthreads();
    float part = 0.f;
    for (int j = lane; j < degc; j += 64) {
      int s = sp[j];
      float e = es[s] + edd;
      e = e > 0.f ? e : 0.2f * e;
      float ex = __expf(e);
      al[w][j] = ex;
      sl[w][j] = (u16)s;
      part += ex;
    }
    for (int j = GCAP + lane; j < deg; j += 64) {  // never taken for this data
      float e = es[sp[j]] + edd;
      e = e > 0.f ? e : 0.2f * e;
      part += __expf(e);
    }
#pragma unroll
    for (int o = 32; o > 0; o >>= 1) part += __shfl_down(part, o);
    const float inv = 1.0f / (__shfl(part, 0) + 1e-16f);
    for (int j = lane; j < degc; j += 64) al[w][j] *= inv;
    if (lane == 0 && (degc & 1)) { al[w][degc] = 0.f; sl[w][degc] = 0; }
    __syncthreads();
    const int npair = (degc + 1) >> 1;
#pragma unroll 4
    for (int k = 0; k < npair; ++k) {
      const int j = 2 * k + hi;
      const float wgt = al[w][j];
      const int s = sl[w][j];
      ushort4 v = *reinterpret_cast<const ushort4*>(hs + (long)s * 384 + fl);
      a0 += wgt * bf2f(v.x);
      a1 += wgt * bf2f(v.y);
      a2 += wgt * bf2f(v.z);
      a3 += wgt * bf2f(v.w);
    }
    if (hi == 0) {
      for (int j = GCAP; j < deg; ++j) {  // never taken
        int s = sp[j];
        float e = es[s] + edd;
        e = e > 0.f ? e : 0.2f * e;
        float wgt = __expf(e) * inv;
        ushort4 v = *reinterpret_cast<const ushort4*>(hs + (long)s * 384 + fl);
        a0 += wgt * bf2f(v.x); a1 += wgt * bf2f(v.y);
        a2 += wgt * bf2f(v.z); a3 += wgt * bf2f(v.w);
      }
    }
  }
  a0 += __shfl_xor(a0, 32);
  a1 += __shfl_xor(a1, 32);
  a2 += __shfl_xor(a2, 32);
  a3 += __shfl_xor(a3, 32);
  if (hi == 0) {
    const float* b1 = ga.bias[half * 2];
    const float* b2 = ga.bias[half * 2 + 1];
    float4 bb1 = *reinterpret_cast<const float4*>(b1 + fl);
    float4 bb2 = *reinterpret_cast<const float4*>(b2 + fl);
    float4 r;
    r.x = fmaxf(a0 + bb1.x + bb2.x, 0.0f);
    r.y = fmaxf(a1 + bb1.y + bb2.y, 0.0f);
    r.z = fmaxf(a2 + bb1.z + bb2.z, 0.0f);
    r.w = fmaxf(a3 + bb1.w + bb2.w, 0.0f);
    *reinterpret_cast<float4*>(out + 16384 + (long)half * ND * HH + (long)d * HH + fl) = r;
    if (half == 0) {
      ushort4 fv;
      fv.x = f2bf(r.x); fv.y = f2bf(r.y); fv.z = f2bf(r.z); fv.w = f2bf(r.w);
      *reinterpret_cast<ushort4*>(feat + (long)d * HH + fl) = fv;
    }
  }
}

// ============ row L2-normalize -> bf16 (with zero pad to Kout) ==============
template <typename T>
__global__ void __launch_bounds__(256) rownorm_kernel(const T* __restrict__ X,
                                                      u16* __restrict__ Y, int Kin, int Kout) {
  const int row = blockIdx.x;
  const int t = threadIdx.x;
  const T* xr = X + (long)row * Kin;
  float ss = 0.f;
  for (int k = t; k < Kin; k += 256) {
    float v = ldval(xr[k]);
    ss += v * v;
  }
#pragma unroll
  for (int o = 32; o > 0; o >>= 1) ss += __shfl_down(ss, o);
  __shared__ float sh[4];
  if ((t & 63) == 0) sh[t >> 6] = ss;
  __syncthreads();
  float tot = sh[0] + sh[1] + sh[2] + sh[3];
  float inv = 1.0f / fmaxf(sqrtf(tot), 1e-12f);
  u16* yr = Y + (long)row * Kout;
  for (int k = t; k < Kin; k += 256) yr[k] = f2bf(ldval(xr[k]) * inv);
  for (int k = Kin + t; k < Kout; k += 256) yr[k] = 0;
}

// ============ buildprep: hidden = [feat[id1],feat[id2],cell] + inv-norm ====
// Writes RAW bf16 hidden + per-row 1/||hidden||; GEMM4 applies the scale.
__global__ void __launch_bounds__(256) buildprep_kernel(const u16* __restrict__ feat,
                                                        const int* __restrict__ id1,
                                                        const int* __restrict__ id2,
                                                        const u16* __restrict__ cell,
                                                        u16* __restrict__ hidraw,
                                                        float* __restrict__ hinvn) {
  const int row = blockIdx.x;
  const int t = threadIdx.x;
  const int i1 = id1[row], i2 = id2[row];
  u16 v[2];
  float ss = 0.f;
#pragma unroll
  for (int u = 0; u < 2; ++u) {
    const int col = t + (u << 8);
    u16 x;
    if (col < 128) x = feat[(long)i1 * HH + col];
    else if (col < 256) x = feat[(long)i2 * HH + (col - 128)];
    else x = cell[(long)row * 256 + (col - 256)];
    v[u] = x;
    float f = bf2f(x);
    ss += f * f;
  }
#pragma unroll
  for (int o = 32; o > 0; o >>= 1) ss += __shfl_down(ss, o);
  __shared__ float sh[4];
  if ((t & 63) == 0) sh[t >> 6] = ss;
  __syncthreads();
  const float tot = sh[0] + sh[1] + sh[2] + sh[3];
  hidraw[(long)row * 512 + t] = v[0];
  hidraw[(long)row * 512 + t + 256] = v[1];
  if (t == 0) hinvn[row] = 1.0f / fmaxf(sqrtf(tot), 1e-12f);
}

// ============ logits: [B,128] @ [128,2] + b -> fp32 =========================
__global__ void __launch_bounds__(128) logits_kernel(const u16* __restrict__ h2,
                                                     const float* __restrict__ W,
                                                     const float* __restrict__ b,
                                                     float* __restrict__ out) {
  const int row = blockIdx.x;
  const int t = threadIdx.x;
  float hv = bf2f(h2[(long)row * HH + t]);
  float p0 = hv * W[2 * t], p1 = hv * W[2 * t + 1];
#pragma unroll
  for (int o = 32; o > 0; o >>= 1) {
    p0 += __shfl_down(p0, o);
    p1 += __shfl_down(p1, o);
  }
  __shared__ float sA[2], sB[2];
  if ((t & 63) == 0) { sA[t >> 6] = p0; sB[t >> 6] = p1; }
  __syncthreads();
  if (t == 0) {
    out[2 * row] = sA[0] + sA[1] + b[0];
    out[2 * row + 1] = sB[0] + sB[1] + b[1];
  }
}

extern "C" void kernel_launch(void* const* d_in, const int* in_sizes, int n_in,
                              void* d_out, int out_size, void* d_ws, size_t ws_size,
                              hipStream_t stream) {
  const float* x_drug = (const float*)d_in[0];
  const float* x_target = (const float*)d_in[1];
  const float* cellf = (const float*)d_in[2];
  const float* dd_W = (const float*)d_in[3];
  const float* dd_as = (const float*)d_in[4];
  const float* dd_ad = (const float*)d_in[5];
  const float* dd_b = (const float*)d_in[6];
  const float* dt_Ws = (const float*)d_in[7];
  const float* dt_Wd = (const float*)d_in[8];
  const float* dt_as = (const float*)d_in[9];
  const float* dt_ad = (const float*)d_in[10];
  const float* dt_b = (const float*)d_in[11];
  const float* td_Ws = (const float*)d_in[12];
  const float* td_Wd = (const float*)d_in[13];
  const float* td_as = (const float*)d_in[14];
  const float* td_ad = (const float*)d_in[15];
  const float* td_b = (const float*)d_in[16];
  const float* tt_W = (const float*)d_in[17];
  const float* tt_as = (const float*)d_in[18];
  const float* tt_ad = (const float*)d_in[19];
  const float* tt_b = (const float*)d_in[20];
  const float* r1_W1 = (const float*)d_in[21];
  const float* r1_b1 = (const float*)d_in[22];
  const float* r1_W2 = (const float*)d_in[23];
  const float* r1_b2 = (const float*)d_in[24];
  const float* r1_W3 = (const float*)d_in[25];
  const float* r1_b3 = (const float*)d_in[26];
  const float* r2_W1 = (const float*)d_in[27];
  const float* r2_b1 = (const float*)d_in[28];
  const float* r2_W2 = (const float*)d_in[29];
  const float* r2_b2 = (const float*)d_in[30];
  const float* r2_W3 = (const float*)d_in[31];
  const float* r2_b3 = (const float*)d_in[32];
  const float* cls_W = (const float*)d_in[33];
  const float* cls_b = (const float*)d_in[34];
  const int* src_dd = (const int*)d_in[35];
  const int* dst_dd = (const int*)d_in[36];
  const int* src_dt = (const int*)d_in[37];
  const int* dst_dt = (const int*)d_in[38];
  const int* src_td = (const int*)d_in[39];
  const int* dst_td = (const int*)d_in[40];
  const int* src_tt = (const int*)d_in[41];
  const int* dst_tt = (const int*)d_in[42];
  const int* drug1 = (const int*)d_in[43];
  const int* drug2 = (const int*)d_in[44];
  float* out = (float*)d_out;

  char* ws = (char*)d_ws;
  size_t cur = 0;
  auto alloc = [&](size_t b) {
    size_t r = cur;
    cur += (b + 255) & ~(size_t)255;
    return r;
  };

  u16* xdb = (u16*)(ws + alloc((size_t)MPAD * DF * 2));
  u16* xtb = (u16*)(ws + alloc((size_t)MPAD * TFD * 2));
  u16* Bd = (u16*)(ws + alloc((size_t)384 * DF * 2));
  u16* Bt6 = (u16*)(ws + alloc((size_t)384 * TFD * 2));
  u16* wt1 = (u16*)(ws + alloc((size_t)P1C * CFP * 2));
  u16* wt2 = (u16*)(ws + alloc((size_t)P2C * P1C * 2));
  u16* wt3 = (u16*)(ws + alloc((size_t)256 * P2C * 2));
  u16* wt4 = (u16*)(ws + alloc((size_t)P1C * 512 * 2));
  u16* wt5 = (u16*)(ws + alloc((size_t)P2C * P1C * 2));
  u16* wt6 = (u16*)(ws + alloc((size_t)HH * P2C * 2));
  u16* h6d = (u16*)(ws + alloc((size_t)MPAD * 384 * 2));
  u16* h6t = (u16*)(ws + alloc((size_t)MPAD * 384 * 2));
  float* es0 = (float*)(ws + alloc(ND * 4));
  float* ed0 = (float*)(ws + alloc(ND * 4));
  float* es1 = (float*)(ws + alloc(NT_ * 4));
  float* ed1 = (float*)(ws + alloc(ND * 4));
  float* es2 = (float*)(ws + alloc(ND * 4));
  float* ed2 = (float*)(ws + alloc(NT_ * 4));
  float* es3 = (float*)(ws + alloc(NT_ * 4));
  float* ed3 = (float*)(ws + alloc(NT_ * 4));
  int* hist = (int*)(ws + alloc((size_t)4 * NCH * NBK * 4));
  int* base = (int*)(ws + alloc((size_t)4 * (NBK + 1) * 4));
  int* offs_all = (int*)(ws + alloc((size_t)4 * 10001 * 4));
  unsigned int* binned = (unsigned int*)(ws + alloc((size_t)4 * EE * 4));
  u16* srcs = (u16*)(ws + alloc((size_t)4 * EE * 2));
  u16* feat = (u16*)(ws + alloc((size_t)ND * HH * 2));
  u16* cellnorm = (u16*)(ws + alloc((size_t)BB * CFP * 2));
  u16* big = (u16*)(ws + alloc((size_t)BB * P1C * 2));
  u16* mid = (u16*)(ws + alloc((size_t)BB * P2C * 2));
  u16* cellout = (u16*)(ws + alloc((size_t)BB * 256 * 2));
  u16* hidraw = (u16*)(ws + alloc((size_t)BB * 512 * 2));
  float* hinvn = (float*)(ws + alloc((size_t)BB * 4));
  u16* h2 = (u16*)(ws + alloc((size_t)BB * HH * 2));

  // ---- x fp32 -> bf16 (padded rows) ----
  xcvt_kernel<<<dim3(MPAD * DF / 8 / 256, 2), 256, 0, stream>>>(x_drug, x_target, xdb, xtb);

  // ---- fused transposes (12) ----
  TransArgs ta;
  const float* tw[12] = {dd_W, td_Wd, dt_Ws, td_Ws, dt_Wd, tt_W, r1_W1, r1_W2, r1_W3, r2_W1, r2_W2, r2_W3};
  u16* twt[12] = {Bd, Bd + 128 * 256, Bd + 2 * 128 * 256, Bt6, Bt6 + 128 * 256, Bt6 + 2 * 128 * 256,
                  wt1, wt2, wt3, wt4, wt5, wt6};
  int tk_[12] = {DF, DF, DF, TFD, TFD, TFD, CF, P1C, P2C, 512, P1C, P2C};
  int tn_[12] = {HH, HH, HH, HH, HH, HH, P1C, P2C, 256, P1C, P2C, HH};
  int tp_[12] = {DF, DF, DF, TFD, TFD, TFD, CFP, P1C, P2C, 512, P1C, P2C};
  for (int i = 0; i < 12; ++i) {
    ta.W[i] = tw[i]; ta.Wt[i] = twt[i]; ta.K[i] = tk_[i]; ta.N[i] = tn_[i]; ta.Kp[i] = tp_[i];
  }
  transpose_all<<<dim3(1920, 12), dim3(32, 8), 0, stream>>>(ta);

  // h layout: h_dd=h6d+0, h_tdd=h6d+128, h_dts=h6d+256, h_tds=h6t+0, h_dtd=h6t+128, h_tt=h6t+256
  const u16* h_dd = h6d;
  const u16* h_tdd = h6d + 128;
  const u16* h_dts = h6d + 256;
  const u16* h_tds = h6t;
  const u16* h_dtd = h6t + 128;
  const u16* h_tt = h6t + 256;

  // ---- node GEMMs with fused es/ed dots ----
  // h6d slices: bn0 h_dd (es0=dd_as, ed0=dd_ad); bn1 h_tdd (ed1=td_ad); bn2 h_dts (es2=dt_as)
  NodeEd ndd;
  ndd.a0[0] = dd_as; ndd.a1[0] = dd_ad; ndd.e0[0] = es0; ndd.e1[0] = ed0;
  ndd.a0[1] = nullptr; ndd.a1[1] = td_ad; ndd.e0[1] = nullptr; ndd.e1[1] = ed1;
  ndd.a0[2] = dt_as; ndd.a1[2] = nullptr; ndd.e0[2] = es2; ndd.e1[2] = nullptr;
  gemm_node<<<(MPAD / 64) * 3, 256, 0, stream>>>(xdb, Bd, h6d, ndd);
  // h6t slices: bn0 h_tds (es1=td_as); bn1 h_dtd (ed2=dt_ad); bn2 h_tt (es3=tt_as, ed3=tt_ad)
  NodeEd ntt;
  ntt.a0[0] = td_as; ntt.a1[0] = nullptr; ntt.e0[0] = es1; ntt.e1[0] = nullptr;
  ntt.a0[1] = nullptr; ntt.a1[1] = dt_ad; ntt.e0[1] = nullptr; ntt.e1[1] = ed2;
  ntt.a0[2] = tt_as; ntt.a1[2] = tt_ad; ntt.e0[2] = es3; ntt.e1[2] = ed3;
  gemm_node<<<(MPAD / 64) * 3, 256, 0, stream>>>(xtb, Bt6, h6t, ntt);

  // ---- binned counting sort -> CSR (conv order: 0=dd, 1=td, 2=dt, 3=tt) ----
  EdgePtrs ep;
  ep.dst[0] = dst_dd; ep.dst[1] = dst_td; ep.dst[2] = dst_dt; ep.dst[3] = dst_tt;
  ep.src[0] = src_dd; ep.src[1] = src_td; ep.src[2] = src_dt; ep.src[3] = src_tt;
  sort_count<<<dim3(NCH, 4), 256, 0, stream>>>(ep, hist);
  sort_scan<<<4, 256, 0, stream>>>(hist, base, offs_all);
  sort_scatter<<<dim3(NCH, 4), 256, 0, stream>>>(ep, hist, base, binned);
  sort_bucket<<<dim3(NBK, 4), 256, 0, stream>>>(binned, base, offs_all, srcs);

  // ---- fused GAT (wave-per-dst) ----
  GatArgs gaa;
  float* ees[4] = {es0, es1, es2, es3};
  float* eed[4] = {ed0, ed1, ed2, ed3};
  const u16* ghs[4] = {h_dd, h_tds, h_dts, h_tt};
  const float* gbias[4] = {dd_b, td_b, dt_b, tt_b};
  for (int i = 0; i < 4; ++i) {
    gaa.offs[i] = offs_all + (long)i * 10001;
    gaa.srcs[i] = srcs + (long)i * EE;
    gaa.es[i] = ees[i];
    gaa.ed[i] = eed[i];
    gaa.hs[i] = ghs[i];
    gaa.bias[i] = gbias[i];
  }
  gat3<<<dim3(2500, 2), 256, 0, stream>>>(gaa, out, feat);

  // ---- MLP chain ----
  rownorm_kernel<float><<<BB, 256, 0, stream>>>(cellf, cellnorm, CF, CFP);
  gemm_db<1, 1, 0><<<(BB / 128) * (P1C / 128), 256, 0, stream>>>(cellnorm, wt1, r1_b1, nullptr,
                                                                 big, BB, P1C, CFP);
  gemm_db64<1, 1><<<(BB / 64) * (P2C / 128), 256, 0, stream>>>(big, wt2, r1_b2, mid, BB, P2C, P1C);
  gemm_db64<1, 1><<<(BB / 64) * (256 / 128), 256, 0, stream>>>(mid, wt3, r1_b3, cellout, BB, 256, P2C);
  buildprep_kernel<<<BB, 256, 0, stream>>>(feat, drug1, drug2, cellout, hidraw, hinvn);
  gemm_db<1, 1, 1><<<(BB / 128) * (P1C / 128), 256, 0, stream>>>(hidraw, wt4, r2_b1, hinvn,
                                                                 big, BB, P1C, 512);
  gemm_db64<1, 1><<<(BB / 64) * (P2C / 128), 256, 0, stream>>>(big, wt5, r2_b2, mid, BB, P2C, P1C);
  gemm_db64<1, 1><<<(BB / 64) * (HH / 128), 256, 0, stream>>>(mid, wt6, r2_b3, h2, BB, HH, P2C);
  logits_kernel<<<BB, 128, 0, stream>>>(h2, cls_W, cls_b, out);
}